// Round 2
// baseline (7045.280 us; speedup 1.0000x reference)
//
#include <hip/hip_runtime.h>
#include <cstdint>
#include <cstddef>

// Problem constants
#define B_  2
#define T_  1024
#define DM  1024
#define H_  16
#define DK_ 64
#define TOPK 128

// monotone map float -> uint (bigger key == bigger float)
__device__ __forceinline__ unsigned fkey(float v) {
  unsigned u = __float_as_uint(v);
  return (u & 0x80000000u) ? ~u : (u | 0x80000000u);
}

// ---------------------------------------------------------------------------
// Exact top-128 (value desc, tie -> lower index, matching jax.lax.top_k) +
// softmax over selected + compact (idx,w) write; optional dense row write.
// scr[e] is the score of element s = tid + 256*e. blockDim.x == 256.
// Scores stay in registers; selection uses 4x8-bit radix passes on the float
// key with per-wave histograms + shfl scans (4 barriers/pass), then resolves
// index ties exactly via per-wave ballot masks.
// ---------------------------------------------------------------------------
__device__ __forceinline__ void topk_select_write(
    const float* scr, int tid, int bid,
    int* __restrict__ idx_out, float* __restrict__ w_out,
    float* __restrict__ dense) {
  __shared__ unsigned hist[4 * 257];          // per-wave, padded (bank = (w+b)%32)
  __shared__ unsigned long long eqm[4][4];    // [e-slot][wave] equality ballots
  __shared__ unsigned bc[2];
  __shared__ float redf[8];
  __shared__ unsigned redu[4];

  const int lane = tid & 63;
  const int wv = tid >> 6;

  unsigned kf[4];
  #pragma unroll
  for (int e = 0; e < 4; ++e) kf[e] = fkey(scr[e]);

  unsigned prefix = 0, r = TOPK;
  for (int pass = 0; pass < 4; ++pass) {
    const int shift = 24 - pass * 8;
    hist[tid] = 0; hist[257 + tid] = 0; hist[2 * 257 + tid] = 0; hist[3 * 257 + tid] = 0;
    __syncthreads();
    #pragma unroll
    for (int e = 0; e < 4; ++e) {
      unsigned hi = pass ? (kf[e] >> (shift + 8)) : 0u;
      if (hi == prefix)
        atomicAdd(&hist[wv * 257 + ((kf[e] >> shift) & 255u)], 1u);
    }
    __syncthreads();
    // suffix-sum over the 256 bins: wave-local shfl scan + cross-wave combine
    unsigned sfx = hist[tid] + hist[257 + tid] + hist[2 * 257 + tid] + hist[3 * 257 + tid];
    #pragma unroll
    for (int off = 1; off < 64; off <<= 1) {
      unsigned o = __shfl_down(sfx, off);
      sfx += (lane + off < 64) ? o : 0u;
    }
    if (lane == 0) redu[wv] = sfx;
    __syncthreads();
    unsigned add = 0;
    #pragma unroll
    for (int ww = 1; ww < 4; ++ww) add += (ww > wv) ? redu[ww] : 0u;
    sfx += add;
    unsigned nd = __shfl_down(sfx, 1);
    unsigned nxt = (lane < 63) ? nd : add;
    if (sfx >= r && nxt < r) { bc[0] = (unsigned)tid; bc[1] = nxt; }
    __syncthreads();
    prefix = (prefix << 8) | bc[0];
    r -= bc[1];
  }
  const unsigned thrf = prefix;  // float key of the K-th value class; take r equals

  // block max (for softmax) + equality ballots, one barrier
  float mx = fmaxf(fmaxf(scr[0], scr[1]), fmaxf(scr[2], scr[3]));
  #pragma unroll
  for (int off = 1; off < 64; off <<= 1) mx = fmaxf(mx, __shfl_xor(mx, off));
  if (lane == 0) redf[wv] = mx;
  #pragma unroll
  for (int e = 0; e < 4; ++e) {
    unsigned long long bm = __ballot(kf[e] == thrf);
    if (lane == 0) eqm[e][wv] = bm;
  }
  __syncthreads();
  const float m = fmaxf(fmaxf(redf[0], redf[1]), fmaxf(redf[2], redf[3]));

  unsigned slotTot[4];
  #pragma unroll
  for (int e = 0; e < 4; ++e)
    slotTot[e] = (unsigned)(__popcll(eqm[e][0]) + __popcll(eqm[e][1]) +
                            __popcll(eqm[e][2]) + __popcll(eqm[e][3]));
  // selection: kf > thrf, or kf == thrf with index-rank < r (rank by s asc;
  // s = tid + 256*e so ordering is (e, wave, lane) lexicographic)
  bool sel[4]; float ex[4];
  unsigned cnt = 0; float ps = 0.f; unsigned basee = 0;
  #pragma unroll
  for (int e = 0; e < 4; ++e) {
    unsigned rank = basee;
    #pragma unroll
    for (int ww = 0; ww < 4; ++ww) rank += (ww < wv) ? (unsigned)__popcll(eqm[e][ww]) : 0u;
    rank += (unsigned)__popcll(eqm[e][wv] & ((1ull << lane) - 1ull));
    bool eq = (kf[e] == thrf);
    sel[e] = (kf[e] > thrf) || (eq && rank < r);
    ex[e] = sel[e] ? __expf(scr[e] - m) : 0.f;
    ps += ex[e];
    cnt += sel[e] ? 1u : 0u;
    basee += slotTot[e];
  }
  // block sum of exp + block prefix of counts (one barrier)
  float pss = ps;
  #pragma unroll
  for (int off = 1; off < 64; off <<= 1) pss += __shfl_xor(pss, off);
  unsigned pfx = cnt;
  #pragma unroll
  for (int off = 1; off < 64; off <<= 1) {
    unsigned o = __shfl_up(pfx, off);
    pfx += (lane >= off) ? o : 0u;
  }
  if (lane == 0) redf[4 + wv] = pss;
  if (lane == 63) redu[wv] = pfx;
  __syncthreads();
  const float inv = 1.f / (redf[4] + redf[5] + redf[6] + redf[7]);
  unsigned offw = 0;
  #pragma unroll
  for (int ww = 0; ww < 4; ++ww) offw += (ww < wv) ? redu[ww] : 0u;
  unsigned pos = (unsigned)bid * TOPK + offw + pfx - cnt;
  #pragma unroll
  for (int e = 0; e < 4; ++e) {
    if (sel[e]) { idx_out[pos] = tid + 256 * e; w_out[pos] = ex[e] * inv; pos++; }
  }
  if (dense) {
    #pragma unroll
    for (int e = 0; e < 4; ++e)
      dense[(size_t)bid * 1024 + tid + 256 * e] = ex[e] * inv;
  }
}

// ---------- fp32 GEMM: C[n][m] = sum_k A[n][k] * Bm[m][k]  (NT) --------------
__global__ __launch_bounds__(256) void gemm_nt_kernel(
    const float* __restrict__ A, const float* __restrict__ Bm,
    float* __restrict__ C, int N, int M, int K) {
  __shared__ float As[16][64];
  __shared__ float Bs[16][64];
  int tid = threadIdx.x;
  int bn = blockIdx.y * 64;
  int bm = blockIdx.x * 64;
  int tx = tid & 15, ty = tid >> 4;
  int lr = tid >> 2;
  int lk = (tid & 3) * 4;
  float acc[4][4] = {{0.f, 0.f, 0.f, 0.f}, {0.f, 0.f, 0.f, 0.f},
                     {0.f, 0.f, 0.f, 0.f}, {0.f, 0.f, 0.f, 0.f}};
  for (int k0 = 0; k0 < K; k0 += 16) {
    float4 a  = *(const float4*)&A [(size_t)(bn + lr) * K + k0 + lk];
    float4 bv = *(const float4*)&Bm[(size_t)(bm + lr) * K + k0 + lk];
    As[lk + 0][lr] = a.x;  As[lk + 1][lr] = a.y;
    As[lk + 2][lr] = a.z;  As[lk + 3][lr] = a.w;
    Bs[lk + 0][lr] = bv.x; Bs[lk + 1][lr] = bv.y;
    Bs[lk + 2][lr] = bv.z; Bs[lk + 3][lr] = bv.w;
    __syncthreads();
    #pragma unroll
    for (int kk = 0; kk < 16; ++kk) {
      float4 av = *(const float4*)&As[kk][ty * 4];
      float4 bw = *(const float4*)&Bs[kk][tx * 4];
      acc[0][0] += av.x * bw.x; acc[0][1] += av.x * bw.y;
      acc[0][2] += av.x * bw.z; acc[0][3] += av.x * bw.w;
      acc[1][0] += av.y * bw.x; acc[1][1] += av.y * bw.y;
      acc[1][2] += av.y * bw.z; acc[1][3] += av.y * bw.w;
      acc[2][0] += av.z * bw.x; acc[2][1] += av.z * bw.y;
      acc[2][2] += av.z * bw.z; acc[2][3] += av.z * bw.w;
      acc[3][0] += av.w * bw.x; acc[3][1] += av.w * bw.y;
      acc[3][2] += av.w * bw.z; acc[3][3] += av.w * bw.w;
    }
    __syncthreads();
  }
  #pragma unroll
  for (int r = 0; r < 4; ++r) {
    float4 o = make_float4(acc[r][0], acc[r][1], acc[r][2], acc[r][3]);
    *(float4*)&C[(size_t)(bn + ty * 4 + r) * M + bm + tx * 4] = o;
  }
}

// ---------- adjacency: row scores + top-128 + softmax -> compact (idx,w) -----
__global__ __launch_bounds__(256) void adj_topk_kernel(
    const float* __restrict__ qf, const float* __restrict__ kf_,
    int* __restrict__ aidx, float* __restrict__ aw) {
  __shared__ float qrow[64];
  int tid = threadIdx.x, bid = blockIdx.x;
  int b = bid >> 14, h = (bid >> 10) & (H_ - 1), t = bid & (T_ - 1);
  const float* kbase = kf_ + (size_t)b * T_ * DM + h * DK_;
  if (tid < DK_) qrow[tid] = qf[((size_t)(b * T_ + t)) * DM + h * DK_ + tid];
  __syncthreads();
  float scr[4];
  #pragma unroll
  for (int si = 0; si < 4; ++si) {
    int s = tid + si * 256;
    const float4* kr = (const float4*)(kbase + (size_t)s * DM);
    float acc = 0.f;
    #pragma unroll
    for (int d4 = 0; d4 < 16; ++d4) {
      float4 kv = kr[d4];
      float4 qv = *(const float4*)&qrow[d4 * 4];
      acc += qv.x * kv.x + qv.y * kv.y + qv.z * kv.z + qv.w * kv.w;
    }
    scr[si] = acc * 0.125f;  // 1/sqrt(64)
  }
  topk_select_write(scr, tid, bid, aidx, aw, nullptr);
}

// ---------- one propagation step: D <- (1-lam) D + lam * A D  (r and i) ------
__global__ __launch_bounds__(128) void prop_kernel(
    const float* __restrict__ srcR, const float* __restrict__ srcI,
    float* __restrict__ dstR, float* __restrict__ dstI,
    const int* __restrict__ aidx, const float* __restrict__ aw,
    const float* __restrict__ logit_lam) {
  __shared__ int li[128];
  __shared__ float lw[128];
  int tid = threadIdx.x, bid = blockIdx.x;
  int b = bid >> 14, h = (bid >> 10) & (H_ - 1), t = bid & (T_ - 1);
  li[tid] = aidx[bid * TOPK + tid];
  lw[tid] = aw[bid * TOPK + tid];
  __syncthreads();
  int half = tid >> 6, d = tid & 63;
  const float* src = half ? srcI : srcR;
  float* dst = half ? dstI : dstR;
  size_t colbase = (size_t)b * (T_ * DM) + h * DK_ + d;
  float acc = 0.f;
  #pragma unroll 8
  for (int j = 0; j < 128; ++j)
    acc += lw[j] * src[colbase + (size_t)li[j] * DM];
  float lam = 1.f / (1.f + __expf(-logit_lam[0]));
  size_t own = colbase + (size_t)t * DM;
  dst[own] = (1.f - lam) * src[own] + lam * acc;
}

// ---------- finalize: D += alpha*D0; normalize -> U --------------------------
__global__ __launch_bounds__(64) void finalize_kernel(
    const float* __restrict__ pr, const float* __restrict__ pi,
    const float* __restrict__ d0r, const float* __restrict__ d0i,
    float* __restrict__ ur, float* __restrict__ ui,
    const float* __restrict__ log_alpha) {
  int tid = threadIdx.x, bid = blockIdx.x;
  int b = bid >> 14, h = (bid >> 10) & (H_ - 1), t = bid & (T_ - 1);
  size_t idx = ((size_t)(b * T_ + t)) * DM + h * DK_ + tid;
  float alpha = 1.f / (1.f + __expf(-log_alpha[0]));
  float fr = pr[idx] + alpha * d0r[idx];
  float fi = pi[idx] + alpha * d0i[idx];
  float s = fr * fr + fi * fi;
  #pragma unroll
  for (int off = 32; off >= 1; off >>= 1) s += __shfl_xor(s, off, 64);
  float nrm = fmaxf(sqrtf(s), 1e-6f);
  ur[idx] = fr / nrm;
  ui[idx] = fi / nrm;
}

// ---------- phase sim + top-128 + softmax: dense row out + compact -----------
__global__ __launch_bounds__(256) void phase_topk_kernel(
    const float* __restrict__ ur, const float* __restrict__ ui,
    float* __restrict__ dense, int* __restrict__ pidx, float* __restrict__ pw) {
  __shared__ float urow[128];
  int tid = threadIdx.x, bid = blockIdx.x;
  int b = bid >> 14, h = (bid >> 10) & (H_ - 1), t = bid & (T_ - 1);
  size_t rowoff = ((size_t)(b * T_ + t)) * DM + h * DK_;
  if (tid < 64) urow[tid] = ur[rowoff + tid];
  else if (tid < 128) urow[tid] = ui[rowoff + (tid - 64)];
  __syncthreads();
  const float* urb = ur + (size_t)b * (T_ * DM) + h * DK_;
  const float* uib = ui + (size_t)b * (T_ * DM) + h * DK_;
  float scr[4];
  #pragma unroll
  for (int si = 0; si < 4; ++si) {
    int s = tid + si * 256;
    const float4* r4 = (const float4*)(urb + (size_t)s * DM);
    const float4* i4 = (const float4*)(uib + (size_t)s * DM);
    float acc = 0.f;
    #pragma unroll
    for (int d4 = 0; d4 < 16; ++d4) {
      float4 a = r4[d4];
      float4 qv = *(const float4*)&urow[d4 * 4];
      acc += qv.x * a.x + qv.y * a.y + qv.z * a.z + qv.w * a.w;
    }
    #pragma unroll
    for (int d4 = 0; d4 < 16; ++d4) {
      float4 a = i4[d4];
      float4 qv = *(const float4*)&urow[64 + d4 * 4];
      acc += qv.x * a.x + qv.y * a.y + qv.z * a.z + qv.w * a.w;
    }
    scr[si] = acc * 11.3137085f;  // sqrt(2*DK)
  }
  topk_select_write(scr, tid, bid, pidx, pw, dense);
}

// ---------- weighted V gather: out_head in (B,T,H*DK) flat layout ------------
__global__ __launch_bounds__(64) void attnv_kernel(
    const float* __restrict__ vf, const int* __restrict__ pidx,
    const float* __restrict__ pw, float* __restrict__ outh) {
  __shared__ int li[128];
  __shared__ float lw[128];
  int tid = threadIdx.x, bid = blockIdx.x;
  int b = bid >> 14, h = (bid >> 10) & (H_ - 1), t = bid & (T_ - 1);
  li[tid] = pidx[bid * TOPK + tid];
  li[tid + 64] = pidx[bid * TOPK + tid + 64];
  lw[tid] = pw[bid * TOPK + tid];
  lw[tid + 64] = pw[bid * TOPK + tid + 64];
  __syncthreads();
  size_t colbase = (size_t)b * (T_ * DM) + h * DK_ + tid;
  float acc = 0.f;
  #pragma unroll 8
  for (int j = 0; j < 128; ++j)
    acc += lw[j] * vf[colbase + (size_t)li[j] * DM];
  outh[colbase + (size_t)t * DM] = acc;
}

extern "C" void kernel_launch(void* const* d_in, const int* in_sizes, int n_in,
                              void* d_out, int out_size, void* d_ws, size_t ws_size,
                              hipStream_t stream) {
  (void)in_sizes; (void)n_in; (void)out_size; (void)ws_size;
  const float* x         = (const float*)d_in[0];
  const float* wq        = (const float*)d_in[1];
  const float* wk        = (const float*)d_in[2];
  const float* wre       = (const float*)d_in[3];
  const float* wim       = (const float*)d_in[4];
  const float* wv        = (const float*)d_in[5];
  const float* wo        = (const float*)d_in[6];
  const float* logit_lam = (const float*)d_in[7];
  const float* log_alpha = (const float*)d_in[8];

  float* out   = (float*)d_out;                 // (B,T,DM) = 2,097,152 floats
  float* dense = out + (size_t)B_ * T_ * DM;    // phase_attn (B,H,T,T)

  char* ws = (char*)d_ws;
  const size_t MB8 = (size_t)8 << 20;
  float* q   = (float*)(ws + 0 * MB8);  // later reused as attn_out
  float* k_  = (float*)(ws + 1 * MB8);
  float* d0r = (float*)(ws + 2 * MB8);
  float* d0i = (float*)(ws + 3 * MB8);
  float* v   = (float*)(ws + 4 * MB8);
  float* b1r = (float*)(ws + 5 * MB8);
  float* b1i = (float*)(ws + 6 * MB8);
  float* b2r = (float*)(ws + 7 * MB8);
  float* b2i = (float*)(ws + 8 * MB8);
  float* urp = b1r;  // alias: b1 dead after step 4
  float* uip = b1i;
  int*   aidx = (int*)(ws + 9 * MB8);    // 16 MB (also phase idx)
  float* aw   = (float*)(ws + 11 * MB8); // 16 MB (also phase w)
  // total workspace: 104 MB

  dim3 gb(256);
  dim3 gg(DM / 64, (B_ * T_) / 64);  // (16, 32)
  gemm_nt_kernel<<<gg, gb, 0, stream>>>(x, wq,  q,   B_ * T_, DM, DM);
  gemm_nt_kernel<<<gg, gb, 0, stream>>>(x, wk,  k_,  B_ * T_, DM, DM);
  gemm_nt_kernel<<<gg, gb, 0, stream>>>(x, wre, d0r, B_ * T_, DM, DM);
  gemm_nt_kernel<<<gg, gb, 0, stream>>>(x, wim, d0i, B_ * T_, DM, DM);
  gemm_nt_kernel<<<gg, gb, 0, stream>>>(x, wv,  v,   B_ * T_, DM, DM);

  int rows = B_ * H_ * T_;  // 32768
  adj_topk_kernel<<<rows, 256, 0, stream>>>(q, k_, aidx, aw);

  prop_kernel<<<rows, 128, 0, stream>>>(d0r, d0i, b1r, b1i, aidx, aw, logit_lam);
  prop_kernel<<<rows, 128, 0, stream>>>(b1r, b1i, b2r, b2i, aidx, aw, logit_lam);
  prop_kernel<<<rows, 128, 0, stream>>>(b2r, b2i, b1r, b1i, aidx, aw, logit_lam);
  prop_kernel<<<rows, 128, 0, stream>>>(b1r, b1i, b2r, b2i, aidx, aw, logit_lam);

  finalize_kernel<<<rows, 64, 0, stream>>>(b2r, b2i, d0r, d0i, urp, uip, log_alpha);

  phase_topk_kernel<<<rows, 256, 0, stream>>>(urp, uip, dense, aidx, aw);

  attnv_kernel<<<rows, 64, 0, stream>>>(v, aidx, aw, q /* attn_out */);

  gemm_nt_kernel<<<gg, gb, 0, stream>>>(q, wo, out, B_ * T_, DM, DM);
}

// Round 3
// 1465.928 us; speedup vs baseline: 4.8060x; 4.8060x over previous
//
#include <hip/hip_runtime.h>
#include <cstdint>
#include <cstddef>

// Problem constants
#define B_  2
#define T_  1024
#define DM  1024
#define H_  16
#define DK_ 64
#define TOPK 128

// monotone map float -> uint (bigger key == bigger float)
__device__ __forceinline__ unsigned fkey(float v) {
  unsigned u = __float_as_uint(v);
  return (u & 0x80000000u) ? ~u : (u | 0x80000000u);
}

// 64x64-tile fp32 NT inner product: acc[4][4] += A-tile x B-tile over 16 k's
#define GEMM_TILE_BODY(AS, BS)                                              \
  _Pragma("unroll")                                                         \
  for (int kk = 0; kk < 16; ++kk) {                                         \
    float4 av = *(const float4*)&AS[kk][ty * 4];                            \
    float4 bw = *(const float4*)&BS[kk][tx * 4];                            \
    acc[0][0] += av.x * bw.x; acc[0][1] += av.x * bw.y;                     \
    acc[0][2] += av.x * bw.z; acc[0][3] += av.x * bw.w;                     \
    acc[1][0] += av.y * bw.x; acc[1][1] += av.y * bw.y;                     \
    acc[1][2] += av.y * bw.z; acc[1][3] += av.y * bw.w;                     \
    acc[2][0] += av.z * bw.x; acc[2][1] += av.z * bw.y;                     \
    acc[2][2] += av.z * bw.z; acc[2][3] += av.z * bw.w;                     \
    acc[3][0] += av.w * bw.x; acc[3][1] += av.w * bw.y;                     \
    acc[3][2] += av.w * bw.z; acc[3][3] += av.w * bw.w;                     \
  }

// ---------- fused 5-way projection: out[z] = x . W[z]^T, head-major ---------
__global__ __launch_bounds__(256) void proj5_kernel(
    const float* __restrict__ x,
    const float* __restrict__ wq, const float* __restrict__ wk,
    const float* __restrict__ wre, const float* __restrict__ wim,
    const float* __restrict__ wv,
    float* __restrict__ qh, float* __restrict__ kh,
    float* __restrict__ d0r, float* __restrict__ d0i, float* __restrict__ vh) {
  const float* W; float* O;
  switch (blockIdx.z) {
    case 0: W = wq;  O = qh;  break;
    case 1: W = wk;  O = kh;  break;
    case 2: W = wre; O = d0r; break;
    case 3: W = wim; O = d0i; break;
    default: W = wv; O = vh;  break;
  }
  __shared__ float As[16][64];
  __shared__ float Bs[16][64];
  int tid = threadIdx.x;
  int bn = blockIdx.y * 64, bm = blockIdx.x * 64;
  int tx = tid & 15, ty = tid >> 4;
  int lr = tid >> 2, lk = (tid & 3) * 4;
  float acc[4][4] = {};
  for (int k0 = 0; k0 < DM; k0 += 16) {
    float4 a = *(const float4*)&x[(size_t)(bn + lr) * DM + k0 + lk];
    float4 b = *(const float4*)&W[(size_t)(bm + lr) * DM + k0 + lk];
    As[lk + 0][lr] = a.x; As[lk + 1][lr] = a.y;
    As[lk + 2][lr] = a.z; As[lk + 3][lr] = a.w;
    Bs[lk + 0][lr] = b.x; Bs[lk + 1][lr] = b.y;
    Bs[lk + 2][lr] = b.z; Bs[lk + 3][lr] = b.w;
    __syncthreads();
    GEMM_TILE_BODY(As, Bs)
    __syncthreads();
  }
  // head-major store: O[b][h][t][d], m = h*64+d (h constant per block col)
  int m = bm + tx * 4;
  int h = m >> 6, d = m & 63;
  #pragma unroll
  for (int r = 0; r < 4; ++r) {
    int n = bn + ty * 4 + r;
    int b = n >> 10, t = n & 1023;
    size_t o = ((size_t)((b * H_ + h) * T_ + t)) * DK_ + d;
    *(float4*)&O[o] = make_float4(acc[r][0], acc[r][1], acc[r][2], acc[r][3]);
  }
}

// ---------- batched NT score GEMM: S[z] = scale * A[z] . B[z]^T -------------
template<int K>
__global__ __launch_bounds__(256) void score_gemm_kernel(
    const float* __restrict__ A, const float* __restrict__ Bm,
    float* __restrict__ S, float scale) {
  __shared__ float As[16][64];
  __shared__ float Bs[16][64];
  int z = blockIdx.z;
  const float* Az = A + (size_t)z * T_ * K;
  const float* Bz = Bm + (size_t)z * T_ * K;
  float* Sz = S + (size_t)z * T_ * T_;
  int tid = threadIdx.x;
  int bn = blockIdx.y * 64, bm = blockIdx.x * 64;
  int tx = tid & 15, ty = tid >> 4;
  int lr = tid >> 2, lk = (tid & 3) * 4;
  float acc[4][4] = {};
  for (int k0 = 0; k0 < K; k0 += 16) {
    float4 a = *(const float4*)&Az[(size_t)(bn + lr) * K + k0 + lk];
    float4 b = *(const float4*)&Bz[(size_t)(bm + lr) * K + k0 + lk];
    As[lk + 0][lr] = a.x; As[lk + 1][lr] = a.y;
    As[lk + 2][lr] = a.z; As[lk + 3][lr] = a.w;
    Bs[lk + 0][lr] = b.x; Bs[lk + 1][lr] = b.y;
    Bs[lk + 2][lr] = b.z; Bs[lk + 3][lr] = b.w;
    __syncthreads();
    GEMM_TILE_BODY(As, Bs)
    __syncthreads();
  }
  #pragma unroll
  for (int r = 0; r < 4; ++r) {
    float4 o = make_float4(acc[r][0] * scale, acc[r][1] * scale,
                           acc[r][2] * scale, acc[r][3] * scale);
    *(float4*)&Sz[(size_t)(bn + ty * 4 + r) * T_ + bm + tx * 4] = o;
  }
}

// ---------- plain NT GEMM for the final output projection --------------------
__global__ __launch_bounds__(256) void gemm_nt_kernel(
    const float* __restrict__ A, const float* __restrict__ Bm,
    float* __restrict__ C, int N, int M, int Kd) {
  __shared__ float As[16][64];
  __shared__ float Bs[16][64];
  int tid = threadIdx.x;
  int bn = blockIdx.y * 64, bm = blockIdx.x * 64;
  int tx = tid & 15, ty = tid >> 4;
  int lr = tid >> 2, lk = (tid & 3) * 4;
  float acc[4][4] = {};
  for (int k0 = 0; k0 < Kd; k0 += 16) {
    float4 a = *(const float4*)&A [(size_t)(bn + lr) * Kd + k0 + lk];
    float4 b = *(const float4*)&Bm[(size_t)(bm + lr) * Kd + k0 + lk];
    As[lk + 0][lr] = a.x; As[lk + 1][lr] = a.y;
    As[lk + 2][lr] = a.z; As[lk + 3][lr] = a.w;
    Bs[lk + 0][lr] = b.x; Bs[lk + 1][lr] = b.y;
    Bs[lk + 2][lr] = b.z; Bs[lk + 3][lr] = b.w;
    __syncthreads();
    GEMM_TILE_BODY(As, Bs)
    __syncthreads();
  }
  #pragma unroll
  for (int r = 0; r < 4; ++r) {
    float4 o = make_float4(acc[r][0], acc[r][1], acc[r][2], acc[r][3]);
    *(float4*)&C[(size_t)(bn + ty * 4 + r) * M + bm + tx * 4] = o;
  }
}

// ---------------------------------------------------------------------------
// Exact top-128 from a dense score row (value desc, tie -> lower index,
// matching jax.lax.top_k) + softmax over selected + compact (idx,w) write.
// Thread tid holds scores s = 4*tid + e (one coalesced float4 per thread).
// If WB, writes the softmax weights back over the score row (dense output).
// ---------------------------------------------------------------------------
template<bool WB>
__global__ __launch_bounds__(256) void topk_kernel(
    float* S, int* __restrict__ idx_out, float* __restrict__ w_out) {
  __shared__ unsigned hist[4 * 257];       // per-wave, padded
  __shared__ unsigned long long eqm[4][4]; // [e-slot][wave] equality ballots
  __shared__ unsigned bc[2];
  __shared__ float redf[8];
  __shared__ unsigned redu[4];

  const int tid = threadIdx.x, bid = blockIdx.x;
  const int lane = tid & 63, wv = tid >> 6;

  float4 sv = *(const float4*)&S[(size_t)bid * 1024 + tid * 4];
  float scr[4] = {sv.x, sv.y, sv.z, sv.w};
  unsigned kf[4];
  #pragma unroll
  for (int e = 0; e < 4; ++e) kf[e] = fkey(scr[e]);

  unsigned prefix = 0, r = TOPK;
  for (int pass = 0; pass < 4; ++pass) {
    const int shift = 24 - pass * 8;
    hist[tid] = 0; hist[257 + tid] = 0; hist[514 + tid] = 0; hist[771 + tid] = 0;
    __syncthreads();
    #pragma unroll
    for (int e = 0; e < 4; ++e) {
      unsigned hi = pass ? (kf[e] >> (shift + 8)) : 0u;
      if (hi == prefix)
        atomicAdd(&hist[wv * 257 + ((kf[e] >> shift) & 255u)], 1u);
    }
    __syncthreads();
    unsigned sfx = hist[tid] + hist[257 + tid] + hist[514 + tid] + hist[771 + tid];
    #pragma unroll
    for (int off = 1; off < 64; off <<= 1) {
      unsigned o = __shfl_down(sfx, off);
      sfx += (lane + off < 64) ? o : 0u;
    }
    if (lane == 0) redu[wv] = sfx;
    __syncthreads();
    unsigned add = 0;
    #pragma unroll
    for (int ww = 1; ww < 4; ++ww) add += (ww > wv) ? redu[ww] : 0u;
    sfx += add;
    unsigned nd = __shfl_down(sfx, 1);
    unsigned nxt = (lane < 63) ? nd : add;
    if (sfx >= r && nxt < r) { bc[0] = (unsigned)tid; bc[1] = nxt; }
    __syncthreads();
    prefix = (prefix << 8) | bc[0];
    r -= bc[1];
  }
  const unsigned thrf = prefix;  // key of K-th value class; take first r equals

  // block max + equality ballots (one barrier)
  float mx = fmaxf(fmaxf(scr[0], scr[1]), fmaxf(scr[2], scr[3]));
  #pragma unroll
  for (int off = 1; off < 64; off <<= 1) mx = fmaxf(mx, __shfl_xor(mx, off));
  if (lane == 0) redf[wv] = mx;
  #pragma unroll
  for (int e = 0; e < 4; ++e) {
    unsigned long long bm = __ballot(kf[e] == thrf);
    if (lane == 0) eqm[e][wv] = bm;
  }
  __syncthreads();
  const float m = fmaxf(fmaxf(redf[0], redf[1]), fmaxf(redf[2], redf[3]));

  // tie rank ordering by s = 4*(wv*64+lane)+e  ->  lex (wv, lane, e)
  unsigned wvTot[4];
  #pragma unroll
  for (int ww = 0; ww < 4; ++ww)
    wvTot[ww] = (unsigned)(__popcll(eqm[0][ww]) + __popcll(eqm[1][ww]) +
                           __popcll(eqm[2][ww]) + __popcll(eqm[3][ww]));
  const unsigned long long below = (1ull << lane) - 1ull;
  unsigned rank_base = 0;
  #pragma unroll
  for (int ww = 0; ww < 4; ++ww) rank_base += (ww < wv) ? wvTot[ww] : 0u;
  #pragma unroll
  for (int e = 0; e < 4; ++e)
    rank_base += (unsigned)__popcll(eqm[e][wv] & below);

  bool sel[4]; float ex[4];
  unsigned cnt = 0, ownPrior = 0; float ps = 0.f;
  #pragma unroll
  for (int e = 0; e < 4; ++e) {
    bool eq = (kf[e] == thrf);
    unsigned rank = rank_base + ownPrior;
    sel[e] = (kf[e] > thrf) || (eq && rank < r);
    ex[e] = sel[e] ? __expf(scr[e] - m) : 0.f;
    ps += ex[e];
    cnt += sel[e] ? 1u : 0u;
    ownPrior += eq ? 1u : 0u;
  }
  // block sum of exp + block prefix of counts (one barrier)
  float pss = ps;
  #pragma unroll
  for (int off = 1; off < 64; off <<= 1) pss += __shfl_xor(pss, off);
  unsigned pfx = cnt;
  #pragma unroll
  for (int off = 1; off < 64; off <<= 1) {
    unsigned o = __shfl_up(pfx, off);
    pfx += (lane >= off) ? o : 0u;
  }
  if (lane == 0) redf[4 + wv] = pss;
  if (lane == 63) redu[wv] = pfx;
  __syncthreads();
  const float inv = 1.f / (redf[4] + redf[5] + redf[6] + redf[7]);
  unsigned offw = 0;
  #pragma unroll
  for (int ww = 0; ww < 4; ++ww) offw += (ww < wv) ? redu[ww] : 0u;
  unsigned pos = (unsigned)bid * TOPK + offw + pfx - cnt;
  #pragma unroll
  for (int e = 0; e < 4; ++e) {
    if (sel[e]) { idx_out[pos] = tid * 4 + e; w_out[pos] = ex[e] * inv; pos++; }
  }
  if (WB) {
    float4 w4 = make_float4(ex[0] * inv, ex[1] * inv, ex[2] * inv, ex[3] * inv);
    *(float4*)&S[(size_t)bid * 1024 + tid * 4] = w4;
  }
}

// ---------- one propagation step (head-major): D <- (1-lam)D + lam A D ------
__global__ __launch_bounds__(128) void prop_kernel(
    const float* __restrict__ srcR, const float* __restrict__ srcI,
    float* __restrict__ dstR, float* __restrict__ dstI,
    const int* __restrict__ aidx, const float* __restrict__ aw,
    const float* __restrict__ logit_lam) {
  __shared__ int li[128];
  __shared__ float lw[128];
  int tid = threadIdx.x, bid = blockIdx.x;
  li[tid] = aidx[bid * TOPK + tid];
  lw[tid] = aw[bid * TOPK + tid];
  __syncthreads();
  int half = tid >> 6, d = tid & 63;
  const float* src = half ? srcI : srcR;
  float* dst = half ? dstI : dstR;
  size_t slice = (size_t)((bid >> 10) << 10) * DK_;  // (b,h) slice start
  float acc = 0.f;
  #pragma unroll 8
  for (int j = 0; j < 128; ++j)
    acc += lw[j] * src[slice + (size_t)li[j] * DK_ + d];
  float lam = 1.f / (1.f + __expf(-logit_lam[0]));
  size_t own = (size_t)bid * DK_ + d;
  dst[own] = (1.f - lam) * src[own] + lam * acc;
}

// ---------- finalize: D += alpha*D0; normalize -> packed P = [Ur|Ui] --------
__global__ __launch_bounds__(64) void finalize_kernel(
    const float* __restrict__ pr, const float* __restrict__ pi,
    const float* __restrict__ d0r, const float* __restrict__ d0i,
    float* __restrict__ P, const float* __restrict__ log_alpha) {
  int tid = threadIdx.x, bid = blockIdx.x;
  size_t idx = (size_t)bid * DK_ + tid;
  float alpha = 1.f / (1.f + __expf(-log_alpha[0]));
  float fr = pr[idx] + alpha * d0r[idx];
  float fi = pi[idx] + alpha * d0i[idx];
  float s = fr * fr + fi * fi;
  #pragma unroll
  for (int off = 32; off >= 1; off >>= 1) s += __shfl_xor(s, off, 64);
  float nrm = fmaxf(sqrtf(s), 1e-6f);
  P[(size_t)bid * 128 + tid] = fr / nrm;
  P[(size_t)bid * 128 + 64 + tid] = fi / nrm;
}

// ---------- weighted V gather (head-major V) -> attn_out (B,T,DM) -----------
__global__ __launch_bounds__(64) void attnv_kernel(
    const float* __restrict__ vh, const int* __restrict__ pidx,
    const float* __restrict__ pw, float* __restrict__ outh) {
  __shared__ int li[128];
  __shared__ float lw[128];
  int tid = threadIdx.x, bid = blockIdx.x;
  li[tid] = pidx[bid * TOPK + tid];
  li[tid + 64] = pidx[bid * TOPK + tid + 64];
  lw[tid] = pw[bid * TOPK + tid];
  lw[tid + 64] = pw[bid * TOPK + tid + 64];
  __syncthreads();
  int b = bid >> 14, h = (bid >> 10) & (H_ - 1), t = bid & (T_ - 1);
  size_t slice = (size_t)((bid >> 10) << 10) * DK_;
  float acc = 0.f;
  #pragma unroll 8
  for (int j = 0; j < 128; ++j)
    acc += lw[j] * vh[slice + (size_t)li[j] * DK_ + tid];
  outh[((size_t)(b * T_ + t)) * DM + h * DK_ + tid] = acc;
}

extern "C" void kernel_launch(void* const* d_in, const int* in_sizes, int n_in,
                              void* d_out, int out_size, void* d_ws, size_t ws_size,
                              hipStream_t stream) {
  (void)in_sizes; (void)n_in; (void)out_size; (void)ws_size;
  const float* x         = (const float*)d_in[0];
  const float* wq        = (const float*)d_in[1];
  const float* wk        = (const float*)d_in[2];
  const float* wre       = (const float*)d_in[3];
  const float* wim       = (const float*)d_in[4];
  const float* wv        = (const float*)d_in[5];
  const float* wo        = (const float*)d_in[6];
  const float* logit_lam = (const float*)d_in[7];
  const float* log_alpha = (const float*)d_in[8];

  float* out   = (float*)d_out;                 // (B,T,DM)
  float* dense = out + (size_t)B_ * T_ * DM;    // phase_attn (B,H,T,T), 128 MB
                                                // also used as score scratch

  char* ws = (char*)d_ws;
  const size_t MB8 = (size_t)8 << 20;
  float* qh  = (float*)(ws + 0 * MB8);  // head-major (B,H,T,64); reused as attn_out
  float* kh  = (float*)(ws + 1 * MB8);
  float* d0r = (float*)(ws + 2 * MB8);
  float* d0i = (float*)(ws + 3 * MB8);
  float* vh  = (float*)(ws + 4 * MB8);
  float* b1r = (float*)(ws + 5 * MB8);
  float* b1i = (float*)(ws + 6 * MB8);
  float* b2r = (float*)(ws + 7 * MB8);
  float* b2i = (float*)(ws + 8 * MB8);
  float* P   = b1r;                      // packed [Ur|Ui] (B,H,T,128) = 16 MB,
                                         // aliases b1r+b1i (dead after step 4)
  int*   aidx = (int*)(ws + 9 * MB8);    // 16 MB (adj idx, then phase idx)
  float* aw   = (float*)(ws + 11 * MB8); // 16 MB (adj w, then phase w)
  // total workspace: 104 MB

  const int rows = B_ * H_ * T_;  // 32768

  // 1. all 5 projections, head-major outputs
  proj5_kernel<<<dim3(16, 32, 5), 256, 0, stream>>>(
      x, wq, wk, wre, wim, wv, qh, kh, d0r, d0i, vh);

  // 2. adjacency scores (dense scratch in d_out) + top-k
  score_gemm_kernel<64><<<dim3(16, 16, 32), 256, 0, stream>>>(
      qh, kh, dense, 0.125f);
  topk_kernel<false><<<rows, 256, 0, stream>>>(dense, aidx, aw);

  // 3. topology propagation x4
  prop_kernel<<<rows, 128, 0, stream>>>(d0r, d0i, b1r, b1i, aidx, aw, logit_lam);
  prop_kernel<<<rows, 128, 0, stream>>>(b1r, b1i, b2r, b2i, aidx, aw, logit_lam);
  prop_kernel<<<rows, 128, 0, stream>>>(b2r, b2i, b1r, b1i, aidx, aw, logit_lam);
  prop_kernel<<<rows, 128, 0, stream>>>(b1r, b1i, b2r, b2i, aidx, aw, logit_lam);

  // 4. finalize + pack normalized U
  finalize_kernel<<<rows, 64, 0, stream>>>(b2r, b2i, d0r, d0i, P, log_alpha);

  // 5. phase scores + top-k (in-place weight writeback -> dense output)
  score_gemm_kernel<128><<<dim3(16, 16, 32), 256, 0, stream>>>(
      P, P, dense, 11.3137085f);
  topk_kernel<true><<<rows, 256, 0, stream>>>(dense, aidx, aw);

  // 6. attn . V, then output projection
  attnv_kernel<<<rows, 64, 0, stream>>>(vh, aidx, aw, qh /* attn_out */);
  gemm_nt_kernel<<<dim3(16, 32), 256, 0, stream>>>(qh, wo, out, B_ * T_, DM, DM);
}

// Round 4
// 963.463 us; speedup vs baseline: 7.3125x; 1.5215x over previous
//
#include <hip/hip_runtime.h>
#include <cstdint>
#include <cstddef>

// Problem constants
#define B_  2
#define T_  1024
#define DM  1024
#define H_  16
#define DK_ 64
#define TOPK 128

typedef unsigned short ushort_t;
typedef __attribute__((ext_vector_type(8))) short short8;
typedef __attribute__((ext_vector_type(4))) float f32x4;

// monotone map float -> uint (bigger key == bigger float)
__device__ __forceinline__ unsigned fkey(float v) {
  unsigned u = __float_as_uint(v);
  return (u & 0x80000000u) ? ~u : (u | 0x80000000u);
}

// round-to-nearest-even float -> bf16
__device__ __forceinline__ ushort_t f2bf(float f) {
  unsigned u = __float_as_uint(f);
  return (ushort_t)((u + 0x7fffu + ((u >> 16) & 1u)) >> 16);
}

// ---------- fp32 -> bf16 cast (float4 / ushort4 vectorized) -----------------
__global__ __launch_bounds__(256) void cast_bf16_kernel(
    const float* __restrict__ in, ushort_t* __restrict__ out, int n4) {
  int i = blockIdx.x * 256 + threadIdx.x;
  if (i < n4) {
    float4 v = ((const float4*)in)[i];
    ushort4 o;
    o.x = f2bf(v.x); o.y = f2bf(v.y); o.z = f2bf(v.z); o.w = f2bf(v.w);
    ((ushort4*)out)[i] = o;
  }
}

// ---------------------------------------------------------------------------
// bf16 MFMA NT GEMM core: 128x128 tile, BK=64, 4 waves (2x2), fp32 acc.
// C[n][m] = sum_k A[n][k] * B[m][k]; A,B bf16 row-major with row stride KDIM.
// LDS tiles XOR-swizzled in 16B chunks (slot = chunk ^ (row&7)) so the
// 16-lane row-sliced ds_read_b128 is at most 2-way bank-aliased (free).
// ---------------------------------------------------------------------------
template<int KDIM>
__device__ __forceinline__ void gemm_core(
    const ushort_t* __restrict__ Ab, const ushort_t* __restrict__ Bb,
    ushort_t* ldsA, ushort_t* ldsB, int tid, f32x4 acc[4][4]) {
  const int lane = tid & 63, wid = tid >> 6;
  const int wr = (wid >> 1) * 64, wc = (wid & 1) * 64;
  const int l15 = lane & 15, l4 = lane >> 4;
  for (int k0 = 0; k0 < KDIM; k0 += 64) {
    #pragma unroll
    for (int i = 0; i < 4; ++i) {
      int cid = tid + 256 * i;          // 1024 chunks of 16B per tile
      int row = cid >> 3, slot = cid & 7;
      int gc = slot ^ (row & 7);        // pre-swizzled global chunk
      *(uint4*)&ldsA[row * 64 + slot * 8] =
          *(const uint4*)&Ab[(size_t)row * KDIM + k0 + gc * 8];
      *(uint4*)&ldsB[row * 64 + slot * 8] =
          *(const uint4*)&Bb[(size_t)row * KDIM + k0 + gc * 8];
    }
    __syncthreads();
    #pragma unroll
    for (int ks = 0; ks < 2; ++ks) {
      short8 af[4], bfr[4];
      #pragma unroll
      for (int m = 0; m < 4; ++m) {
        int r = wr + m * 16 + l15;
        int c = ks * 4 + l4;
        af[m] = *(const short8*)&ldsA[r * 64 + (c ^ (r & 7)) * 8];
      }
      #pragma unroll
      for (int n = 0; n < 4; ++n) {
        int r = wc + n * 16 + l15;
        int c = ks * 4 + l4;
        bfr[n] = *(const short8*)&ldsB[r * 64 + (c ^ (r & 7)) * 8];
      }
      #pragma unroll
      for (int m = 0; m < 4; ++m)
        #pragma unroll
        for (int n = 0; n < 4; ++n)
          acc[m][n] = __builtin_amdgcn_mfma_f32_16x16x32_bf16(
              af[m], bfr[n], acc[m][n], 0, 0, 0);
    }
    __syncthreads();
  }
}

// ---------- fused 5-way projection (MFMA): out[z] = x . W[z]^T, head-major --
__global__ __launch_bounds__(256) void proj5_mfma(
    const ushort_t* __restrict__ xb, const ushort_t* __restrict__ wb,
    ushort_t* __restrict__ qh_b, ushort_t* __restrict__ kh_b,
    float* __restrict__ d0r, float* __restrict__ d0i, float* __restrict__ vh) {
  __shared__ ushort_t ldsA[128 * 64];
  __shared__ ushort_t ldsB[128 * 64];
  int tid = threadIdx.x, z = blockIdx.z;
  const ushort_t* W = wb + (size_t)z * (DM * DM);
  f32x4 acc[4][4];
  #pragma unroll
  for (int m = 0; m < 4; ++m)
    #pragma unroll
    for (int n = 0; n < 4; ++n) acc[m][n] = (f32x4){0.f, 0.f, 0.f, 0.f};
  gemm_core<DM>(xb + (size_t)blockIdx.y * 128 * DM,
                W + (size_t)blockIdx.x * 128 * DM, ldsA, ldsB, tid, acc);
  const int lane = tid & 63, wid = tid >> 6;
  int row0 = blockIdx.y * 128 + (wid >> 1) * 64 + (lane >> 4) * 4;
  int col0 = blockIdx.x * 128 + (wid & 1) * 64 + (lane & 15);
  float* fdst = (z == 2) ? d0r : (z == 3) ? d0i : vh;
  #pragma unroll
  for (int m = 0; m < 4; ++m)
    #pragma unroll
    for (int n = 0; n < 4; ++n)
      #pragma unroll
      for (int j = 0; j < 4; ++j) {
        int nr = row0 + m * 16 + j;
        int mc = col0 + n * 16;
        int b = nr >> 10, t = nr & 1023, h = mc >> 6, d = mc & 63;
        size_t o = ((size_t)((b * H_ + h) * T_ + t)) * DK_ + d;
        float v = acc[m][n][j];
        if (z == 0) qh_b[o] = f2bf(v);
        else if (z == 1) kh_b[o] = f2bf(v);
        else fdst[o] = v;
      }
}

// ---------- batched NT MFMA GEMM -> fp32 scaled dense (also out-proj) -------
template<int KDIM>
__global__ __launch_bounds__(256) void score_mfma(
    const ushort_t* __restrict__ A, const ushort_t* __restrict__ Bm,
    float* __restrict__ S, float scale) {
  __shared__ ushort_t ldsA[128 * 64];
  __shared__ ushort_t ldsB[128 * 64];
  int tid = threadIdx.x, z = blockIdx.z;
  f32x4 acc[4][4];
  #pragma unroll
  for (int m = 0; m < 4; ++m)
    #pragma unroll
    for (int n = 0; n < 4; ++n) acc[m][n] = (f32x4){0.f, 0.f, 0.f, 0.f};
  gemm_core<KDIM>(A + (size_t)z * T_ * KDIM + (size_t)blockIdx.y * 128 * KDIM,
                  Bm + (size_t)z * T_ * KDIM + (size_t)blockIdx.x * 128 * KDIM,
                  ldsA, ldsB, tid, acc);
  const int lane = tid & 63, wid = tid >> 6;
  int row0 = blockIdx.y * 128 + (wid >> 1) * 64 + (lane >> 4) * 4;
  int col0 = blockIdx.x * 128 + (wid & 1) * 64 + (lane & 15);
  float* Sz = S + (size_t)z * T_ * T_;
  #pragma unroll
  for (int m = 0; m < 4; ++m)
    #pragma unroll
    for (int n = 0; n < 4; ++n)
      #pragma unroll
      for (int j = 0; j < 4; ++j)
        Sz[(size_t)(row0 + m * 16 + j) * T_ + col0 + n * 16] =
            acc[m][n][j] * scale;
}

// ---------------------------------------------------------------------------
// Exact top-128 from a dense score row (value desc, tie -> lower index,
// matching jax.lax.top_k) + softmax over selected + compact (idx,w) write.
// If WB, writes the softmax weights back over the score row (dense output).
// ---------------------------------------------------------------------------
template<bool WB>
__global__ __launch_bounds__(256) void topk_kernel(
    float* S, int* __restrict__ idx_out, float* __restrict__ w_out) {
  __shared__ unsigned hist[4 * 257];       // per-wave, padded
  __shared__ unsigned long long eqm[4][4]; // [e-slot][wave] equality ballots
  __shared__ unsigned bc[2];
  __shared__ float redf[8];
  __shared__ unsigned redu[4];

  const int tid = threadIdx.x, bid = blockIdx.x;
  const int lane = tid & 63, wv = tid >> 6;

  float4 sv = *(const float4*)&S[(size_t)bid * 1024 + tid * 4];
  float scr[4] = {sv.x, sv.y, sv.z, sv.w};
  unsigned kf[4];
  #pragma unroll
  for (int e = 0; e < 4; ++e) kf[e] = fkey(scr[e]);

  unsigned prefix = 0, r = TOPK;
  for (int pass = 0; pass < 4; ++pass) {
    const int shift = 24 - pass * 8;
    hist[tid] = 0; hist[257 + tid] = 0; hist[514 + tid] = 0; hist[771 + tid] = 0;
    __syncthreads();
    #pragma unroll
    for (int e = 0; e < 4; ++e) {
      unsigned hi = pass ? (kf[e] >> (shift + 8)) : 0u;
      if (hi == prefix)
        atomicAdd(&hist[wv * 257 + ((kf[e] >> shift) & 255u)], 1u);
    }
    __syncthreads();
    unsigned sfx = hist[tid] + hist[257 + tid] + hist[514 + tid] + hist[771 + tid];
    #pragma unroll
    for (int off = 1; off < 64; off <<= 1) {
      unsigned o = __shfl_down(sfx, off);
      sfx += (lane + off < 64) ? o : 0u;
    }
    if (lane == 0) redu[wv] = sfx;
    __syncthreads();
    unsigned add = 0;
    #pragma unroll
    for (int ww = 1; ww < 4; ++ww) add += (ww > wv) ? redu[ww] : 0u;
    sfx += add;
    unsigned nd = __shfl_down(sfx, 1);
    unsigned nxt = (lane < 63) ? nd : add;
    if (sfx >= r && nxt < r) { bc[0] = (unsigned)tid; bc[1] = nxt; }
    __syncthreads();
    prefix = (prefix << 8) | bc[0];
    r -= bc[1];
  }
  const unsigned thrf = prefix;  // key of K-th value class; take first r equals

  // block max + equality ballots (one barrier)
  float mx = fmaxf(fmaxf(scr[0], scr[1]), fmaxf(scr[2], scr[3]));
  #pragma unroll
  for (int off = 1; off < 64; off <<= 1) mx = fmaxf(mx, __shfl_xor(mx, off));
  if (lane == 0) redf[wv] = mx;
  #pragma unroll
  for (int e = 0; e < 4; ++e) {
    unsigned long long bm = __ballot(kf[e] == thrf);
    if (lane == 0) eqm[e][wv] = bm;
  }
  __syncthreads();
  const float m = fmaxf(fmaxf(redf[0], redf[1]), fmaxf(redf[2], redf[3]));

  // tie rank ordering by s = 4*(wv*64+lane)+e  ->  lex (wv, lane, e)
  unsigned wvTot[4];
  #pragma unroll
  for (int ww = 0; ww < 4; ++ww)
    wvTot[ww] = (unsigned)(__popcll(eqm[0][ww]) + __popcll(eqm[1][ww]) +
                           __popcll(eqm[2][ww]) + __popcll(eqm[3][ww]));
  const unsigned long long below = (1ull << lane) - 1ull;
  unsigned rank_base = 0;
  #pragma unroll
  for (int ww = 0; ww < 4; ++ww) rank_base += (ww < wv) ? wvTot[ww] : 0u;
  #pragma unroll
  for (int e = 0; e < 4; ++e)
    rank_base += (unsigned)__popcll(eqm[e][wv] & below);

  bool sel[4]; float ex[4];
  unsigned cnt = 0, ownPrior = 0; float ps = 0.f;
  #pragma unroll
  for (int e = 0; e < 4; ++e) {
    bool eq = (kf[e] == thrf);
    unsigned rank = rank_base + ownPrior;
    sel[e] = (kf[e] > thrf) || (eq && rank < r);
    ex[e] = sel[e] ? __expf(scr[e] - m) : 0.f;
    ps += ex[e];
    cnt += sel[e] ? 1u : 0u;
    ownPrior += eq ? 1u : 0u;
  }
  // block sum of exp + block prefix of counts (one barrier)
  float pss = ps;
  #pragma unroll
  for (int off = 1; off < 64; off <<= 1) pss += __shfl_xor(pss, off);
  unsigned pfx = cnt;
  #pragma unroll
  for (int off = 1; off < 64; off <<= 1) {
    unsigned o = __shfl_up(pfx, off);
    pfx += (lane >= off) ? o : 0u;
  }
  if (lane == 0) redf[4 + wv] = pss;
  if (lane == 63) redu[wv] = pfx;
  __syncthreads();
  const float inv = 1.f / (redf[4] + redf[5] + redf[6] + redf[7]);
  unsigned offw = 0;
  #pragma unroll
  for (int ww = 0; ww < 4; ++ww) offw += (ww < wv) ? redu[ww] : 0u;
  unsigned pos = (unsigned)bid * TOPK + offw + pfx - cnt;
  #pragma unroll
  for (int e = 0; e < 4; ++e) {
    if (sel[e]) { idx_out[pos] = tid * 4 + e; w_out[pos] = ex[e] * inv; pos++; }
  }
  if (WB) {
    float4 w4 = make_float4(ex[0] * inv, ex[1] * inv, ex[2] * inv, ex[3] * inv);
    *(float4*)&S[(size_t)bid * 1024 + tid * 4] = w4;
  }
}

// ---------- one propagation step (head-major): D <- (1-lam)D + lam A D ------
__global__ __launch_bounds__(128) void prop_kernel(
    const float* __restrict__ srcR, const float* __restrict__ srcI,
    float* __restrict__ dstR, float* __restrict__ dstI,
    const int* __restrict__ aidx, const float* __restrict__ aw,
    const float* __restrict__ logit_lam) {
  __shared__ int li[128];
  __shared__ float lw[128];
  int tid = threadIdx.x, bid = blockIdx.x;
  li[tid] = aidx[bid * TOPK + tid];
  lw[tid] = aw[bid * TOPK + tid];
  __syncthreads();
  int half = tid >> 6, d = tid & 63;
  const float* src = half ? srcI : srcR;
  float* dst = half ? dstI : dstR;
  size_t slice = (size_t)((bid >> 10) << 10) * DK_;  // (b,h) slice start
  float acc = 0.f;
  #pragma unroll 8
  for (int j = 0; j < 128; ++j)
    acc += lw[j] * src[slice + (size_t)li[j] * DK_ + d];
  float lam = 1.f / (1.f + __expf(-logit_lam[0]));
  size_t own = (size_t)bid * DK_ + d;
  dst[own] = (1.f - lam) * src[own] + lam * acc;
}

// ---------- finalize: D += alpha*D0; normalize -> packed bf16 P = [Ur|Ui] ---
__global__ __launch_bounds__(64) void finalize_kernel(
    const float* __restrict__ pr, const float* __restrict__ pi,
    const float* __restrict__ d0r, const float* __restrict__ d0i,
    ushort_t* __restrict__ P, const float* __restrict__ log_alpha) {
  int tid = threadIdx.x, bid = blockIdx.x;
  size_t idx = (size_t)bid * DK_ + tid;
  float alpha = 1.f / (1.f + __expf(-log_alpha[0]));
  float fr = pr[idx] + alpha * d0r[idx];
  float fi = pi[idx] + alpha * d0i[idx];
  float s = fr * fr + fi * fi;
  #pragma unroll
  for (int off = 32; off >= 1; off >>= 1) s += __shfl_xor(s, off, 64);
  float nrm = fmaxf(sqrtf(s), 1e-6f);
  P[(size_t)bid * 128 + tid] = f2bf(fr / nrm);
  P[(size_t)bid * 128 + 64 + tid] = f2bf(fi / nrm);
}

// ---------- weighted V gather (head-major fp32 V) -> bf16 attn_out ----------
__global__ __launch_bounds__(64) void attnv_kernel(
    const float* __restrict__ vh, const int* __restrict__ pidx,
    const float* __restrict__ pw, ushort_t* __restrict__ outh) {
  __shared__ int li[128];
  __shared__ float lw[128];
  int tid = threadIdx.x, bid = blockIdx.x;
  li[tid] = pidx[bid * TOPK + tid];
  li[tid + 64] = pidx[bid * TOPK + tid + 64];
  lw[tid] = pw[bid * TOPK + tid];
  lw[tid + 64] = pw[bid * TOPK + tid + 64];
  __syncthreads();
  int b = bid >> 14, h = (bid >> 10) & (H_ - 1), t = bid & (T_ - 1);
  size_t slice = (size_t)((bid >> 10) << 10) * DK_;
  float acc = 0.f;
  #pragma unroll 8
  for (int j = 0; j < 128; ++j)
    acc += lw[j] * vh[slice + (size_t)li[j] * DK_ + tid];
  outh[((size_t)(b * T_ + t)) * DM + h * DK_ + tid] = f2bf(acc);
}

extern "C" void kernel_launch(void* const* d_in, const int* in_sizes, int n_in,
                              void* d_out, int out_size, void* d_ws, size_t ws_size,
                              hipStream_t stream) {
  (void)in_sizes; (void)n_in; (void)out_size; (void)ws_size;
  const float* x         = (const float*)d_in[0];
  const float* wq        = (const float*)d_in[1];
  const float* wk        = (const float*)d_in[2];
  const float* wre       = (const float*)d_in[3];
  const float* wim       = (const float*)d_in[4];
  const float* wv        = (const float*)d_in[5];
  const float* wo        = (const float*)d_in[6];
  const float* logit_lam = (const float*)d_in[7];
  const float* log_alpha = (const float*)d_in[8];

  float* out   = (float*)d_out;                 // (B,T,DM)
  float* dense = out + (size_t)B_ * T_ * DM;    // phase_attn (B,H,T,T), 128 MB
  // first 10 MB of dense doubles as bf16 weight scratch (wq..wv), dead once
  // the adjacency score GEMM overwrites it (stream-ordered after proj).
  ushort_t* w5_b = (ushort_t*)dense;

  char* ws = (char*)d_ws;
  const size_t MB = (size_t)1 << 20;
  float* d0r = (float*)(ws + 0 * MB);
  float* d0i = (float*)(ws + 8 * MB);
  float* vh  = (float*)(ws + 16 * MB);
  float* b1r = (float*)(ws + 24 * MB);   // aliased by P_b after prop is done
  float* b1i = (float*)(ws + 32 * MB);
  float* b2r = (float*)(ws + 40 * MB);
  float* b2i = (float*)(ws + 48 * MB);
  int*   aidx = (int*)(ws + 56 * MB);    // 16 MB (adj idx, then phase idx)
  float* aw   = (float*)(ws + 72 * MB);  // 16 MB (adj w, then phase w)
  ushort_t* qh_b   = (ushort_t*)(ws + 88 * MB);   // 4 MB bf16 head-major Q
  ushort_t* kh_b   = (ushort_t*)(ws + 92 * MB);   // 4 MB bf16 head-major K
  ushort_t* xb     = (ushort_t*)(ws + 96 * MB);   // 4 MB bf16 x; reused attn_b
  ushort_t* attn_b = xb;                          // alias (x dead after proj)
  ushort_t* wo_b   = (ushort_t*)(ws + 100 * MB);  // 2 MB bf16 W_O
  ushort_t* P_b    = (ushort_t*)b1r;              // 8 MB bf16 packed [Ur|Ui]
  // total workspace: 102 MB

  const int rows = B_ * H_ * T_;  // 32768

  // 0. bf16 casts
  cast_bf16_kernel<<<2048, 256, 0, stream>>>(x, xb, (B_ * T_ * DM) / 4);
  cast_bf16_kernel<<<1024, 256, 0, stream>>>(wq,  w5_b + 0 * DM * DM, DM * DM / 4);
  cast_bf16_kernel<<<1024, 256, 0, stream>>>(wk,  w5_b + 1 * (size_t)DM * DM, DM * DM / 4);
  cast_bf16_kernel<<<1024, 256, 0, stream>>>(wre, w5_b + 2 * (size_t)DM * DM, DM * DM / 4);
  cast_bf16_kernel<<<1024, 256, 0, stream>>>(wim, w5_b + 3 * (size_t)DM * DM, DM * DM / 4);
  cast_bf16_kernel<<<1024, 256, 0, stream>>>(wv,  w5_b + 4 * (size_t)DM * DM, DM * DM / 4);
  cast_bf16_kernel<<<1024, 256, 0, stream>>>(wo,  wo_b, DM * DM / 4);

  // 1. all 5 projections (MFMA), head-major outputs
  proj5_mfma<<<dim3(8, 16, 5), 256, 0, stream>>>(
      xb, w5_b, qh_b, kh_b, d0r, d0i, vh);

  // 2. adjacency scores (dense scratch in d_out) + top-k
  score_mfma<64><<<dim3(8, 8, 32), 256, 0, stream>>>(qh_b, kh_b, dense, 0.125f);
  topk_kernel<false><<<rows, 256, 0, stream>>>(dense, aidx, aw);

  // 3. topology propagation x4 (fp32)
  prop_kernel<<<rows, 128, 0, stream>>>(d0r, d0i, b1r, b1i, aidx, aw, logit_lam);
  prop_kernel<<<rows, 128, 0, stream>>>(b1r, b1i, b2r, b2i, aidx, aw, logit_lam);
  prop_kernel<<<rows, 128, 0, stream>>>(b2r, b2i, b1r, b1i, aidx, aw, logit_lam);
  prop_kernel<<<rows, 128, 0, stream>>>(b1r, b1i, b2r, b2i, aidx, aw, logit_lam);

  // 4. finalize + pack normalized U as bf16 (over dead b1r)
  finalize_kernel<<<rows, 64, 0, stream>>>(b2r, b2i, d0r, d0i, P_b, log_alpha);

  // 5. phase scores (MFMA, K=128) + top-k (weight writeback -> dense output)
  score_mfma<128><<<dim3(8, 8, 32), 256, 0, stream>>>(P_b, P_b, dense, 11.3137085f);
  topk_kernel<true><<<rows, 256, 0, stream>>>(dense, aidx, aw);

  // 6. attn . V (bf16 out), then output projection (MFMA)
  attnv_kernel<<<rows, 64, 0, stream>>>(vh, aidx, aw, attn_b);
  score_mfma<DM><<<dim3(8, 16, 1), 256, 0, stream>>>(attn_b, wo_b, out, 1.0f);
}

// Round 5
// 778.219 us; speedup vs baseline: 9.0531x; 1.2380x over previous
//
#include <hip/hip_runtime.h>
#include <cstdint>
#include <cstddef>

// Problem constants
#define B_  2
#define T_  1024
#define DM  1024
#define H_  16
#define DK_ 64
#define TOPK 128

typedef unsigned short ushort_t;
typedef __attribute__((ext_vector_type(8))) short short8;
typedef __attribute__((ext_vector_type(4))) float f32x4;

// monotone map float -> uint (bigger key == bigger float)
__device__ __forceinline__ unsigned fkey(float v) {
  unsigned u = __float_as_uint(v);
  return (u & 0x80000000u) ? ~u : (u | 0x80000000u);
}

// round-to-nearest-even float -> bf16
__device__ __forceinline__ ushort_t f2bf(float f) {
  unsigned u = __float_as_uint(f);
  return (ushort_t)((u + 0x7fffu + ((u >> 16) & 1u)) >> 16);
}

// ---------- fp32 -> bf16 cast (float4 / ushort4 vectorized) -----------------
__global__ __launch_bounds__(256) void cast_bf16_kernel(
    const float* __restrict__ in, ushort_t* __restrict__ out, int n4) {
  int i = blockIdx.x * 256 + threadIdx.x;
  if (i < n4) {
    float4 v = ((const float4*)in)[i];
    ushort4 o;
    o.x = f2bf(v.x); o.y = f2bf(v.y); o.z = f2bf(v.z); o.w = f2bf(v.w);
    ((ushort4*)out)[i] = o;
  }
}

// ---------------------------------------------------------------------------
// bf16 MFMA NT GEMM core: 128x128 tile, BK=64, 4 waves (2x2), fp32 acc.
// ---------------------------------------------------------------------------
template<int KDIM>
__device__ __forceinline__ void gemm_core(
    const ushort_t* __restrict__ Ab, const ushort_t* __restrict__ Bb,
    ushort_t* ldsA, ushort_t* ldsB, int tid, f32x4 acc[4][4]) {
  const int lane = tid & 63, wid = tid >> 6;
  const int wr = (wid >> 1) * 64, wc = (wid & 1) * 64;
  const int l15 = lane & 15, l4 = lane >> 4;
  for (int k0 = 0; k0 < KDIM; k0 += 64) {
    #pragma unroll
    for (int i = 0; i < 4; ++i) {
      int cid = tid + 256 * i;          // 1024 chunks of 16B per tile
      int row = cid >> 3, slot = cid & 7;
      int gc = slot ^ (row & 7);        // pre-swizzled global chunk
      *(uint4*)&ldsA[row * 64 + slot * 8] =
          *(const uint4*)&Ab[(size_t)row * KDIM + k0 + gc * 8];
      *(uint4*)&ldsB[row * 64 + slot * 8] =
          *(const uint4*)&Bb[(size_t)row * KDIM + k0 + gc * 8];
    }
    __syncthreads();
    #pragma unroll
    for (int ks = 0; ks < 2; ++ks) {
      short8 af[4], bfr[4];
      #pragma unroll
      for (int m = 0; m < 4; ++m) {
        int r = wr + m * 16 + l15;
        int c = ks * 4 + l4;
        af[m] = *(const short8*)&ldsA[r * 64 + (c ^ (r & 7)) * 8];
      }
      #pragma unroll
      for (int n = 0; n < 4; ++n) {
        int r = wc + n * 16 + l15;
        int c = ks * 4 + l4;
        bfr[n] = *(const short8*)&ldsB[r * 64 + (c ^ (r & 7)) * 8];
      }
      #pragma unroll
      for (int m = 0; m < 4; ++m)
        #pragma unroll
        for (int n = 0; n < 4; ++n)
          acc[m][n] = __builtin_amdgcn_mfma_f32_16x16x32_bf16(
              af[m], bfr[n], acc[m][n], 0, 0, 0);
    }
    __syncthreads();
  }
}

// ---------- fused 5-way projection (MFMA): out[z] = x . W[z]^T, head-major --
__global__ __launch_bounds__(256) void proj5_mfma(
    const ushort_t* __restrict__ xb, const ushort_t* __restrict__ wb,
    ushort_t* __restrict__ qh_b, ushort_t* __restrict__ kh_b,
    float* __restrict__ d0r, float* __restrict__ d0i, float* __restrict__ vh) {
  __shared__ ushort_t ldsA[128 * 64];
  __shared__ ushort_t ldsB[128 * 64];
  int tid = threadIdx.x, z = blockIdx.z;
  const ushort_t* W = wb + (size_t)z * (DM * DM);
  f32x4 acc[4][4];
  #pragma unroll
  for (int m = 0; m < 4; ++m)
    #pragma unroll
    for (int n = 0; n < 4; ++n) acc[m][n] = (f32x4){0.f, 0.f, 0.f, 0.f};
  gemm_core<DM>(xb + (size_t)blockIdx.y * 128 * DM,
                W + (size_t)blockIdx.x * 128 * DM, ldsA, ldsB, tid, acc);
  const int lane = tid & 63, wid = tid >> 6;
  int row0 = blockIdx.y * 128 + (wid >> 1) * 64 + (lane >> 4) * 4;
  int col0 = blockIdx.x * 128 + (wid & 1) * 64 + (lane & 15);
  float* fdst = (z == 2) ? d0r : (z == 3) ? d0i : vh;
  #pragma unroll
  for (int m = 0; m < 4; ++m)
    #pragma unroll
    for (int n = 0; n < 4; ++n)
      #pragma unroll
      for (int j = 0; j < 4; ++j) {
        int nr = row0 + m * 16 + j;
        int mc = col0 + n * 16;
        int b = nr >> 10, t = nr & 1023, h = mc >> 6, d = mc & 63;
        size_t o = ((size_t)((b * H_ + h) * T_ + t)) * DK_ + d;
        float v = acc[m][n][j];
        if (z == 0) qh_b[o] = f2bf(v);
        else if (z == 1) kh_b[o] = f2bf(v);
        else fdst[o] = v;
      }
}

// ---------- batched NT MFMA GEMM -> fp32 scaled dense (also out-proj) -------
template<int KDIM>
__global__ __launch_bounds__(256) void score_mfma(
    const ushort_t* __restrict__ A, const ushort_t* __restrict__ Bm,
    float* __restrict__ S, float scale) {
  __shared__ ushort_t ldsA[128 * 64];
  __shared__ ushort_t ldsB[128 * 64];
  int tid = threadIdx.x, z = blockIdx.z;
  f32x4 acc[4][4];
  #pragma unroll
  for (int m = 0; m < 4; ++m)
    #pragma unroll
    for (int n = 0; n < 4; ++n) acc[m][n] = (f32x4){0.f, 0.f, 0.f, 0.f};
  gemm_core<KDIM>(A + (size_t)z * T_ * KDIM + (size_t)blockIdx.y * 128 * KDIM,
                  Bm + (size_t)z * T_ * KDIM + (size_t)blockIdx.x * 128 * KDIM,
                  ldsA, ldsB, tid, acc);
  const int lane = tid & 63, wid = tid >> 6;
  int row0 = blockIdx.y * 128 + (wid >> 1) * 64 + (lane >> 4) * 4;
  int col0 = blockIdx.x * 128 + (wid & 1) * 64 + (lane & 15);
  float* Sz = S + (size_t)z * T_ * T_;
  #pragma unroll
  for (int m = 0; m < 4; ++m)
    #pragma unroll
    for (int n = 0; n < 4; ++n)
      #pragma unroll
      for (int j = 0; j < 4; ++j)
        Sz[(size_t)(row0 + m * 16 + j) * T_ + col0 + n * 16] =
            acc[m][n][j] * scale;
}

// ---------------------------------------------------------------------------
// Wave-synchronous exact top-128: one WAVE per row, 4 rows per block, zero
// __syncthreads(). Lane holds 16 scores: s = g*256 + lane*4 + e (g,e in 0..3).
// 4x8-bit radix on the float key with wave-private parity-split histograms;
// tie -> lower index resolved by per-(g,e) ballots in (g,lane,e) lex order
// (bit-exact vs jax.lax.top_k). Softmax over selected; compact (idx,w) write.
// If WB, writes softmax weights back over the score row (dense output).
// ---------------------------------------------------------------------------
#define WAVE_FENCE() asm volatile("s_waitcnt lgkmcnt(0)" ::: "memory")

template<bool WB>
__global__ __launch_bounds__(256) void topk_kernel(
    float* S, int* __restrict__ idx_out, float* __restrict__ w_out) {
  __shared__ unsigned hist[4][2][260];  // per-wave, parity-split, padded

  const int tid = threadIdx.x;
  const int lane = tid & 63, wv = tid >> 6;
  const int row = blockIdx.x * 4 + wv;
  float* Srow = S + (size_t)row * 1024;

  float scr[4][4];
  unsigned kf[4][4];
  #pragma unroll
  for (int g = 0; g < 4; ++g) {
    float4 v = *(const float4*)&Srow[g * 256 + lane * 4];
    scr[g][0] = v.x; scr[g][1] = v.y; scr[g][2] = v.z; scr[g][3] = v.w;
    #pragma unroll
    for (int e = 0; e < 4; ++e) kf[g][e] = fkey(scr[g][e]);
  }

  const uint4 zero4 = make_uint4(0, 0, 0, 0);
  unsigned prefix = 0, r = TOPK;
  #pragma unroll
  for (int pass = 0; pass < 4; ++pass) {
    const int shift = 24 - pass * 8;
    *(uint4*)&hist[wv][0][lane * 4] = zero4;
    *(uint4*)&hist[wv][1][lane * 4] = zero4;
    WAVE_FENCE();
    #pragma unroll
    for (int g = 0; g < 4; ++g)
      #pragma unroll
      for (int e = 0; e < 4; ++e) {
        unsigned hi = pass ? (kf[g][e] >> (shift + 8)) : 0u;
        if (hi == prefix)
          atomicAdd(&hist[wv][e & 1][(kf[g][e] >> shift) & 255u], 1u);
      }
    WAVE_FENCE();
    uint4 c0 = *(const uint4*)&hist[wv][0][lane * 4];
    uint4 c1 = *(const uint4*)&hist[wv][1][lane * 4];
    unsigned c[4] = {c0.x + c1.x, c0.y + c1.y, c0.z + c1.z, c0.w + c1.w};
    // in-lane suffix sums over the lane's 4 bins
    unsigned s3 = c[3], s2 = c[2] + s3, s1 = c[1] + s2, s0 = c[0] + s1;
    // cross-lane suffix over lane totals
    unsigned acc = s0;
    #pragma unroll
    for (int off = 1; off < 64; off <<= 1) {
      unsigned t = __shfl_down(acc, off);
      acc += (lane + off < 64) ? t : 0u;
    }
    unsigned hsum = acc - s0;  // sum of totals of higher lanes
    unsigned sfx[4] = {s0 + hsum, s1 + hsum, s2 + hsum, s3 + hsum};
    unsigned nxt[4] = {sfx[1], sfx[2], sfx[3], hsum};
    bool has = false; unsigned binc = 0, nxtc = 0;
    #pragma unroll
    for (int i = 0; i < 4; ++i)
      if (sfx[i] >= r && nxt[i] < r) { has = true; binc = lane * 4 + i; nxtc = nxt[i]; }
    unsigned long long fm = __ballot(has);
    int src = __ffsll((long long)fm) - 1;
    unsigned bin = __shfl(binc, src);
    unsigned nx  = __shfl(nxtc, src);
    prefix = (prefix << 8) | bin;
    r -= nx;
  }
  const unsigned thr = prefix;  // key of K-th value class; take first r equals

  // wave max for softmax
  float mx = -3.402823466e38f;
  #pragma unroll
  for (int g = 0; g < 4; ++g)
    #pragma unroll
    for (int e = 0; e < 4; ++e) mx = fmaxf(mx, scr[g][e]);
  #pragma unroll
  for (int off = 1; off < 64; off <<= 1) mx = fmaxf(mx, __shfl_xor(mx, off));

  // selection with exact (g,lane,e) lex tie-ranking; accumulate exp-sum
  const unsigned long long below = (1ull << lane) - 1ull;
  unsigned selm = 0, cnt = 0, cum = 0;
  float ps = 0.f;
  #pragma unroll
  for (int g = 0; g < 4; ++g) {
    unsigned long long bal[4];
    #pragma unroll
    for (int e = 0; e < 4; ++e) bal[e] = __ballot(kf[g][e] == thr);
    unsigned rb = cum;
    #pragma unroll
    for (int e = 0; e < 4; ++e) rb += (unsigned)__popcll(bal[e] & below);
    unsigned ownPrior = 0;
    #pragma unroll
    for (int e = 0; e < 4; ++e) {
      bool eq = (kf[g][e] == thr);
      bool sel = (kf[g][e] > thr) || (eq && (rb + ownPrior) < r);
      ownPrior += eq ? 1u : 0u;
      if (sel) {
        selm |= 1u << (g * 4 + e);
        ps += __expf(scr[g][e] - mx);
        cnt++;
      }
    }
    #pragma unroll
    for (int e = 0; e < 4; ++e) cum += (unsigned)__popcll(bal[e]);
  }
  // wave sum of exp + wave prefix of counts
  float pss = ps;
  #pragma unroll
  for (int off = 1; off < 64; off <<= 1) pss += __shfl_xor(pss, off);
  unsigned pfx = cnt;
  #pragma unroll
  for (int off = 1; off < 64; off <<= 1) {
    unsigned o = __shfl_up(pfx, off);
    pfx += (lane >= off) ? o : 0u;
  }
  const float inv = 1.f / pss;
  unsigned pos = (unsigned)row * TOPK + pfx - cnt;
  #pragma unroll
  for (int g = 0; g < 4; ++g)
    #pragma unroll
    for (int e = 0; e < 4; ++e) {
      bool sel = (selm >> (g * 4 + e)) & 1u;
      float w = sel ? __expf(scr[g][e] - mx) * inv : 0.f;
      scr[g][e] = w;
      if (sel) { idx_out[pos] = g * 256 + lane * 4 + e; w_out[pos] = w; pos++; }
    }
  if (WB) {
    #pragma unroll
    for (int g = 0; g < 4; ++g)
      *(float4*)&Srow[g * 256 + lane * 4] =
          make_float4(scr[g][0], scr[g][1], scr[g][2], scr[g][3]);
  }
}

// ---------- one propagation step (head-major): D <- (1-lam)D + lam A D ------
__global__ __launch_bounds__(128) void prop_kernel(
    const float* __restrict__ srcR, const float* __restrict__ srcI,
    float* __restrict__ dstR, float* __restrict__ dstI,
    const int* __restrict__ aidx, const float* __restrict__ aw,
    const float* __restrict__ logit_lam) {
  __shared__ int li[128];
  __shared__ float lw[128];
  int tid = threadIdx.x, bid = blockIdx.x;
  li[tid] = aidx[bid * TOPK + tid];
  lw[tid] = aw[bid * TOPK + tid];
  __syncthreads();
  int half = tid >> 6, d = tid & 63;
  const float* src = half ? srcI : srcR;
  float* dst = half ? dstI : dstR;
  size_t slice = (size_t)((bid >> 10) << 10) * DK_;  // (b,h) slice start
  float acc = 0.f;
  #pragma unroll 8
  for (int j = 0; j < 128; ++j)
    acc += lw[j] * src[slice + (size_t)li[j] * DK_ + d];
  float lam = 1.f / (1.f + __expf(-logit_lam[0]));
  size_t own = (size_t)bid * DK_ + d;
  dst[own] = (1.f - lam) * src[own] + lam * acc;
}

// ---------- finalize: D += alpha*D0; normalize -> packed bf16 P = [Ur|Ui] ---
__global__ __launch_bounds__(64) void finalize_kernel(
    const float* __restrict__ pr, const float* __restrict__ pi,
    const float* __restrict__ d0r, const float* __restrict__ d0i,
    ushort_t* __restrict__ P, const float* __restrict__ log_alpha) {
  int tid = threadIdx.x, bid = blockIdx.x;
  size_t idx = (size_t)bid * DK_ + tid;
  float alpha = 1.f / (1.f + __expf(-log_alpha[0]));
  float fr = pr[idx] + alpha * d0r[idx];
  float fi = pi[idx] + alpha * d0i[idx];
  float s = fr * fr + fi * fi;
  #pragma unroll
  for (int off = 32; off >= 1; off >>= 1) s += __shfl_xor(s, off, 64);
  float nrm = fmaxf(sqrtf(s), 1e-6f);
  P[(size_t)bid * 128 + tid] = f2bf(fr / nrm);
  P[(size_t)bid * 128 + 64 + tid] = f2bf(fi / nrm);
}

// ---------- weighted V gather (head-major fp32 V) -> bf16 attn_out ----------
__global__ __launch_bounds__(64) void attnv_kernel(
    const float* __restrict__ vh, const int* __restrict__ pidx,
    const float* __restrict__ pw, ushort_t* __restrict__ outh) {
  __shared__ int li[128];
  __shared__ float lw[128];
  int tid = threadIdx.x, bid = blockIdx.x;
  li[tid] = pidx[bid * TOPK + tid];
  li[tid + 64] = pidx[bid * TOPK + tid + 64];
  lw[tid] = pw[bid * TOPK + tid];
  lw[tid + 64] = pw[bid * TOPK + tid + 64];
  __syncthreads();
  int b = bid >> 14, h = (bid >> 10) & (H_ - 1), t = bid & (T_ - 1);
  size_t slice = (size_t)((bid >> 10) << 10) * DK_;
  float acc = 0.f;
  #pragma unroll 8
  for (int j = 0; j < 128; ++j)
    acc += lw[j] * vh[slice + (size_t)li[j] * DK_ + tid];
  outh[((size_t)(b * T_ + t)) * DM + h * DK_ + tid] = f2bf(acc);
}

extern "C" void kernel_launch(void* const* d_in, const int* in_sizes, int n_in,
                              void* d_out, int out_size, void* d_ws, size_t ws_size,
                              hipStream_t stream) {
  (void)in_sizes; (void)n_in; (void)out_size; (void)ws_size;
  const float* x         = (const float*)d_in[0];
  const float* wq        = (const float*)d_in[1];
  const float* wk        = (const float*)d_in[2];
  const float* wre       = (const float*)d_in[3];
  const float* wim       = (const float*)d_in[4];
  const float* wv        = (const float*)d_in[5];
  const float* wo        = (const float*)d_in[6];
  const float* logit_lam = (const float*)d_in[7];
  const float* log_alpha = (const float*)d_in[8];

  float* out   = (float*)d_out;                 // (B,T,DM)
  float* dense = out + (size_t)B_ * T_ * DM;    // phase_attn (B,H,T,T), 128 MB
  // first 10 MB of dense doubles as bf16 weight scratch (wq..wv), dead once
  // the adjacency score GEMM overwrites it (stream-ordered after proj).
  ushort_t* w5_b = (ushort_t*)dense;

  char* ws = (char*)d_ws;
  const size_t MB = (size_t)1 << 20;
  float* d0r = (float*)(ws + 0 * MB);
  float* d0i = (float*)(ws + 8 * MB);
  float* vh  = (float*)(ws + 16 * MB);
  float* b1r = (float*)(ws + 24 * MB);   // aliased by P_b after prop is done
  float* b1i = (float*)(ws + 32 * MB);
  float* b2r = (float*)(ws + 40 * MB);
  float* b2i = (float*)(ws + 48 * MB);
  int*   aidx = (int*)(ws + 56 * MB);    // 16 MB (adj idx, then phase idx)
  float* aw   = (float*)(ws + 72 * MB);  // 16 MB (adj w, then phase w)
  ushort_t* qh_b   = (ushort_t*)(ws + 88 * MB);   // 4 MB bf16 head-major Q
  ushort_t* kh_b   = (ushort_t*)(ws + 92 * MB);   // 4 MB bf16 head-major K
  ushort_t* xb     = (ushort_t*)(ws + 96 * MB);   // 4 MB bf16 x; reused attn_b
  ushort_t* attn_b = xb;                          // alias (x dead after proj)
  ushort_t* wo_b   = (ushort_t*)(ws + 100 * MB);  // 2 MB bf16 W_O
  ushort_t* P_b    = (ushort_t*)b1r;              // 8 MB bf16 packed [Ur|Ui]
  // total workspace: 102 MB

  const int rows = B_ * H_ * T_;  // 32768

  // 0. bf16 casts
  cast_bf16_kernel<<<2048, 256, 0, stream>>>(x, xb, (B_ * T_ * DM) / 4);
  cast_bf16_kernel<<<1024, 256, 0, stream>>>(wq,  w5_b + 0 * DM * DM, DM * DM / 4);
  cast_bf16_kernel<<<1024, 256, 0, stream>>>(wk,  w5_b + 1 * (size_t)DM * DM, DM * DM / 4);
  cast_bf16_kernel<<<1024, 256, 0, stream>>>(wre, w5_b + 2 * (size_t)DM * DM, DM * DM / 4);
  cast_bf16_kernel<<<1024, 256, 0, stream>>>(wim, w5_b + 3 * (size_t)DM * DM, DM * DM / 4);
  cast_bf16_kernel<<<1024, 256, 0, stream>>>(wv,  w5_b + 4 * (size_t)DM * DM, DM * DM / 4);
  cast_bf16_kernel<<<1024, 256, 0, stream>>>(wo,  wo_b, DM * DM / 4);

  // 1. all 5 projections (MFMA), head-major outputs
  proj5_mfma<<<dim3(8, 16, 5), 256, 0, stream>>>(
      xb, w5_b, qh_b, kh_b, d0r, d0i, vh);

  // 2. adjacency scores (dense scratch in d_out) + top-k (wave-sync)
  score_mfma<64><<<dim3(8, 8, 32), 256, 0, stream>>>(qh_b, kh_b, dense, 0.125f);
  topk_kernel<false><<<rows / 4, 256, 0, stream>>>(dense, aidx, aw);

  // 3. topology propagation x4 (fp32)
  prop_kernel<<<rows, 128, 0, stream>>>(d0r, d0i, b1r, b1i, aidx, aw, logit_lam);
  prop_kernel<<<rows, 128, 0, stream>>>(b1r, b1i, b2r, b2i, aidx, aw, logit_lam);
  prop_kernel<<<rows, 128, 0, stream>>>(b2r, b2i, b1r, b1i, aidx, aw, logit_lam);
  prop_kernel<<<rows, 128, 0, stream>>>(b1r, b1i, b2r, b2i, aidx, aw, logit_lam);

  // 4. finalize + pack normalized U as bf16 (over dead b1r)
  finalize_kernel<<<rows, 64, 0, stream>>>(b2r, b2i, d0r, d0i, P_b, log_alpha);

  // 5. phase scores (MFMA, K=128) + top-k (weight writeback -> dense output)
  score_mfma<128><<<dim3(8, 8, 32), 256, 0, stream>>>(P_b, P_b, dense, 11.3137085f);
  topk_kernel<true><<<rows / 4, 256, 0, stream>>>(dense, aidx, aw);

  // 6. attn . V (bf16 out), then output projection (MFMA)
  attnv_kernel<<<rows, 64, 0, stream>>>(vh, aidx, aw, attn_b);
  score_mfma<DM><<<dim3(8, 16, 1), 256, 0, stream>>>(attn_b, wo_b, out, 1.0f);
}

// Round 6
// 486.127 us; speedup vs baseline: 14.4927x; 1.6009x over previous
//
#include <hip/hip_runtime.h>
#include <cstdint>
#include <cstddef>

// Problem constants
#define B_  2
#define T_  1024
#define DM  1024
#define H_  16
#define DK_ 64
#define TOPK 128

typedef unsigned short ushort_t;
typedef __attribute__((ext_vector_type(8))) short short8;
typedef __attribute__((ext_vector_type(4))) float f32x4;

// monotone map float -> uint (bigger key == bigger float)
__device__ __forceinline__ unsigned fkey(float v) {
  unsigned u = __float_as_uint(v);
  return (u & 0x80000000u) ? ~u : (u | 0x80000000u);
}

// round-to-nearest-even float -> bf16
__device__ __forceinline__ ushort_t f2bf(float f) {
  unsigned u = __float_as_uint(f);
  return (ushort_t)((u + 0x7fffu + ((u >> 16) & 1u)) >> 16);
}
__device__ __forceinline__ float bf2f(ushort_t u) {
  return __uint_as_float((unsigned)u << 16);
}

// ---------- fp32 -> bf16 cast (float4 / ushort4 vectorized) -----------------
__global__ __launch_bounds__(256) void cast_bf16_kernel(
    const float* __restrict__ in, ushort_t* __restrict__ out, int n4) {
  int i = blockIdx.x * 256 + threadIdx.x;
  if (i < n4) {
    float4 v = ((const float4*)in)[i];
    ushort4 o;
    o.x = f2bf(v.x); o.y = f2bf(v.y); o.z = f2bf(v.z); o.w = f2bf(v.w);
    ((ushort4*)out)[i] = o;
  }
}

// ---------------------------------------------------------------------------
// bf16 MFMA NT GEMM core: 128x128 tile, BK=64, 4 waves (2x2), fp32 acc.
// C[n][m] = sum_k A[n][k]*B[m][k]; A,B bf16 row-major, row stride KDIM.
// ---------------------------------------------------------------------------
template<int KDIM>
__device__ __forceinline__ void gemm_core(
    const ushort_t* __restrict__ Ab, const ushort_t* __restrict__ Bb,
    ushort_t* ldsA, ushort_t* ldsB, int tid, f32x4 acc[4][4]) {
  const int lane = tid & 63, wid = tid >> 6;
  const int wr = (wid >> 1) * 64, wc = (wid & 1) * 64;
  const int l15 = lane & 15, l4 = lane >> 4;
  for (int k0 = 0; k0 < KDIM; k0 += 64) {
    #pragma unroll
    for (int i = 0; i < 4; ++i) {
      int cid = tid + 256 * i;          // 1024 chunks of 16B per tile
      int row = cid >> 3, slot = cid & 7;
      int gc = slot ^ (row & 7);        // pre-swizzled global chunk
      *(uint4*)&ldsA[row * 64 + slot * 8] =
          *(const uint4*)&Ab[(size_t)row * KDIM + k0 + gc * 8];
      *(uint4*)&ldsB[row * 64 + slot * 8] =
          *(const uint4*)&Bb[(size_t)row * KDIM + k0 + gc * 8];
    }
    __syncthreads();
    #pragma unroll
    for (int ks = 0; ks < 2; ++ks) {
      short8 af[4], bfr[4];
      #pragma unroll
      for (int m = 0; m < 4; ++m) {
        int r = wr + m * 16 + l15;
        int c = ks * 4 + l4;
        af[m] = *(const short8*)&ldsA[r * 64 + (c ^ (r & 7)) * 8];
      }
      #pragma unroll
      for (int n = 0; n < 4; ++n) {
        int r = wc + n * 16 + l15;
        int c = ks * 4 + l4;
        bfr[n] = *(const short8*)&ldsB[r * 64 + (c ^ (r & 7)) * 8];
      }
      #pragma unroll
      for (int m = 0; m < 4; ++m)
        #pragma unroll
        for (int n = 0; n < 4; ++n)
          acc[m][n] = __builtin_amdgcn_mfma_f32_16x16x32_bf16(
              af[m], bfr[n], acc[m][n], 0, 0, 0);
    }
    __syncthreads();
  }
}

// ---------- fused 5-way projection (MFMA): out[z] = x . W[z]^T ---------------
// z=0,1,4 -> head-major bf16 (Q,K,V); z=2,3 -> packed-transposed bf16 D0:
// Dt0[head][dd][t] with dd=d (re) or 64+d (im).
__global__ __launch_bounds__(256) void proj5_mfma(
    const ushort_t* __restrict__ xb, const ushort_t* __restrict__ wb,
    ushort_t* __restrict__ qh_b, ushort_t* __restrict__ kh_b,
    ushort_t* __restrict__ dt0, ushort_t* __restrict__ vh_b) {
  __shared__ ushort_t ldsA[128 * 64];
  __shared__ ushort_t ldsB[128 * 64];
  int tid = threadIdx.x, z = blockIdx.z;
  const ushort_t* W = wb + (size_t)z * (DM * DM);
  f32x4 acc[4][4];
  #pragma unroll
  for (int m = 0; m < 4; ++m)
    #pragma unroll
    for (int n = 0; n < 4; ++n) acc[m][n] = (f32x4){0.f, 0.f, 0.f, 0.f};
  gemm_core<DM>(xb + (size_t)blockIdx.y * 128 * DM,
                W + (size_t)blockIdx.x * 128 * DM, ldsA, ldsB, tid, acc);
  const int lane = tid & 63, wid = tid >> 6;
  int row0 = blockIdx.y * 128 + (wid >> 1) * 64 + (lane >> 4) * 4;
  int col0 = blockIdx.x * 128 + (wid & 1) * 64 + (lane & 15);
  if (z == 2 || z == 3) {
    int ddofs = (z == 3) ? 64 : 0;
    #pragma unroll
    for (int m = 0; m < 4; ++m)
      #pragma unroll
      for (int n = 0; n < 4; ++n)
        #pragma unroll
        for (int j = 0; j < 4; ++j) {
          int nr = row0 + m * 16 + j;
          int mc = col0 + n * 16;
          int b = nr >> 10, t = nr & 1023, h = mc >> 6, d = mc & 63;
          size_t o = ((size_t)(b * H_ + h)) * 131072 +
                     (size_t)(d + ddofs) * 1024 + t;
          dt0[o] = f2bf(acc[m][n][j]);
        }
  } else {
    ushort_t* O = (z == 0) ? qh_b : (z == 1) ? kh_b : vh_b;
    #pragma unroll
    for (int m = 0; m < 4; ++m)
      #pragma unroll
      for (int n = 0; n < 4; ++n)
        #pragma unroll
        for (int j = 0; j < 4; ++j) {
          int nr = row0 + m * 16 + j;
          int mc = col0 + n * 16;
          int b = nr >> 10, t = nr & 1023, h = mc >> 6, d = mc & 63;
          size_t o = ((size_t)((b * H_ + h) * T_ + t)) * DK_ + d;
          O[o] = f2bf(acc[m][n][j]);
        }
  }
}

// ---------- batched NT MFMA GEMM -> fp32 scaled dense (also out-proj) -------
template<int KDIM>
__global__ __launch_bounds__(256) void score_mfma(
    const ushort_t* __restrict__ A, const ushort_t* __restrict__ Bm,
    float* __restrict__ S, float scale) {
  __shared__ ushort_t ldsA[128 * 64];
  __shared__ ushort_t ldsB[128 * 64];
  int tid = threadIdx.x, z = blockIdx.z;
  f32x4 acc[4][4];
  #pragma unroll
  for (int m = 0; m < 4; ++m)
    #pragma unroll
    for (int n = 0; n < 4; ++n) acc[m][n] = (f32x4){0.f, 0.f, 0.f, 0.f};
  gemm_core<KDIM>(A + (size_t)z * T_ * KDIM + (size_t)blockIdx.y * 128 * KDIM,
                  Bm + (size_t)z * T_ * KDIM + (size_t)blockIdx.x * 128 * KDIM,
                  ldsA, ldsB, tid, acc);
  const int lane = tid & 63, wid = tid >> 6;
  int row0 = blockIdx.y * 128 + (wid >> 1) * 64 + (lane >> 4) * 4;
  int col0 = blockIdx.x * 128 + (wid & 1) * 64 + (lane & 15);
  float* Sz = S + (size_t)z * T_ * T_;
  #pragma unroll
  for (int m = 0; m < 4; ++m)
    #pragma unroll
    for (int n = 0; n < 4; ++n)
      #pragma unroll
      for (int j = 0; j < 4; ++j)
        Sz[(size_t)(row0 + m * 16 + j) * T_ + col0 + n * 16] =
            acc[m][n][j] * scale;
}

// ---------- propagation step as MFMA GEMM (per head) -------------------------
// Dt layout: [head][128 dd][1024 t] bf16. Computes for tile t0..t0+127:
// acc[t][dd] = sum_s A[t][s]*Dt[dd][s]; Dnew[dd][t] = (1-lam)Dold[dd][t]+lam*acc
__global__ __launch_bounds__(256) void prop_mfma(
    const ushort_t* __restrict__ Ab, const ushort_t* __restrict__ Dsrc,
    ushort_t* __restrict__ Ddst, const float* __restrict__ logit_lam) {
  __shared__ ushort_t ldsA[128 * 64];
  __shared__ ushort_t ldsB[128 * 64];
  int tid = threadIdx.x, hz = blockIdx.y;
  f32x4 acc[4][4];
  #pragma unroll
  for (int m = 0; m < 4; ++m)
    #pragma unroll
    for (int n = 0; n < 4; ++n) acc[m][n] = (f32x4){0.f, 0.f, 0.f, 0.f};
  const ushort_t* Dh = Dsrc + (size_t)hz * 131072;
  gemm_core<1024>(Ab + (size_t)hz * 1048576 + (size_t)blockIdx.x * 128 * 1024,
                  Dh, ldsA, ldsB, tid, acc);
  float lam = 1.f / (1.f + __expf(-logit_lam[0]));
  const int lane = tid & 63, wid = tid >> 6;
  int row0 = blockIdx.x * 128 + (wid >> 1) * 64 + (lane >> 4) * 4;  // t
  int col0 = (wid & 1) * 64 + (lane & 15);                          // dd
  ushort_t* Dd = Ddst + (size_t)hz * 131072;
  #pragma unroll
  for (int m = 0; m < 4; ++m)
    #pragma unroll
    for (int n = 0; n < 4; ++n)
      #pragma unroll
      for (int j = 0; j < 4; ++j) {
        int t = row0 + m * 16 + j;
        int dd = col0 + n * 16;
        size_t o = (size_t)dd * 1024 + t;
        float oldv = bf2f(Dh[o]);
        Dd[o] = f2bf((1.f - lam) * oldv + lam * acc[m][n][j]);
      }
}

// ---------------------------------------------------------------------------
// Wave-synchronous exact top-128 (tie -> lower index, matches jax.lax.top_k),
// softmax over selected. One wave per row, zero __syncthreads().
// MODE 0: compact (idx,w) + fp32 dense writeback (phase).
// MODE 1: bf16 dense weight matrix only (adjacency).
// ---------------------------------------------------------------------------
#define WAVE_FENCE() asm volatile("s_waitcnt lgkmcnt(0)" ::: "memory")

template<int MODE>
__global__ __launch_bounds__(256) void topk_kernel(
    float* S, int* __restrict__ idx_out, float* __restrict__ w_out,
    ushort_t* __restrict__ Ab) {
  __shared__ unsigned hist[4][2][260];  // per-wave, parity-split, padded

  const int tid = threadIdx.x;
  const int lane = tid & 63, wv = tid >> 6;
  const int row = blockIdx.x * 4 + wv;
  float* Srow = S + (size_t)row * 1024;

  float scr[4][4];
  unsigned kf[4][4];
  #pragma unroll
  for (int g = 0; g < 4; ++g) {
    float4 v = *(const float4*)&Srow[g * 256 + lane * 4];
    scr[g][0] = v.x; scr[g][1] = v.y; scr[g][2] = v.z; scr[g][3] = v.w;
    #pragma unroll
    for (int e = 0; e < 4; ++e) kf[g][e] = fkey(scr[g][e]);
  }

  const uint4 zero4 = make_uint4(0, 0, 0, 0);
  unsigned prefix = 0, r = TOPK;
  #pragma unroll
  for (int pass = 0; pass < 4; ++pass) {
    const int shift = 24 - pass * 8;
    *(uint4*)&hist[wv][0][lane * 4] = zero4;
    *(uint4*)&hist[wv][1][lane * 4] = zero4;
    WAVE_FENCE();
    #pragma unroll
    for (int g = 0; g < 4; ++g)
      #pragma unroll
      for (int e = 0; e < 4; ++e) {
        unsigned hi = pass ? (kf[g][e] >> (shift + 8)) : 0u;
        if (hi == prefix)
          atomicAdd(&hist[wv][e & 1][(kf[g][e] >> shift) & 255u], 1u);
      }
    WAVE_FENCE();
    uint4 c0 = *(const uint4*)&hist[wv][0][lane * 4];
    uint4 c1 = *(const uint4*)&hist[wv][1][lane * 4];
    unsigned c[4] = {c0.x + c1.x, c0.y + c1.y, c0.z + c1.z, c0.w + c1.w};
    unsigned s3 = c[3], s2 = c[2] + s3, s1 = c[1] + s2, s0 = c[0] + s1;
    unsigned acc = s0;
    #pragma unroll
    for (int off = 1; off < 64; off <<= 1) {
      unsigned t = __shfl_down(acc, off);
      acc += (lane + off < 64) ? t : 0u;
    }
    unsigned hsum = acc - s0;  // sum of totals of higher lanes
    unsigned sfx[4] = {s0 + hsum, s1 + hsum, s2 + hsum, s3 + hsum};
    unsigned nxt[4] = {sfx[1], sfx[2], sfx[3], hsum};
    bool has = false; unsigned binc = 0, nxtc = 0;
    #pragma unroll
    for (int i = 0; i < 4; ++i)
      if (sfx[i] >= r && nxt[i] < r) { has = true; binc = lane * 4 + i; nxtc = nxt[i]; }
    unsigned long long fm = __ballot(has);
    int src = __ffsll((long long)fm) - 1;
    unsigned bin = __shfl(binc, src);
    unsigned nx  = __shfl(nxtc, src);
    prefix = (prefix << 8) | bin;
    r -= nx;
  }
  const unsigned thr = prefix;

  float mx = -3.402823466e38f;
  #pragma unroll
  for (int g = 0; g < 4; ++g)
    #pragma unroll
    for (int e = 0; e < 4; ++e) mx = fmaxf(mx, scr[g][e]);
  #pragma unroll
  for (int off = 1; off < 64; off <<= 1) mx = fmaxf(mx, __shfl_xor(mx, off));

  const unsigned long long below = (1ull << lane) - 1ull;
  unsigned selm = 0, cnt = 0, cum = 0;
  float ps = 0.f;
  #pragma unroll
  for (int g = 0; g < 4; ++g) {
    unsigned long long bal[4];
    #pragma unroll
    for (int e = 0; e < 4; ++e) bal[e] = __ballot(kf[g][e] == thr);
    unsigned rb = cum;
    #pragma unroll
    for (int e = 0; e < 4; ++e) rb += (unsigned)__popcll(bal[e] & below);
    unsigned ownPrior = 0;
    #pragma unroll
    for (int e = 0; e < 4; ++e) {
      bool eq = (kf[g][e] == thr);
      bool sel = (kf[g][e] > thr) || (eq && (rb + ownPrior) < r);
      ownPrior += eq ? 1u : 0u;
      if (sel) {
        selm |= 1u << (g * 4 + e);
        ps += __expf(scr[g][e] - mx);
        cnt++;
      }
    }
    #pragma unroll
    for (int e = 0; e < 4; ++e) cum += (unsigned)__popcll(bal[e]);
  }
  float pss = ps;
  #pragma unroll
  for (int off = 1; off < 64; off <<= 1) pss += __shfl_xor(pss, off);
  const float inv = 1.f / pss;

  if (MODE == 0) {
    unsigned pfx = cnt;
    #pragma unroll
    for (int off = 1; off < 64; off <<= 1) {
      unsigned o = __shfl_up(pfx, off);
      pfx += (lane >= off) ? o : 0u;
    }
    unsigned pos = (unsigned)row * TOPK + pfx - cnt;
    #pragma unroll
    for (int g = 0; g < 4; ++g)
      #pragma unroll
      for (int e = 0; e < 4; ++e) {
        bool sel = (selm >> (g * 4 + e)) & 1u;
        float w = sel ? __expf(scr[g][e] - mx) * inv : 0.f;
        scr[g][e] = w;
        if (sel) { idx_out[pos] = g * 256 + lane * 4 + e; w_out[pos] = w; pos++; }
      }
    #pragma unroll
    for (int g = 0; g < 4; ++g)
      *(float4*)&Srow[g * 256 + lane * 4] =
          make_float4(scr[g][0], scr[g][1], scr[g][2], scr[g][3]);
  } else {
    #pragma unroll
    for (int g = 0; g < 4; ++g) {
      ushort4 o;
      float w0 = ((selm >> (g * 4 + 0)) & 1u) ? __expf(scr[g][0] - mx) * inv : 0.f;
      float w1 = ((selm >> (g * 4 + 1)) & 1u) ? __expf(scr[g][1] - mx) * inv : 0.f;
      float w2 = ((selm >> (g * 4 + 2)) & 1u) ? __expf(scr[g][2] - mx) * inv : 0.f;
      float w3 = ((selm >> (g * 4 + 3)) & 1u) ? __expf(scr[g][3] - mx) * inv : 0.f;
      o.x = f2bf(w0); o.y = f2bf(w1); o.z = f2bf(w2); o.w = f2bf(w3);
      *(ushort4*)&Ab[(size_t)row * 1024 + g * 256 + lane * 4] = o;
    }
  }
}

// ---------- finalize: D += alpha*D0 (Dt layout); normalize -> P=[Ur|Ui] -----
// Tile-transpose per (head, 64-t chunk): Dt [128 dd][64 t] -> P [64 t][128 dd]
__global__ __launch_bounds__(256) void finalize_kernel(
    const ushort_t* __restrict__ Dt, const ushort_t* __restrict__ Dt0,
    ushort_t* __restrict__ P, const float* __restrict__ log_alpha) {
  __shared__ float lds[64][129];
  __shared__ float red[4][64];
  __shared__ float nrmi[64];
  int tid = threadIdx.x;
  int hz = blockIdx.y;
  int t0 = blockIdx.x * 64;
  size_t base = (size_t)hz * 131072 + t0;
  float alpha = 1.f / (1.f + __expf(-log_alpha[0]));
  #pragma unroll
  for (int i = 0; i < 32; ++i) {
    int eid = tid + i * 256;
    int dd = eid >> 6, t = eid & 63;
    size_t o = base + (size_t)dd * 1024 + t;
    lds[t][dd] = bf2f(Dt[o]) + alpha * bf2f(Dt0[o]);
  }
  __syncthreads();
  int t = tid & 63, q = tid >> 6;
  float s = 0.f;
  #pragma unroll
  for (int k = 0; k < 32; ++k) {
    float v = lds[t][q * 32 + k];
    s += v * v;
  }
  red[q][t] = s;
  __syncthreads();
  if (tid < 64) {
    float tot = red[0][tid] + red[1][tid] + red[2][tid] + red[3][tid];
    nrmi[tid] = 1.f / fmaxf(sqrtf(tot), 1e-6f);
  }
  __syncthreads();
  #pragma unroll
  for (int i = 0; i < 32; ++i) {
    int eid = tid + i * 256;
    int dd = eid & 127, tt = eid >> 7;
    P[((size_t)hz * 1024 + t0 + tt) * 128 + dd] = f2bf(lds[tt][dd] * nrmi[tt]);
  }
}

// ---------- weighted V gather (head-major bf16 V) -> bf16 attn_out ----------
__global__ __launch_bounds__(64) void attnv_kernel(
    const ushort_t* __restrict__ vh, const int* __restrict__ pidx,
    const float* __restrict__ pw, ushort_t* __restrict__ outh) {
  __shared__ int li[128];
  __shared__ float lw[128];
  int tid = threadIdx.x, bid = blockIdx.x;
  li[tid] = pidx[bid * TOPK + tid];
  li[tid + 64] = pidx[bid * TOPK + tid + 64];
  lw[tid] = pw[bid * TOPK + tid];
  lw[tid + 64] = pw[bid * TOPK + tid + 64];
  __syncthreads();
  int b = bid >> 14, h = (bid >> 10) & (H_ - 1), t = bid & (T_ - 1);
  size_t slice = (size_t)((bid >> 10) << 10) * DK_;
  float acc = 0.f;
  #pragma unroll 8
  for (int j = 0; j < 128; ++j)
    acc += lw[j] * bf2f(vh[slice + (size_t)li[j] * DK_ + tid]);
  outh[((size_t)(b * T_ + t)) * DM + h * DK_ + tid] = f2bf(acc);
}

extern "C" void kernel_launch(void* const* d_in, const int* in_sizes, int n_in,
                              void* d_out, int out_size, void* d_ws, size_t ws_size,
                              hipStream_t stream) {
  (void)in_sizes; (void)n_in; (void)out_size; (void)ws_size;
  const float* x         = (const float*)d_in[0];
  const float* wq        = (const float*)d_in[1];
  const float* wk        = (const float*)d_in[2];
  const float* wre       = (const float*)d_in[3];
  const float* wim       = (const float*)d_in[4];
  const float* wv        = (const float*)d_in[5];
  const float* wo        = (const float*)d_in[6];
  const float* logit_lam = (const float*)d_in[7];
  const float* log_alpha = (const float*)d_in[8];

  float* out   = (float*)d_out;                 // (B,T,DM)
  float* dense = out + (size_t)B_ * T_ * DM;    // phase_attn (B,H,T,T), 128 MB
  // first 10 MB of dense doubles as bf16 weight scratch (wq..wv), dead once
  // the adjacency score GEMM overwrites it (stream-ordered after proj).
  ushort_t* w5_b = (ushort_t*)dense;

  char* ws = (char*)d_ws;
  const size_t MB = (size_t)1 << 20;
  // A region (64 MB), dead after the 4 prop steps; then overlaid:
  ushort_t* A_b  = (ushort_t*)(ws + 0 * MB);     // 64 MB dense bf16 adjacency
  ushort_t* P_b  = (ushort_t*)(ws + 0 * MB);     // 8 MB packed [Ur|Ui] bf16
  int*      pidx = (int*)(ws + 8 * MB);          // 16 MB phase idx
  float*    pw   = (float*)(ws + 24 * MB);       // 16 MB phase w
  ushort_t* wo_b = (ushort_t*)(ws + 40 * MB);    // 2 MB bf16 W_O (cast late!)
  // persistent region:
  ushort_t* dt0  = (ushort_t*)(ws + 64 * MB);    // 8 MB Dt0 [32][128][1024]
  ushort_t* dtA  = (ushort_t*)(ws + 72 * MB);    // 8 MB ping
  ushort_t* dtB  = (ushort_t*)(ws + 80 * MB);    // 8 MB pong
  ushort_t* vh_b = (ushort_t*)(ws + 88 * MB);    // 4 MB bf16 head-major V
  ushort_t* xb   = (ushort_t*)(ws + 92 * MB);    // 4 MB bf16 x; reused attn_b
  ushort_t* attn_b = xb;                         // alias (x dead after proj)
  ushort_t* qh_b = (ushort_t*)(ws + 96 * MB);    // 4 MB bf16 head-major Q
  ushort_t* kh_b = (ushort_t*)(ws + 100 * MB);   // 4 MB bf16 head-major K
  // total workspace: 104 MB

  const int rows = B_ * H_ * T_;  // 32768

  // 0. bf16 casts (W_O deferred until A region is dead)
  cast_bf16_kernel<<<2048, 256, 0, stream>>>(x, xb, (B_ * T_ * DM) / 4);
  cast_bf16_kernel<<<1024, 256, 0, stream>>>(wq,  w5_b + 0 * DM * DM, DM * DM / 4);
  cast_bf16_kernel<<<1024, 256, 0, stream>>>(wk,  w5_b + 1 * (size_t)DM * DM, DM * DM / 4);
  cast_bf16_kernel<<<1024, 256, 0, stream>>>(wre, w5_b + 2 * (size_t)DM * DM, DM * DM / 4);
  cast_bf16_kernel<<<1024, 256, 0, stream>>>(wim, w5_b + 3 * (size_t)DM * DM, DM * DM / 4);
  cast_bf16_kernel<<<1024, 256, 0, stream>>>(wv,  w5_b + 4 * (size_t)DM * DM, DM * DM / 4);

  // 1. all 5 projections (MFMA)
  proj5_mfma<<<dim3(8, 16, 5), 256, 0, stream>>>(
      xb, w5_b, qh_b, kh_b, dt0, vh_b);

  // 2. adjacency scores + top-k -> dense bf16 A
  score_mfma<64><<<dim3(8, 8, 32), 256, 0, stream>>>(qh_b, kh_b, dense, 0.125f);
  topk_kernel<1><<<rows / 4, 256, 0, stream>>>(dense, nullptr, nullptr, A_b);

  // 3. topology propagation x4 as batched MFMA GEMM
  prop_mfma<<<dim3(8, 32), 256, 0, stream>>>(A_b, dt0, dtA, logit_lam);
  prop_mfma<<<dim3(8, 32), 256, 0, stream>>>(A_b, dtA, dtB, logit_lam);
  prop_mfma<<<dim3(8, 32), 256, 0, stream>>>(A_b, dtB, dtA, logit_lam);
  prop_mfma<<<dim3(8, 32), 256, 0, stream>>>(A_b, dtA, dtB, logit_lam);

  // A region dead -> cast W_O into it
  cast_bf16_kernel<<<1024, 256, 0, stream>>>(wo, wo_b, DM * DM / 4);

  // 4. finalize (+alpha*D0, normalize, transpose) -> P_b
  finalize_kernel<<<dim3(16, 32), 256, 0, stream>>>(dtB, dt0, P_b, log_alpha);

  // 5. phase scores (K=128) + top-k (fp32 WB -> dense output, compact lists)
  score_mfma<128><<<dim3(8, 8, 32), 256, 0, stream>>>(P_b, P_b, dense, 11.3137085f);
  topk_kernel<0><<<rows / 4, 256, 0, stream>>>(dense, pidx, pw, nullptr);

  // 6. attn . V (bf16 out), then output projection (MFMA)
  attnv_kernel<<<rows, 64, 0, stream>>>(vh_b, pidx, pw, attn_b);
  score_mfma<DM><<<dim3(8, 16, 1), 256, 0, stream>>>(attn_b, wo_b, out, 1.0f);
}

// Round 7
// 434.769 us; speedup vs baseline: 16.2047x; 1.1181x over previous
//
#include <hip/hip_runtime.h>
#include <cstdint>
#include <cstddef>

// Problem constants
#define B_  2
#define T_  1024
#define DM  1024
#define H_  16
#define DK_ 64
#define TOPK 128

typedef unsigned short ushort_t;
typedef __attribute__((ext_vector_type(8))) short short8;
typedef __attribute__((ext_vector_type(8))) unsigned short u16x8;
typedef __attribute__((ext_vector_type(4))) float f32x4;

// monotone map bf16 bits -> u16 (bigger key == bigger float)
__device__ __forceinline__ unsigned fkey16(unsigned b) {
  return (b & 0x8000u) ? (0xffffu & ~b) : (b | 0x8000u);
}

// round-to-nearest-even float -> bf16
__device__ __forceinline__ ushort_t f2bf(float f) {
  unsigned u = __float_as_uint(f);
  return (ushort_t)((u + 0x7fffu + ((u >> 16) & 1u)) >> 16);
}
__device__ __forceinline__ float bf2f(ushort_t u) {
  return __uint_as_float((unsigned)u << 16);
}

// ---------- fp32 -> bf16 cast (float4 / ushort4 vectorized) -----------------
__global__ __launch_bounds__(256) void cast_bf16_kernel(
    const float* __restrict__ in, ushort_t* __restrict__ out, int n4) {
  int i = blockIdx.x * 256 + threadIdx.x;
  if (i < n4) {
    float4 v = ((const float4*)in)[i];
    ushort4 o;
    o.x = f2bf(v.x); o.y = f2bf(v.y); o.z = f2bf(v.z); o.w = f2bf(v.w);
    ((ushort4*)out)[i] = o;
  }
}

// ---------------------------------------------------------------------------
// bf16 MFMA NT GEMM core: 128x128 tile, BK=64, 4 waves (2x2), fp32 acc.
// C[n][m] = sum_k A[n][k]*B[m][k]; A,B bf16 row-major, row stride KDIM.
// ---------------------------------------------------------------------------
template<int KDIM>
__device__ __forceinline__ void gemm_core(
    const ushort_t* __restrict__ Ab, const ushort_t* __restrict__ Bb,
    ushort_t* ldsA, ushort_t* ldsB, int tid, f32x4 acc[4][4]) {
  const int lane = tid & 63, wid = tid >> 6;
  const int wr = (wid >> 1) * 64, wc = (wid & 1) * 64;
  const int l15 = lane & 15, l4 = lane >> 4;
  for (int k0 = 0; k0 < KDIM; k0 += 64) {
    #pragma unroll
    for (int i = 0; i < 4; ++i) {
      int cid = tid + 256 * i;          // 1024 chunks of 16B per tile
      int row = cid >> 3, slot = cid & 7;
      int gc = slot ^ (row & 7);        // pre-swizzled global chunk
      *(uint4*)&ldsA[row * 64 + slot * 8] =
          *(const uint4*)&Ab[(size_t)row * KDIM + k0 + gc * 8];
      *(uint4*)&ldsB[row * 64 + slot * 8] =
          *(const uint4*)&Bb[(size_t)row * KDIM + k0 + gc * 8];
    }
    __syncthreads();
    #pragma unroll
    for (int ks = 0; ks < 2; ++ks) {
      short8 af[4], bfr[4];
      #pragma unroll
      for (int m = 0; m < 4; ++m) {
        int r = wr + m * 16 + l15;
        int c = ks * 4 + l4;
        af[m] = *(const short8*)&ldsA[r * 64 + (c ^ (r & 7)) * 8];
      }
      #pragma unroll
      for (int n = 0; n < 4; ++n) {
        int r = wc + n * 16 + l15;
        int c = ks * 4 + l4;
        bfr[n] = *(const short8*)&ldsB[r * 64 + (c ^ (r & 7)) * 8];
      }
      #pragma unroll
      for (int m = 0; m < 4; ++m)
        #pragma unroll
        for (int n = 0; n < 4; ++n)
          acc[m][n] = __builtin_amdgcn_mfma_f32_16x16x32_bf16(
              af[m], bfr[n], acc[m][n], 0, 0, 0);
    }
    __syncthreads();
  }
}

// ---------- fused 5-way projection (MFMA): out[z] = x . W[z]^T ---------------
// z=0,1 -> head-major bf16 (Q,K); z=2,3 -> packed-transposed D0
// Dt0[head][dd][t]; z=4 -> transposed V: Vt[head][d][t].
__global__ __launch_bounds__(256) void proj5_mfma(
    const ushort_t* __restrict__ xb, const ushort_t* __restrict__ wb,
    ushort_t* __restrict__ qh_b, ushort_t* __restrict__ kh_b,
    ushort_t* __restrict__ dt0, ushort_t* __restrict__ vt_b) {
  __shared__ ushort_t ldsA[128 * 64];
  __shared__ ushort_t ldsB[128 * 64];
  int tid = threadIdx.x, z = blockIdx.z;
  const ushort_t* W = wb + (size_t)z * (DM * DM);
  f32x4 acc[4][4];
  #pragma unroll
  for (int m = 0; m < 4; ++m)
    #pragma unroll
    for (int n = 0; n < 4; ++n) acc[m][n] = (f32x4){0.f, 0.f, 0.f, 0.f};
  gemm_core<DM>(xb + (size_t)blockIdx.y * 128 * DM,
                W + (size_t)blockIdx.x * 128 * DM, ldsA, ldsB, tid, acc);
  const int lane = tid & 63, wid = tid >> 6;
  int row0 = blockIdx.y * 128 + (wid >> 1) * 64 + (lane >> 4) * 4;
  int col0 = blockIdx.x * 128 + (wid & 1) * 64 + (lane & 15);
  #pragma unroll
  for (int m = 0; m < 4; ++m)
    #pragma unroll
    for (int n = 0; n < 4; ++n)
      #pragma unroll
      for (int j = 0; j < 4; ++j) {
        int nr = row0 + m * 16 + j;
        int mc = col0 + n * 16;
        int b = nr >> 10, t = nr & 1023, h = mc >> 6, d = mc & 63;
        int head = b * H_ + h;
        float v = acc[m][n][j];
        if (z == 0) {
          qh_b[((size_t)head * T_ + t) * DK_ + d] = f2bf(v);
        } else if (z == 1) {
          kh_b[((size_t)head * T_ + t) * DK_ + d] = f2bf(v);
        } else if (z == 4) {
          vt_b[(size_t)head * 65536 + (size_t)d * 1024 + t] = f2bf(v);
        } else {
          int ddofs = (z == 3) ? 64 : 0;
          dt0[(size_t)head * 131072 + (size_t)(d + ddofs) * 1024 + t] = f2bf(v);
        }
      }
}

// ---------- batched NT MFMA GEMM -> scaled dense (bf16 or fp32 out) ---------
template<int KDIM, bool BF16OUT>
__global__ __launch_bounds__(256) void score_mfma(
    const ushort_t* __restrict__ A, const ushort_t* __restrict__ Bm,
    void* __restrict__ Sout, float scale) {
  __shared__ ushort_t ldsA[128 * 64];
  __shared__ ushort_t ldsB[128 * 64];
  int tid = threadIdx.x, z = blockIdx.z;
  f32x4 acc[4][4];
  #pragma unroll
  for (int m = 0; m < 4; ++m)
    #pragma unroll
    for (int n = 0; n < 4; ++n) acc[m][n] = (f32x4){0.f, 0.f, 0.f, 0.f};
  gemm_core<KDIM>(A + (size_t)z * T_ * KDIM + (size_t)blockIdx.y * 128 * KDIM,
                  Bm + (size_t)z * T_ * KDIM + (size_t)blockIdx.x * 128 * KDIM,
                  ldsA, ldsB, tid, acc);
  const int lane = tid & 63, wid = tid >> 6;
  int row0 = blockIdx.y * 128 + (wid >> 1) * 64 + (lane >> 4) * 4;
  int col0 = blockIdx.x * 128 + (wid & 1) * 64 + (lane & 15);
  if (BF16OUT) {
    ushort_t* Sz = (ushort_t*)Sout + (size_t)z * T_ * T_;
    #pragma unroll
    for (int m = 0; m < 4; ++m)
      #pragma unroll
      for (int n = 0; n < 4; ++n)
        #pragma unroll
        for (int j = 0; j < 4; ++j)
          Sz[(size_t)(row0 + m * 16 + j) * T_ + col0 + n * 16] =
              f2bf(acc[m][n][j] * scale);
  } else {
    float* Sz = (float*)Sout + (size_t)z * T_ * T_;
    #pragma unroll
    for (int m = 0; m < 4; ++m)
      #pragma unroll
      for (int n = 0; n < 4; ++n)
        #pragma unroll
        for (int j = 0; j < 4; ++j)
          Sz[(size_t)(row0 + m * 16 + j) * T_ + col0 + n * 16] =
              acc[m][n][j] * scale;
  }
}

// ---------- propagation step as MFMA GEMM (per head) -------------------------
__global__ __launch_bounds__(256) void prop_mfma(
    const ushort_t* __restrict__ Ab, const ushort_t* __restrict__ Dsrc,
    ushort_t* __restrict__ Ddst, const float* __restrict__ logit_lam) {
  __shared__ ushort_t ldsA[128 * 64];
  __shared__ ushort_t ldsB[128 * 64];
  int tid = threadIdx.x, hz = blockIdx.y;
  f32x4 acc[4][4];
  #pragma unroll
  for (int m = 0; m < 4; ++m)
    #pragma unroll
    for (int n = 0; n < 4; ++n) acc[m][n] = (f32x4){0.f, 0.f, 0.f, 0.f};
  const ushort_t* Dh = Dsrc + (size_t)hz * 131072;
  gemm_core<1024>(Ab + (size_t)hz * 1048576 + (size_t)blockIdx.x * 128 * 1024,
                  Dh, ldsA, ldsB, tid, acc);
  float lam = 1.f / (1.f + __expf(-logit_lam[0]));
  const int lane = tid & 63, wid = tid >> 6;
  int row0 = blockIdx.x * 128 + (wid >> 1) * 64 + (lane >> 4) * 4;  // t
  int col0 = (wid & 1) * 64 + (lane & 15);                          // dd
  ushort_t* Dd = Ddst + (size_t)hz * 131072;
  #pragma unroll
  for (int m = 0; m < 4; ++m)
    #pragma unroll
    for (int n = 0; n < 4; ++n)
      #pragma unroll
      for (int j = 0; j < 4; ++j) {
        int t = row0 + m * 16 + j;
        int dd = col0 + n * 16;
        size_t o = (size_t)dd * 1024 + t;
        float oldv = bf2f(Dh[o]);
        Dd[o] = f2bf((1.f - lam) * oldv + lam * acc[m][n][j]);
      }
}

// ---------------------------------------------------------------------------
// Wave-synchronous exact top-128 on bf16 scores (16-bit keys, 2 radix passes,
// tie -> lower index, matches jax.lax.top_k applied to these scores), softmax
// over selected. One wave per row, zero __syncthreads().
// MODE 0: fp32 dense weight write (phase output). MODE 1: bf16 in-place WB.
// ---------------------------------------------------------------------------
#define WAVE_FENCE() asm volatile("s_waitcnt lgkmcnt(0)" ::: "memory")

template<int MODE>
__global__ __launch_bounds__(256) void topk16_kernel(
    ushort_t* __restrict__ Sb, float* __restrict__ denseOut) {
  __shared__ unsigned hist[4][4][264];  // per-wave, 4-way split, padded

  const int tid = threadIdx.x;
  const int lane = tid & 63, wv = tid >> 6;
  const int row = blockIdx.x * 4 + wv;
  ushort_t* Srow = Sb + (size_t)row * 1024;

  float scr[2][8];
  unsigned kk[2][8];
  #pragma unroll
  for (int g = 0; g < 2; ++g) {
    u16x8 v = *(const u16x8*)&Srow[g * 512 + lane * 8];
    #pragma unroll
    for (int e = 0; e < 8; ++e) {
      scr[g][e] = bf2f(v[e]);
      kk[g][e] = fkey16((unsigned)v[e]);
    }
  }

  const uint4 zero4 = make_uint4(0, 0, 0, 0);
  unsigned prefix = 0, r = TOPK;
  #pragma unroll
  for (int pass = 0; pass < 2; ++pass) {
    *(uint4*)&hist[wv][0][lane * 4] = zero4;
    *(uint4*)&hist[wv][1][lane * 4] = zero4;
    *(uint4*)&hist[wv][2][lane * 4] = zero4;
    *(uint4*)&hist[wv][3][lane * 4] = zero4;
    WAVE_FENCE();
    #pragma unroll
    for (int g = 0; g < 2; ++g)
      #pragma unroll
      for (int e = 0; e < 8; ++e) {
        unsigned key = kk[g][e];
        if (pass == 0)
          atomicAdd(&hist[wv][e & 3][key >> 8], 1u);
        else if ((key >> 8) == prefix)
          atomicAdd(&hist[wv][e & 3][key & 255u], 1u);
      }
    WAVE_FENCE();
    uint4 c0 = *(const uint4*)&hist[wv][0][lane * 4];
    uint4 c1 = *(const uint4*)&hist[wv][1][lane * 4];
    uint4 c2 = *(const uint4*)&hist[wv][2][lane * 4];
    uint4 c3 = *(const uint4*)&hist[wv][3][lane * 4];
    unsigned c[4] = {c0.x + c1.x + c2.x + c3.x, c0.y + c1.y + c2.y + c3.y,
                     c0.z + c1.z + c2.z + c3.z, c0.w + c1.w + c2.w + c3.w};
    unsigned s3 = c[3], s2 = c[2] + s3, s1 = c[1] + s2, s0 = c[0] + s1;
    unsigned acc = s0;
    #pragma unroll
    for (int off = 1; off < 64; off <<= 1) {
      unsigned t = __shfl_down(acc, off);
      acc += (lane + off < 64) ? t : 0u;
    }
    unsigned hsum = acc - s0;  // sum of totals of higher lanes
    unsigned sfx[4] = {s0 + hsum, s1 + hsum, s2 + hsum, s3 + hsum};
    unsigned nxt[4] = {sfx[1], sfx[2], sfx[3], hsum};
    bool has = false; unsigned binc = 0, nxtc = 0;
    #pragma unroll
    for (int i = 0; i < 4; ++i)
      if (sfx[i] >= r && nxt[i] < r) { has = true; binc = lane * 4 + i; nxtc = nxt[i]; }
    unsigned long long fm = __ballot(has);
    int src = __ffsll((long long)fm) - 1;
    unsigned bin = __shfl(binc, src);
    unsigned nx  = __shfl(nxtc, src);
    prefix = (prefix << 8) | bin;
    r -= nx;
  }
  const unsigned thr = prefix;  // 16-bit key of K-th class; take first r equals

  // wave max for softmax
  float mx = -3.402823466e38f;
  #pragma unroll
  for (int g = 0; g < 2; ++g)
    #pragma unroll
    for (int e = 0; e < 8; ++e) mx = fmaxf(mx, scr[g][e]);
  #pragma unroll
  for (int off = 1; off < 64; off <<= 1) mx = fmaxf(mx, __shfl_xor(mx, off));

  // selection with exact (g,lane,e) lex tie-ranking (s = g*512+lane*8+e)
  const unsigned long long below = (1ull << lane) - 1ull;
  unsigned cum = 0;
  float w[2][8];
  float ps = 0.f;
  #pragma unroll
  for (int g = 0; g < 2; ++g) {
    unsigned long long bal[8];
    #pragma unroll
    for (int e = 0; e < 8; ++e) bal[e] = __ballot(kk[g][e] == thr);
    unsigned rb = cum;
    #pragma unroll
    for (int e = 0; e < 8; ++e) rb += (unsigned)__popcll(bal[e] & below);
    unsigned ownPrior = 0;
    #pragma unroll
    for (int e = 0; e < 8; ++e) {
      bool eq = (kk[g][e] == thr);
      bool sel = (kk[g][e] > thr) || (eq && (rb + ownPrior) < r);
      ownPrior += eq ? 1u : 0u;
      float ex = sel ? __expf(scr[g][e] - mx) : 0.f;
      w[g][e] = ex;
      ps += ex;
    }
    #pragma unroll
    for (int e = 0; e < 8; ++e) cum += (unsigned)__popcll(bal[e]);
  }
  float pss = ps;
  #pragma unroll
  for (int off = 1; off < 64; off <<= 1) pss += __shfl_xor(pss, off);
  const float inv = 1.f / pss;

  if (MODE == 0) {
    float* Drow = denseOut + (size_t)row * 1024;
    #pragma unroll
    for (int g = 0; g < 2; ++g) {
      *(float4*)&Drow[g * 512 + lane * 8] =
          make_float4(w[g][0] * inv, w[g][1] * inv, w[g][2] * inv, w[g][3] * inv);
      *(float4*)&Drow[g * 512 + lane * 8 + 4] =
          make_float4(w[g][4] * inv, w[g][5] * inv, w[g][6] * inv, w[g][7] * inv);
    }
  } else {
    #pragma unroll
    for (int g = 0; g < 2; ++g) {
      u16x8 o;
      #pragma unroll
      for (int e = 0; e < 8; ++e) o[e] = f2bf(w[g][e] * inv);
      *(u16x8*)&Srow[g * 512 + lane * 8] = o;
    }
  }
}

// ---------- finalize: D += alpha*D0 (Dt layout); normalize -> P=[Ur|Ui] -----
__global__ __launch_bounds__(256) void finalize_kernel(
    const ushort_t* __restrict__ Dt, const ushort_t* __restrict__ Dt0,
    ushort_t* __restrict__ P, const float* __restrict__ log_alpha) {
  __shared__ float lds[64][129];
  __shared__ float red[4][64];
  __shared__ float nrmi[64];
  int tid = threadIdx.x;
  int hz = blockIdx.y;
  int t0 = blockIdx.x * 64;
  size_t base = (size_t)hz * 131072 + t0;
  float alpha = 1.f / (1.f + __expf(-log_alpha[0]));
  #pragma unroll
  for (int i = 0; i < 32; ++i) {
    int eid = tid + i * 256;
    int dd = eid >> 6, t = eid & 63;
    size_t o = base + (size_t)dd * 1024 + t;
    lds[t][dd] = bf2f(Dt[o]) + alpha * bf2f(Dt0[o]);
  }
  __syncthreads();
  int t = tid & 63, q = tid >> 6;
  float s = 0.f;
  #pragma unroll
  for (int k = 0; k < 32; ++k) {
    float v = lds[t][q * 32 + k];
    s += v * v;
  }
  red[q][t] = s;
  __syncthreads();
  if (tid < 64) {
    float tot = red[0][tid] + red[1][tid] + red[2][tid] + red[3][tid];
    nrmi[tid] = 1.f / fmaxf(sqrtf(tot), 1e-6f);
  }
  __syncthreads();
  #pragma unroll
  for (int i = 0; i < 32; ++i) {
    int eid = tid + i * 256;
    int dd = eid & 127, tt = eid >> 7;
    P[((size_t)hz * 1024 + t0 + tt) * 128 + dd] = f2bf(lds[tt][dd] * nrmi[tt]);
  }
}

// ---------- attn.V as MFMA: C[t][d] = sum_s W[t][s]*Vt[d][s] per head --------
// W is fp32 dense (just-written phase_attn, L2/L3 resident); staged to bf16.
__global__ __launch_bounds__(256) void attnv_mfma(
    const float* __restrict__ Wf, const ushort_t* __restrict__ Vt,
    ushort_t* __restrict__ attn_b) {
  __shared__ ushort_t ldsA[128 * 64];  // 16 KB
  __shared__ ushort_t ldsB[64 * 64];   // 8 KB
  int tid = threadIdx.x, hz = blockIdx.y;
  const int lane = tid & 63, wid = tid >> 6;
  const int l15 = lane & 15, l4 = lane >> 4;
  const float* Wh = Wf + (size_t)hz * 1048576 + (size_t)blockIdx.x * 128 * 1024;
  const ushort_t* Vh = Vt + (size_t)hz * 65536;
  f32x4 acc[2][4];
  #pragma unroll
  for (int m = 0; m < 2; ++m)
    #pragma unroll
    for (int n = 0; n < 4; ++n) acc[m][n] = (f32x4){0.f, 0.f, 0.f, 0.f};
  for (int k0 = 0; k0 < 1024; k0 += 64) {
    #pragma unroll
    for (int i = 0; i < 8; ++i) {       // A: 2048 fp32-16B chunks -> bf16
      int cid = tid + 256 * i;
      int row = cid >> 4, c4 = cid & 15;
      float4 v = *(const float4*)&Wh[(size_t)row * 1024 + k0 + c4 * 4];
      int c = c4 >> 1, half = c4 & 1;
      ushort4 o;
      o.x = f2bf(v.x); o.y = f2bf(v.y); o.z = f2bf(v.z); o.w = f2bf(v.w);
      *(ushort4*)&ldsA[row * 64 + (c ^ (row & 7)) * 8 + half * 4] = o;
    }
    #pragma unroll
    for (int i = 0; i < 2; ++i) {       // B: 512 bf16-16B chunks
      int cid = tid + 256 * i;
      int row = cid >> 3, slot = cid & 7;
      int gc = slot ^ (row & 7);
      *(uint4*)&ldsB[row * 64 + slot * 8] =
          *(const uint4*)&Vh[(size_t)row * 1024 + k0 + gc * 8];
    }
    __syncthreads();
    #pragma unroll
    for (int ks = 0; ks < 2; ++ks) {
      short8 af[2], bfr[4];
      #pragma unroll
      for (int m = 0; m < 2; ++m) {
        int rr = wid * 32 + m * 16 + l15;
        int c = ks * 4 + l4;
        af[m] = *(const short8*)&ldsA[rr * 64 + (c ^ (rr & 7)) * 8];
      }
      #pragma unroll
      for (int n = 0; n < 4; ++n) {
        int rr = n * 16 + l15;
        int c = ks * 4 + l4;
        bfr[n] = *(const short8*)&ldsB[rr * 64 + (c ^ (rr & 7)) * 8];
      }
      #pragma unroll
      for (int m = 0; m < 2; ++m)
        #pragma unroll
        for (int n = 0; n < 4; ++n)
          acc[m][n] = __builtin_amdgcn_mfma_f32_16x16x32_bf16(
              af[m], bfr[n], acc[m][n], 0, 0, 0);
    }
    __syncthreads();
  }
  int b = hz >> 4, h = hz & 15;
  #pragma unroll
  for (int m = 0; m < 2; ++m)
    #pragma unroll
    for (int n = 0; n < 4; ++n)
      #pragma unroll
      for (int j = 0; j < 4; ++j) {
        int t = blockIdx.x * 128 + wid * 32 + m * 16 + l4 * 4 + j;
        int d = n * 16 + l15;
        attn_b[((size_t)(b * T_ + t)) * DM + h * DK_ + d] = f2bf(acc[m][n][j]);
      }
}

extern "C" void kernel_launch(void* const* d_in, const int* in_sizes, int n_in,
                              void* d_out, int out_size, void* d_ws, size_t ws_size,
                              hipStream_t stream) {
  (void)in_sizes; (void)n_in; (void)out_size; (void)ws_size;
  const float* x         = (const float*)d_in[0];
  const float* wq        = (const float*)d_in[1];
  const float* wk        = (const float*)d_in[2];
  const float* wre       = (const float*)d_in[3];
  const float* wim       = (const float*)d_in[4];
  const float* wv        = (const float*)d_in[5];
  const float* wo        = (const float*)d_in[6];
  const float* logit_lam = (const float*)d_in[7];
  const float* log_alpha = (const float*)d_in[8];

  float* out   = (float*)d_out;                 // (B,T,DM)
  float* dense = out + (size_t)B_ * T_ * DM;    // phase_attn (B,H,T,T) fp32 out
  // first 10 MB of dense doubles as bf16 weight scratch (wq..wv); dead after
  // proj5 and long before topk16<0> writes the dense region (stream-ordered).
  ushort_t* w5_b = (ushort_t*)dense;

  char* ws = (char*)d_ws;
  const size_t MB = (size_t)1 << 20;
  // 0-64 MB: adjacency bf16 scores -> in-place weights (prop input);
  //          later reused for phase bf16 scores.
  ushort_t* A_b  = (ushort_t*)(ws + 0 * MB);
  ushort_t* S2_b = A_b;                          // phase scores (A dead)
  ushort_t* dt0  = (ushort_t*)(ws + 64 * MB);    // 8 MB Dt0 [32][128][1024]
  ushort_t* dtA  = (ushort_t*)(ws + 72 * MB);    // 8 MB ping; P_b after prop
  ushort_t* P_b  = dtA;                          // packed [Ur|Ui] bf16
  ushort_t* dtB  = (ushort_t*)(ws + 80 * MB);    // 8 MB pong (final D)
  ushort_t* vt_b = (ushort_t*)(ws + 88 * MB);    // 4 MB Vt [32][64][1024]
  ushort_t* xb   = (ushort_t*)(ws + 92 * MB);    // 4 MB bf16 x; reused attn_b
  ushort_t* attn_b = xb;                         // alias (x dead after proj)
  ushort_t* qh_b = (ushort_t*)(ws + 96 * MB);    // 4 MB bf16 Q; wo_b after adj
  ushort_t* wo_b = qh_b;                         // alias (Q dead after scores)
  ushort_t* kh_b = (ushort_t*)(ws + 100 * MB);   // 4 MB bf16 K
  // total workspace: 104 MB

  const int rows = B_ * H_ * T_;  // 32768

  // 0. bf16 casts (W_O deferred until Q is dead)
  cast_bf16_kernel<<<2048, 256, 0, stream>>>(x, xb, (B_ * T_ * DM) / 4);
  cast_bf16_kernel<<<1024, 256, 0, stream>>>(wq,  w5_b + 0 * DM * DM, DM * DM / 4);
  cast_bf16_kernel<<<1024, 256, 0, stream>>>(wk,  w5_b + 1 * (size_t)DM * DM, DM * DM / 4);
  cast_bf16_kernel<<<1024, 256, 0, stream>>>(wre, w5_b + 2 * (size_t)DM * DM, DM * DM / 4);
  cast_bf16_kernel<<<1024, 256, 0, stream>>>(wim, w5_b + 3 * (size_t)DM * DM, DM * DM / 4);
  cast_bf16_kernel<<<1024, 256, 0, stream>>>(wv,  w5_b + 4 * (size_t)DM * DM, DM * DM / 4);

  // 1. all 5 projections (MFMA)
  proj5_mfma<<<dim3(8, 16, 5), 256, 0, stream>>>(
      xb, w5_b, qh_b, kh_b, dt0, vt_b);

  // 2. adjacency scores (bf16 -> A_b) + top-k (in-place bf16 weights)
  score_mfma<64, true><<<dim3(8, 8, 32), 256, 0, stream>>>(
      qh_b, kh_b, A_b, 0.125f);
  cast_bf16_kernel<<<1024, 256, 0, stream>>>(wo, wo_b, DM * DM / 4);  // Q dead
  topk16_kernel<1><<<rows / 4, 256, 0, stream>>>(A_b, nullptr);

  // 3. topology propagation x4 as batched MFMA GEMM
  prop_mfma<<<dim3(8, 32), 256, 0, stream>>>(A_b, dt0, dtA, logit_lam);
  prop_mfma<<<dim3(8, 32), 256, 0, stream>>>(A_b, dtA, dtB, logit_lam);
  prop_mfma<<<dim3(8, 32), 256, 0, stream>>>(A_b, dtB, dtA, logit_lam);
  prop_mfma<<<dim3(8, 32), 256, 0, stream>>>(A_b, dtA, dtB, logit_lam);

  // 4. finalize (+alpha*D0, normalize, transpose) -> P_b (over dead dtA)
  finalize_kernel<<<dim3(16, 32), 256, 0, stream>>>(dtB, dt0, P_b, log_alpha);

  // 5. phase scores (bf16 -> S2_b over dead A) + top-k -> fp32 dense output
  score_mfma<128, true><<<dim3(8, 8, 32), 256, 0, stream>>>(
      P_b, P_b, S2_b, 11.3137085f);
  topk16_kernel<0><<<rows / 4, 256, 0, stream>>>(S2_b, dense);

  // 6. attn . V as dense MFMA from fp32 phase_attn, then output projection
  attnv_mfma<<<dim3(8, 32), 256, 0, stream>>>(dense, vt_b, attn_b);
  score_mfma<DM, false><<<dim3(8, 16, 1), 256, 0, stream>>>(
      attn_b, wo_b, out, 1.0f);
}

// Round 8
// 405.379 us; speedup vs baseline: 17.3795x; 1.0725x over previous
//
#include <hip/hip_runtime.h>
#include <cstdint>
#include <cstddef>

// Problem constants
#define B_  2
#define T_  1024
#define DM  1024
#define H_  16
#define DK_ 64
#define TOPK 128

typedef unsigned short ushort_t;
typedef __attribute__((ext_vector_type(8))) short short8;
typedef __attribute__((ext_vector_type(8))) unsigned short u16x8;
typedef __attribute__((ext_vector_type(4))) float f32x4;

// monotone map bf16 bits -> u16 (bigger key == bigger float)
__device__ __forceinline__ unsigned fkey16(unsigned b) {
  return (b & 0x8000u) ? (0xffffu & ~b) : (b | 0x8000u);
}

// round-to-nearest-even float -> bf16
__device__ __forceinline__ ushort_t f2bf(float f) {
  unsigned u = __float_as_uint(f);
  return (ushort_t)((u + 0x7fffu + ((u >> 16) & 1u)) >> 16);
}
__device__ __forceinline__ float bf2f(ushort_t u) {
  return __uint_as_float((unsigned)u << 16);
}

// ---------- fp32 -> bf16 cast (float4 / ushort4 vectorized) -----------------
__global__ __launch_bounds__(256) void cast_bf16_kernel(
    const float* __restrict__ in, ushort_t* __restrict__ out, int n4) {
  int i = blockIdx.x * 256 + threadIdx.x;
  if (i < n4) {
    float4 v = ((const float4*)in)[i];
    ushort4 o;
    o.x = f2bf(v.x); o.y = f2bf(v.y); o.z = f2bf(v.z); o.w = f2bf(v.w);
    ((ushort4*)out)[i] = o;
  }
}

// ---------------------------------------------------------------------------
// bf16 MFMA NT GEMM core: 128x128 tile, BK=64, 4 waves (2x2), fp32 acc.
// C[n][m] = sum_k A[n][k]*B[m][k]; A,B bf16 row-major, row stride KDIM.
// ---------------------------------------------------------------------------
template<int KDIM>
__device__ __forceinline__ void gemm_core(
    const ushort_t* __restrict__ Ab, const ushort_t* __restrict__ Bb,
    ushort_t* ldsA, ushort_t* ldsB, int tid, f32x4 acc[4][4]) {
  const int lane = tid & 63, wid = tid >> 6;
  const int wr = (wid >> 1) * 64, wc = (wid & 1) * 64;
  const int l15 = lane & 15, l4 = lane >> 4;
  for (int k0 = 0; k0 < KDIM; k0 += 64) {
    #pragma unroll
    for (int i = 0; i < 4; ++i) {
      int cid = tid + 256 * i;          // 1024 chunks of 16B per tile
      int row = cid >> 3, slot = cid & 7;
      int gc = slot ^ (row & 7);        // pre-swizzled global chunk
      *(uint4*)&ldsA[row * 64 + slot * 8] =
          *(const uint4*)&Ab[(size_t)row * KDIM + k0 + gc * 8];
      *(uint4*)&ldsB[row * 64 + slot * 8] =
          *(const uint4*)&Bb[(size_t)row * KDIM + k0 + gc * 8];
    }
    __syncthreads();
    #pragma unroll
    for (int ks = 0; ks < 2; ++ks) {
      short8 af[4], bfr[4];
      #pragma unroll
      for (int m = 0; m < 4; ++m) {
        int r = wr + m * 16 + l15;
        int c = ks * 4 + l4;
        af[m] = *(const short8*)&ldsA[r * 64 + (c ^ (r & 7)) * 8];
      }
      #pragma unroll
      for (int n = 0; n < 4; ++n) {
        int r = wc + n * 16 + l15;
        int c = ks * 4 + l4;
        bfr[n] = *(const short8*)&ldsB[r * 64 + (c ^ (r & 7)) * 8];
      }
      #pragma unroll
      for (int m = 0; m < 4; ++m)
        #pragma unroll
        for (int n = 0; n < 4; ++n)
          acc[m][n] = __builtin_amdgcn_mfma_f32_16x16x32_bf16(
              af[m], bfr[n], acc[m][n], 0, 0, 0);
    }
    __syncthreads();
  }
}

// ---------- fused 5-way projection (MFMA): out[z] = x . W[z]^T ---------------
// z=0,1 -> head-major bf16 (Q,K); z=2,3 -> packed-transposed D0
// Dt0[head][dd][t]; z=4 -> transposed V: Vt[head][d][t].
__global__ __launch_bounds__(256) void proj5_mfma(
    const ushort_t* __restrict__ xb, const ushort_t* __restrict__ wb,
    ushort_t* __restrict__ qh_b, ushort_t* __restrict__ kh_b,
    ushort_t* __restrict__ dt0, ushort_t* __restrict__ vt_b) {
  __shared__ ushort_t ldsA[128 * 64];
  __shared__ ushort_t ldsB[128 * 64];
  int tid = threadIdx.x, z = blockIdx.z;
  const ushort_t* W = wb + (size_t)z * (DM * DM);
  f32x4 acc[4][4];
  #pragma unroll
  for (int m = 0; m < 4; ++m)
    #pragma unroll
    for (int n = 0; n < 4; ++n) acc[m][n] = (f32x4){0.f, 0.f, 0.f, 0.f};
  gemm_core<DM>(xb + (size_t)blockIdx.y * 128 * DM,
                W + (size_t)blockIdx.x * 128 * DM, ldsA, ldsB, tid, acc);
  const int lane = tid & 63, wid = tid >> 6;
  int row0 = blockIdx.y * 128 + (wid >> 1) * 64 + (lane >> 4) * 4;
  int col0 = blockIdx.x * 128 + (wid & 1) * 64 + (lane & 15);
  #pragma unroll
  for (int m = 0; m < 4; ++m)
    #pragma unroll
    for (int n = 0; n < 4; ++n)
      #pragma unroll
      for (int j = 0; j < 4; ++j) {
        int nr = row0 + m * 16 + j;
        int mc = col0 + n * 16;
        int b = nr >> 10, t = nr & 1023, h = mc >> 6, d = mc & 63;
        int head = b * H_ + h;
        float v = acc[m][n][j];
        if (z == 0) {
          qh_b[((size_t)head * T_ + t) * DK_ + d] = f2bf(v);
        } else if (z == 1) {
          kh_b[((size_t)head * T_ + t) * DK_ + d] = f2bf(v);
        } else if (z == 4) {
          vt_b[(size_t)head * 65536 + (size_t)d * 1024 + t] = f2bf(v);
        } else {
          int ddofs = (z == 3) ? 64 : 0;
          dt0[(size_t)head * 131072 + (size_t)(d + ddofs) * 1024 + t] = f2bf(v);
        }
      }
}

// ---------- batched NT MFMA GEMM -> scaled dense (bf16 or fp32 out) ---------
template<int KDIM, bool BF16OUT>
__global__ __launch_bounds__(256) void score_mfma(
    const ushort_t* __restrict__ A, const ushort_t* __restrict__ Bm,
    void* __restrict__ Sout, float scale) {
  __shared__ ushort_t ldsA[128 * 64];
  __shared__ ushort_t ldsB[128 * 64];
  int tid = threadIdx.x, z = blockIdx.z;
  f32x4 acc[4][4];
  #pragma unroll
  for (int m = 0; m < 4; ++m)
    #pragma unroll
    for (int n = 0; n < 4; ++n) acc[m][n] = (f32x4){0.f, 0.f, 0.f, 0.f};
  gemm_core<KDIM>(A + (size_t)z * T_ * KDIM + (size_t)blockIdx.y * 128 * KDIM,
                  Bm + (size_t)z * T_ * KDIM + (size_t)blockIdx.x * 128 * KDIM,
                  ldsA, ldsB, tid, acc);
  const int lane = tid & 63, wid = tid >> 6;
  int row0 = blockIdx.y * 128 + (wid >> 1) * 64 + (lane >> 4) * 4;
  int col0 = blockIdx.x * 128 + (wid & 1) * 64 + (lane & 15);
  if (BF16OUT) {
    ushort_t* Sz = (ushort_t*)Sout + (size_t)z * T_ * T_;
    #pragma unroll
    for (int m = 0; m < 4; ++m)
      #pragma unroll
      for (int n = 0; n < 4; ++n)
        #pragma unroll
        for (int j = 0; j < 4; ++j)
          Sz[(size_t)(row0 + m * 16 + j) * T_ + col0 + n * 16] =
              f2bf(acc[m][n][j] * scale);
  } else {
    float* Sz = (float*)Sout + (size_t)z * T_ * T_;
    #pragma unroll
    for (int m = 0; m < 4; ++m)
      #pragma unroll
      for (int n = 0; n < 4; ++n)
        #pragma unroll
        for (int j = 0; j < 4; ++j)
          Sz[(size_t)(row0 + m * 16 + j) * T_ + col0 + n * 16] =
              acc[m][n][j] * scale;
  }
}

// ---------- propagation step as MFMA GEMM (per head), BM=64 -----------------
// Dt layout: [head][128 dd][1024 t]. Grid (16 t-tiles, 32 heads) = 512 blocks
// (2 blocks/CU so barrier stalls overlap with the co-resident block).
__global__ __launch_bounds__(256) void prop_mfma(
    const ushort_t* __restrict__ Ab, const ushort_t* __restrict__ Dsrc,
    ushort_t* __restrict__ Ddst, const float* __restrict__ logit_lam) {
  __shared__ ushort_t ldsA[64 * 64];    // t x k
  __shared__ ushort_t ldsB[128 * 64];   // dd x k
  int tid = threadIdx.x, hz = blockIdx.y;
  const int lane = tid & 63, wid = tid >> 6;
  const int wr = wid >> 1, wc = wid & 1;  // wr: 32-t half, wc: 64-dd half
  const int l15 = lane & 15, l4 = lane >> 4;
  const ushort_t* Ah = Ab + (size_t)hz * 1048576 + (size_t)blockIdx.x * 64 * 1024;
  const ushort_t* Dh = Dsrc + (size_t)hz * 131072;
  f32x4 acc[2][4];
  #pragma unroll
  for (int m = 0; m < 2; ++m)
    #pragma unroll
    for (int n = 0; n < 4; ++n) acc[m][n] = (f32x4){0.f, 0.f, 0.f, 0.f};
  for (int k0 = 0; k0 < 1024; k0 += 64) {
    #pragma unroll
    for (int i = 0; i < 2; ++i) {       // A: 512 chunks of 16B
      int cid = tid + 256 * i;
      int rowc = cid >> 3, slot = cid & 7;
      int gc = slot ^ (rowc & 7);
      *(uint4*)&ldsA[rowc * 64 + slot * 8] =
          *(const uint4*)&Ah[(size_t)rowc * 1024 + k0 + gc * 8];
    }
    #pragma unroll
    for (int i = 0; i < 4; ++i) {       // B: 1024 chunks of 16B
      int cid = tid + 256 * i;
      int rowc = cid >> 3, slot = cid & 7;
      int gc = slot ^ (rowc & 7);
      *(uint4*)&ldsB[rowc * 64 + slot * 8] =
          *(const uint4*)&Dh[(size_t)rowc * 1024 + k0 + gc * 8];
    }
    __syncthreads();
    #pragma unroll
    for (int ks = 0; ks < 2; ++ks) {
      short8 af[2], bfr[4];
      #pragma unroll
      for (int m = 0; m < 2; ++m) {
        int r = wr * 32 + m * 16 + l15;
        int c = ks * 4 + l4;
        af[m] = *(const short8*)&ldsA[r * 64 + (c ^ (r & 7)) * 8];
      }
      #pragma unroll
      for (int n = 0; n < 4; ++n) {
        int r = wc * 64 + n * 16 + l15;
        int c = ks * 4 + l4;
        bfr[n] = *(const short8*)&ldsB[r * 64 + (c ^ (r & 7)) * 8];
      }
      #pragma unroll
      for (int m = 0; m < 2; ++m)
        #pragma unroll
        for (int n = 0; n < 4; ++n)
          acc[m][n] = __builtin_amdgcn_mfma_f32_16x16x32_bf16(
              af[m], bfr[n], acc[m][n], 0, 0, 0);
    }
    __syncthreads();
  }
  float lam = 1.f / (1.f + __expf(-logit_lam[0]));
  ushort_t* Dd = Ddst + (size_t)hz * 131072;
  #pragma unroll
  for (int m = 0; m < 2; ++m)
    #pragma unroll
    for (int n = 0; n < 4; ++n)
      #pragma unroll
      for (int j = 0; j < 4; ++j) {
        int t = blockIdx.x * 64 + wr * 32 + m * 16 + l4 * 4 + j;
        int dd = wc * 64 + n * 16 + l15;
        size_t o = (size_t)dd * 1024 + t;
        float oldv = bf2f(Dh[o]);
        Dd[o] = f2bf((1.f - lam) * oldv + lam * acc[m][n][j]);
      }
}

// ---------------------------------------------------------------------------
// Wave-synchronous exact top-128 on bf16 scores. Threshold via 16-step
// ballot binary search on the 16-bit key: each step is one wave-count
// (v_cmp ballot + scalar popcount) -- zero LDS, zero atomics, zero barriers.
// Tie -> lower index via ballot rank (matches jax.lax.top_k). Softmax over
// selected. MODE 0: fp32 dense write (phase output). MODE 1: bf16 in-place.
// ---------------------------------------------------------------------------
template<int MODE>
__global__ __launch_bounds__(256) void topk16_kernel(
    ushort_t* __restrict__ Sb, float* __restrict__ denseOut) {
  const int tid = threadIdx.x;
  const int lane = tid & 63, wv = tid >> 6;
  const int row = blockIdx.x * 4 + wv;
  ushort_t* Srow = Sb + (size_t)row * 1024;

  float scr[2][8];
  unsigned kk[2][8];
  #pragma unroll
  for (int g = 0; g < 2; ++g) {
    u16x8 v = *(const u16x8*)&Srow[g * 512 + lane * 8];
    #pragma unroll
    for (int e = 0; e < 8; ++e) {
      scr[g][e] = bf2f(v[e]);
      kk[g][e] = fkey16((unsigned)v[e]);
    }
  }

  // exact K-th threshold: binary search bit-by-bit, wave-wide ballot counts
  unsigned prefix = 0, r = TOPK;
  #pragma unroll
  for (int b = 15; b >= 0; --b) {
    unsigned want = (prefix << 1) | 1u;
    unsigned cnt = 0;
    #pragma unroll
    for (int g = 0; g < 2; ++g)
      #pragma unroll
      for (int e = 0; e < 8; ++e)
        cnt += (unsigned)__popcll(__ballot((kk[g][e] >> b) == want));
    if (cnt >= r) prefix = want;
    else { prefix <<= 1; r -= cnt; }
  }
  const unsigned thr = prefix;  // key of K-th class; take first r equals

  // wave max for softmax
  float mx = -3.402823466e38f;
  #pragma unroll
  for (int g = 0; g < 2; ++g)
    #pragma unroll
    for (int e = 0; e < 8; ++e) mx = fmaxf(mx, scr[g][e]);
  #pragma unroll
  for (int off = 1; off < 64; off <<= 1) mx = fmaxf(mx, __shfl_xor(mx, off));

  // selection with exact (g,lane,e) lex tie-ranking (s = g*512+lane*8+e)
  const unsigned long long below = (1ull << lane) - 1ull;
  unsigned cum = 0;
  float w[2][8];
  float ps = 0.f;
  #pragma unroll
  for (int g = 0; g < 2; ++g) {
    unsigned long long bal[8];
    #pragma unroll
    for (int e = 0; e < 8; ++e) bal[e] = __ballot(kk[g][e] == thr);
    unsigned rb = cum;
    #pragma unroll
    for (int e = 0; e < 8; ++e) rb += (unsigned)__popcll(bal[e] & below);
    unsigned ownPrior = 0;
    #pragma unroll
    for (int e = 0; e < 8; ++e) {
      bool eq = (kk[g][e] == thr);
      bool sel = (kk[g][e] > thr) || (eq && (rb + ownPrior) < r);
      ownPrior += eq ? 1u : 0u;
      float ex = sel ? __expf(scr[g][e] - mx) : 0.f;
      w[g][e] = ex;
      ps += ex;
    }
    #pragma unroll
    for (int e = 0; e < 8; ++e) cum += (unsigned)__popcll(bal[e]);
  }
  float pss = ps;
  #pragma unroll
  for (int off = 1; off < 64; off <<= 1) pss += __shfl_xor(pss, off);
  const float inv = 1.f / pss;

  if (MODE == 0) {
    float* Drow = denseOut + (size_t)row * 1024;
    #pragma unroll
    for (int g = 0; g < 2; ++g) {
      *(float4*)&Drow[g * 512 + lane * 8] =
          make_float4(w[g][0] * inv, w[g][1] * inv, w[g][2] * inv, w[g][3] * inv);
      *(float4*)&Drow[g * 512 + lane * 8 + 4] =
          make_float4(w[g][4] * inv, w[g][5] * inv, w[g][6] * inv, w[g][7] * inv);
    }
  } else {
    #pragma unroll
    for (int g = 0; g < 2; ++g) {
      u16x8 o;
      #pragma unroll
      for (int e = 0; e < 8; ++e) o[e] = f2bf(w[g][e] * inv);
      *(u16x8*)&Srow[g * 512 + lane * 8] = o;
    }
  }
}

// ---------- finalize: D += alpha*D0 (Dt layout); normalize -> P=[Ur|Ui] -----
__global__ __launch_bounds__(256) void finalize_kernel(
    const ushort_t* __restrict__ Dt, const ushort_t* __restrict__ Dt0,
    ushort_t* __restrict__ P, const float* __restrict__ log_alpha) {
  __shared__ float lds[64][129];
  __shared__ float red[4][64];
  __shared__ float nrmi[64];
  int tid = threadIdx.x;
  int hz = blockIdx.y;
  int t0 = blockIdx.x * 64;
  size_t base = (size_t)hz * 131072 + t0;
  float alpha = 1.f / (1.f + __expf(-log_alpha[0]));
  #pragma unroll
  for (int i = 0; i < 32; ++i) {
    int eid = tid + i * 256;
    int dd = eid >> 6, t = eid & 63;
    size_t o = base + (size_t)dd * 1024 + t;
    lds[t][dd] = bf2f(Dt[o]) + alpha * bf2f(Dt0[o]);
  }
  __syncthreads();
  int t = tid & 63, q = tid >> 6;
  float s = 0.f;
  #pragma unroll
  for (int k = 0; k < 32; ++k) {
    float v = lds[t][q * 32 + k];
    s += v * v;
  }
  red[q][t] = s;
  __syncthreads();
  if (tid < 64) {
    float tot = red[0][tid] + red[1][tid] + red[2][tid] + red[3][tid];
    nrmi[tid] = 1.f / fmaxf(sqrtf(tot), 1e-6f);
  }
  __syncthreads();
  #pragma unroll
  for (int i = 0; i < 32; ++i) {
    int eid = tid + i * 256;
    int dd = eid & 127, tt = eid >> 7;
    P[((size_t)hz * 1024 + t0 + tt) * 128 + dd] = f2bf(lds[tt][dd] * nrmi[tt]);
  }
}

// ---------- attn.V as MFMA (BM=64): C[t][d] = sum_s W[t][s]*Vt[d][s] --------
// W is fp32 dense (just-written phase_attn, L2/L3 resident); staged to bf16.
// Grid (16 t-tiles, 32 heads) = 512 blocks.
__global__ __launch_bounds__(256) void attnv_mfma(
    const float* __restrict__ Wf, const ushort_t* __restrict__ Vt,
    ushort_t* __restrict__ attn_b) {
  __shared__ ushort_t ldsA[64 * 64];   // t x k (8 KB)
  __shared__ ushort_t ldsB[64 * 64];   // d x k (8 KB)
  int tid = threadIdx.x, hz = blockIdx.y;
  const int lane = tid & 63, wid = tid >> 6;
  const int wr = wid >> 1, wc = wid & 1;  // 32-t half, 32-d half
  const int l15 = lane & 15, l4 = lane >> 4;
  const float* Wh = Wf + (size_t)hz * 1048576 + (size_t)blockIdx.x * 64 * 1024;
  const ushort_t* Vh = Vt + (size_t)hz * 65536;
  f32x4 acc[2][2];
  #pragma unroll
  for (int m = 0; m < 2; ++m)
    #pragma unroll
    for (int n = 0; n < 2; ++n) acc[m][n] = (f32x4){0.f, 0.f, 0.f, 0.f};
  for (int k0 = 0; k0 < 1024; k0 += 64) {
    #pragma unroll
    for (int i = 0; i < 4; ++i) {       // A: 1024 fp32-16B chunks -> bf16
      int cid = tid + 256 * i;
      int rowc = cid >> 4, c4 = cid & 15;
      float4 v = *(const float4*)&Wh[(size_t)rowc * 1024 + k0 + c4 * 4];
      int c = c4 >> 1, half = c4 & 1;
      ushort4 o;
      o.x = f2bf(v.x); o.y = f2bf(v.y); o.z = f2bf(v.z); o.w = f2bf(v.w);
      *(ushort4*)&ldsA[rowc * 64 + (c ^ (rowc & 7)) * 8 + half * 4] = o;
    }
    #pragma unroll
    for (int i = 0; i < 2; ++i) {       // B: 512 bf16-16B chunks
      int cid = tid + 256 * i;
      int rowc = cid >> 3, slot = cid & 7;
      int gc = slot ^ (rowc & 7);
      *(uint4*)&ldsB[rowc * 64 + slot * 8] =
          *(const uint4*)&Vh[(size_t)rowc * 1024 + k0 + gc * 8];
    }
    __syncthreads();
    #pragma unroll
    for (int ks = 0; ks < 2; ++ks) {
      short8 af[2], bfr[2];
      #pragma unroll
      for (int m = 0; m < 2; ++m) {
        int r = wr * 32 + m * 16 + l15;
        int c = ks * 4 + l4;
        af[m] = *(const short8*)&ldsA[r * 64 + (c ^ (r & 7)) * 8];
      }
      #pragma unroll
      for (int n = 0; n < 2; ++n) {
        int r = wc * 32 + n * 16 + l15;
        int c = ks * 4 + l4;
        bfr[n] = *(const short8*)&ldsB[r * 64 + (c ^ (r & 7)) * 8];
      }
      #pragma unroll
      for (int m = 0; m < 2; ++m)
        #pragma unroll
        for (int n = 0; n < 2; ++n)
          acc[m][n] = __builtin_amdgcn_mfma_f32_16x16x32_bf16(
              af[m], bfr[n], acc[m][n], 0, 0, 0);
    }
    __syncthreads();
  }
  int b = hz >> 4, h = hz & 15;
  #pragma unroll
  for (int m = 0; m < 2; ++m)
    #pragma unroll
    for (int n = 0; n < 2; ++n)
      #pragma unroll
      for (int j = 0; j < 4; ++j) {
        int t = blockIdx.x * 64 + wr * 32 + m * 16 + l4 * 4 + j;
        int d = wc * 32 + n * 16 + l15;
        attn_b[((size_t)(b * T_ + t)) * DM + h * DK_ + d] = f2bf(acc[m][n][j]);
      }
}

extern "C" void kernel_launch(void* const* d_in, const int* in_sizes, int n_in,
                              void* d_out, int out_size, void* d_ws, size_t ws_size,
                              hipStream_t stream) {
  (void)in_sizes; (void)n_in; (void)out_size; (void)ws_size;
  const float* x         = (const float*)d_in[0];
  const float* wq        = (const float*)d_in[1];
  const float* wk        = (const float*)d_in[2];
  const float* wre       = (const float*)d_in[3];
  const float* wim       = (const float*)d_in[4];
  const float* wv        = (const float*)d_in[5];
  const float* wo        = (const float*)d_in[6];
  const float* logit_lam = (const float*)d_in[7];
  const float* log_alpha = (const float*)d_in[8];

  float* out   = (float*)d_out;                 // (B,T,DM)
  float* dense = out + (size_t)B_ * T_ * DM;    // phase_attn (B,H,T,T) fp32 out
  // first 10 MB of dense doubles as bf16 weight scratch (wq..wv); dead after
  // proj5 and long before topk16<0> writes the dense region (stream-ordered).
  ushort_t* w5_b = (ushort_t*)dense;

  char* ws = (char*)d_ws;
  const size_t MB = (size_t)1 << 20;
  // 0-64 MB: adjacency bf16 scores -> in-place weights (prop input);
  //          later reused for phase bf16 scores.
  ushort_t* A_b  = (ushort_t*)(ws + 0 * MB);
  ushort_t* S2_b = A_b;                          // phase scores (A dead)
  ushort_t* dt0  = (ushort_t*)(ws + 64 * MB);    // 8 MB Dt0 [32][128][1024]
  ushort_t* dtA  = (ushort_t*)(ws + 72 * MB);    // 8 MB ping; P_b after prop
  ushort_t* P_b  = dtA;                          // packed [Ur|Ui] bf16
  ushort_t* dtB  = (ushort_t*)(ws + 80 * MB);    // 8 MB pong (final D)
  ushort_t* vt_b = (ushort_t*)(ws + 88 * MB);    // 4 MB Vt [32][64][1024]
  ushort_t* xb   = (ushort_t*)(ws + 92 * MB);    // 4 MB bf16 x; reused attn_b
  ushort_t* attn_b = xb;                         // alias (x dead after proj)
  ushort_t* qh_b = (ushort_t*)(ws + 96 * MB);    // 4 MB bf16 Q; wo_b after adj
  ushort_t* wo_b = qh_b;                         // alias (Q dead after scores)
  ushort_t* kh_b = (ushort_t*)(ws + 100 * MB);   // 4 MB bf16 K
  // total workspace: 104 MB

  const int rows = B_ * H_ * T_;  // 32768

  // 0. bf16 casts (W_O deferred until Q is dead)
  cast_bf16_kernel<<<2048, 256, 0, stream>>>(x, xb, (B_ * T_ * DM) / 4);
  cast_bf16_kernel<<<1024, 256, 0, stream>>>(wq,  w5_b + 0 * DM * DM, DM * DM / 4);
  cast_bf16_kernel<<<1024, 256, 0, stream>>>(wk,  w5_b + 1 * (size_t)DM * DM, DM * DM / 4);
  cast_bf16_kernel<<<1024, 256, 0, stream>>>(wre, w5_b + 2 * (size_t)DM * DM, DM * DM / 4);
  cast_bf16_kernel<<<1024, 256, 0, stream>>>(wim, w5_b + 3 * (size_t)DM * DM, DM * DM / 4);
  cast_bf16_kernel<<<1024, 256, 0, stream>>>(wv,  w5_b + 4 * (size_t)DM * DM, DM * DM / 4);

  // 1. all 5 projections (MFMA)
  proj5_mfma<<<dim3(8, 16, 5), 256, 0, stream>>>(
      xb, w5_b, qh_b, kh_b, dt0, vt_b);

  // 2. adjacency scores (bf16 -> A_b) + top-k (in-place bf16 weights)
  score_mfma<64, true><<<dim3(8, 8, 32), 256, 0, stream>>>(
      qh_b, kh_b, A_b, 0.125f);
  cast_bf16_kernel<<<1024, 256, 0, stream>>>(wo, wo_b, DM * DM / 4);  // Q dead
  topk16_kernel<1><<<rows / 4, 256, 0, stream>>>(A_b, nullptr);

  // 3. topology propagation x4 as batched MFMA GEMM (512 blocks each)
  prop_mfma<<<dim3(16, 32), 256, 0, stream>>>(A_b, dt0, dtA, logit_lam);
  prop_mfma<<<dim3(16, 32), 256, 0, stream>>>(A_b, dtA, dtB, logit_lam);
  prop_mfma<<<dim3(16, 32), 256, 0, stream>>>(A_b, dtB, dtA, logit_lam);
  prop_mfma<<<dim3(16, 32), 256, 0, stream>>>(A_b, dtA, dtB, logit_lam);

  // 4. finalize (+alpha*D0, normalize, transpose) -> P_b (over dead dtA)
  finalize_kernel<<<dim3(16, 32), 256, 0, stream>>>(dtB, dt0, P_b, log_alpha);

  // 5. phase scores (bf16 -> S2_b over dead A) + top-k -> fp32 dense output
  score_mfma<128, true><<<dim3(8, 8, 32), 256, 0, stream>>>(
      P_b, P_b, S2_b, 11.3137085f);
  topk16_kernel<0><<<rows / 4, 256, 0, stream>>>(S2_b, dense);

  // 6. attn . V as dense MFMA from fp32 phase_attn, then output projection
  attnv_mfma<<<dim3(16, 32), 256, 0, stream>>>(dense, vt_b, attn_b);
  score_mfma<DM, false><<<dim3(8, 16, 1), 256, 0, stream>>>(
      attn_b, wo_b, out, 1.0f);
}

// Round 9
// 378.348 us; speedup vs baseline: 18.6212x; 1.0714x over previous
//
#include <hip/hip_runtime.h>
#include <cstdint>
#include <cstddef>

// Problem constants
#define B_  2
#define T_  1024
#define DM  1024
#define H_  16
#define DK_ 64
#define TOPK 128

typedef unsigned short ushort_t;
typedef __attribute__((ext_vector_type(8))) short short8;
typedef __attribute__((ext_vector_type(8))) unsigned short u16x8;
typedef __attribute__((ext_vector_type(4))) float f32x4;

// monotone map bf16 bits -> u16 (bigger key == bigger float)
__device__ __forceinline__ unsigned fkey16(unsigned b) {
  return (b & 0x8000u) ? (0xffffu & ~b) : (b | 0x8000u);
}

// round-to-nearest-even float -> bf16
__device__ __forceinline__ ushort_t f2bf(float f) {
  unsigned u = __float_as_uint(f);
  return (ushort_t)((u + 0x7fffu + ((u >> 16) & 1u)) >> 16);
}
__device__ __forceinline__ float bf2f(ushort_t u) {
  return __uint_as_float((unsigned)u << 16);
}

// async global->LDS 16B copy (linear LDS dest = wave-uniform base + lane*16;
// global src may be per-lane swizzled). Drained by the compiler's vmcnt(0)
// before each __syncthreads().
__device__ __forceinline__ void gload_lds16(const ushort_t* g, ushort_t* l) {
  __builtin_amdgcn_global_load_lds(
      (const __attribute__((address_space(1))) unsigned int*)(const void*)g,
      (__attribute__((address_space(3))) unsigned int*)(void*)l, 16, 0, 0);
}

// ---------- fused bf16 casts: x + 5 weights in one launch --------------------
__global__ __launch_bounds__(256) void cast6_kernel(
    const float* __restrict__ x, const float* __restrict__ wq,
    const float* __restrict__ wk, const float* __restrict__ wre,
    const float* __restrict__ wim, const float* __restrict__ wv,
    ushort_t* __restrict__ xb, ushort_t* __restrict__ w5b) {
  int z = blockIdx.y;
  const float* src; ushort_t* dst; int n4;
  switch (z) {
    case 0: src = x;   dst = xb;                 n4 = 524288; break;
    case 1: src = wq;  dst = w5b;                n4 = 262144; break;
    case 2: src = wk;  dst = w5b + 1048576;      n4 = 262144; break;
    case 3: src = wre; dst = w5b + 2097152;      n4 = 262144; break;
    case 4: src = wim; dst = w5b + 3145728;      n4 = 262144; break;
    default: src = wv; dst = w5b + 4194304;      n4 = 262144; break;
  }
  int i = blockIdx.x * 256 + threadIdx.x;
  if (i < n4) {
    float4 v = ((const float4*)src)[i];
    ushort4 o;
    o.x = f2bf(v.x); o.y = f2bf(v.y); o.z = f2bf(v.z); o.w = f2bf(v.w);
    ((ushort4*)dst)[i] = o;
  }
}

__global__ __launch_bounds__(256) void cast_bf16_kernel(
    const float* __restrict__ in, ushort_t* __restrict__ out, int n4) {
  int i = blockIdx.x * 256 + threadIdx.x;
  if (i < n4) {
    float4 v = ((const float4*)in)[i];
    ushort4 o;
    o.x = f2bf(v.x); o.y = f2bf(v.y); o.z = f2bf(v.z); o.w = f2bf(v.w);
    ((ushort4*)out)[i] = o;
  }
}

// ---------------------------------------------------------------------------
// bf16 MFMA NT GEMM core: 128x128 tile, BK=64, 4 waves (2x2), fp32 acc.
// Staging via global_load_lds (linear LDS dest, pre-swizzled global src).
// ---------------------------------------------------------------------------
template<int KDIM>
__device__ __forceinline__ void gemm_core(
    const ushort_t* __restrict__ Ab, const ushort_t* __restrict__ Bb,
    ushort_t* ldsA, ushort_t* ldsB, int tid, f32x4 acc[4][4]) {
  const int lane = tid & 63, wid = tid >> 6;
  const int wr = (wid >> 1) * 64, wc = (wid & 1) * 64;
  const int l15 = lane & 15, l4 = lane >> 4;
  for (int k0 = 0; k0 < KDIM; k0 += 64) {
    #pragma unroll
    for (int i = 0; i < 4; ++i) {
      int cid = tid + 256 * i;          // 1024 chunks of 16B per tile
      int row = cid >> 3, slot = cid & 7;
      int gc = slot ^ (row & 7);        // pre-swizzled global chunk
      gload_lds16(&Ab[(size_t)row * KDIM + k0 + gc * 8], &ldsA[cid * 8]);
      gload_lds16(&Bb[(size_t)row * KDIM + k0 + gc * 8], &ldsB[cid * 8]);
    }
    __syncthreads();
    #pragma unroll
    for (int ks = 0; ks < 2; ++ks) {
      short8 af[4], bfr[4];
      #pragma unroll
      for (int m = 0; m < 4; ++m) {
        int r = wr + m * 16 + l15;
        int c = ks * 4 + l4;
        af[m] = *(const short8*)&ldsA[r * 64 + (c ^ (r & 7)) * 8];
      }
      #pragma unroll
      for (int n = 0; n < 4; ++n) {
        int r = wc + n * 16 + l15;
        int c = ks * 4 + l4;
        bfr[n] = *(const short8*)&ldsB[r * 64 + (c ^ (r & 7)) * 8];
      }
      #pragma unroll
      for (int m = 0; m < 4; ++m)
        #pragma unroll
        for (int n = 0; n < 4; ++n)
          acc[m][n] = __builtin_amdgcn_mfma_f32_16x16x32_bf16(
              af[m], bfr[n], acc[m][n], 0, 0, 0);
    }
    __syncthreads();
  }
}

// ---------- fused 5-way projection (MFMA): out[z] = x . W[z]^T ---------------
__global__ __launch_bounds__(256) void proj5_mfma(
    const ushort_t* __restrict__ xb, const ushort_t* __restrict__ wb,
    ushort_t* __restrict__ qh_b, ushort_t* __restrict__ kh_b,
    ushort_t* __restrict__ dt0, ushort_t* __restrict__ vt_b) {
  __shared__ ushort_t ldsA[128 * 64];
  __shared__ ushort_t ldsB[128 * 64];
  int tid = threadIdx.x, z = blockIdx.z;
  const ushort_t* W = wb + (size_t)z * (DM * DM);
  f32x4 acc[4][4];
  #pragma unroll
  for (int m = 0; m < 4; ++m)
    #pragma unroll
    for (int n = 0; n < 4; ++n) acc[m][n] = (f32x4){0.f, 0.f, 0.f, 0.f};
  gemm_core<DM>(xb + (size_t)blockIdx.y * 128 * DM,
                W + (size_t)blockIdx.x * 128 * DM, ldsA, ldsB, tid, acc);
  const int lane = tid & 63, wid = tid >> 6;
  int row0 = blockIdx.y * 128 + (wid >> 1) * 64 + (lane >> 4) * 4;
  int col0 = blockIdx.x * 128 + (wid & 1) * 64 + (lane & 15);
  #pragma unroll
  for (int m = 0; m < 4; ++m)
    #pragma unroll
    for (int n = 0; n < 4; ++n)
      #pragma unroll
      for (int j = 0; j < 4; ++j) {
        int nr = row0 + m * 16 + j;
        int mc = col0 + n * 16;
        int b = nr >> 10, t = nr & 1023, h = mc >> 6, d = mc & 63;
        int head = b * H_ + h;
        float v = acc[m][n][j];
        if (z == 0) {
          qh_b[((size_t)head * T_ + t) * DK_ + d] = f2bf(v);
        } else if (z == 1) {
          kh_b[((size_t)head * T_ + t) * DK_ + d] = f2bf(v);
        } else if (z == 4) {
          vt_b[(size_t)head * 65536 + (size_t)d * 1024 + t] = f2bf(v);
        } else {
          int ddofs = (z == 3) ? 64 : 0;
          dt0[(size_t)head * 131072 + (size_t)(d + ddofs) * 1024 + t] = f2bf(v);
        }
      }
}

// ---------- batched NT MFMA GEMM -> scaled dense (bf16 or fp32 out) ---------
template<int KDIM, bool BF16OUT>
__global__ __launch_bounds__(256) void score_mfma(
    const ushort_t* __restrict__ A, const ushort_t* __restrict__ Bm,
    void* __restrict__ Sout, float scale) {
  __shared__ ushort_t ldsA[128 * 64];
  __shared__ ushort_t ldsB[128 * 64];
  int tid = threadIdx.x, z = blockIdx.z;
  f32x4 acc[4][4];
  #pragma unroll
  for (int m = 0; m < 4; ++m)
    #pragma unroll
    for (int n = 0; n < 4; ++n) acc[m][n] = (f32x4){0.f, 0.f, 0.f, 0.f};
  gemm_core<KDIM>(A + (size_t)z * T_ * KDIM + (size_t)blockIdx.y * 128 * KDIM,
                  Bm + (size_t)z * T_ * KDIM + (size_t)blockIdx.x * 128 * KDIM,
                  ldsA, ldsB, tid, acc);
  const int lane = tid & 63, wid = tid >> 6;
  int row0 = blockIdx.y * 128 + (wid >> 1) * 64 + (lane >> 4) * 4;
  int col0 = blockIdx.x * 128 + (wid & 1) * 64 + (lane & 15);
  if (BF16OUT) {
    ushort_t* Sz = (ushort_t*)Sout + (size_t)z * T_ * T_;
    #pragma unroll
    for (int m = 0; m < 4; ++m)
      #pragma unroll
      for (int n = 0; n < 4; ++n)
        #pragma unroll
        for (int j = 0; j < 4; ++j)
          Sz[(size_t)(row0 + m * 16 + j) * T_ + col0 + n * 16] =
              f2bf(acc[m][n][j] * scale);
  } else {
    float* Sz = (float*)Sout + (size_t)z * T_ * T_;
    #pragma unroll
    for (int m = 0; m < 4; ++m)
      #pragma unroll
      for (int n = 0; n < 4; ++n)
        #pragma unroll
        for (int j = 0; j < 4; ++j)
          Sz[(size_t)(row0 + m * 16 + j) * T_ + col0 + n * 16] =
              acc[m][n][j] * scale;
  }
}

// ---------- propagation step as MFMA GEMM (per head), BM=64 -----------------
__global__ __launch_bounds__(256) void prop_mfma(
    const ushort_t* __restrict__ Ab, const ushort_t* __restrict__ Dsrc,
    ushort_t* __restrict__ Ddst, const float* __restrict__ logit_lam) {
  __shared__ ushort_t ldsA[64 * 64];    // t x k
  __shared__ ushort_t ldsB[128 * 64];   // dd x k
  int tid = threadIdx.x, hz = blockIdx.y;
  const int lane = tid & 63, wid = tid >> 6;
  const int wr = wid >> 1, wc = wid & 1;
  const int l15 = lane & 15, l4 = lane >> 4;
  const ushort_t* Ah = Ab + (size_t)hz * 1048576 + (size_t)blockIdx.x * 64 * 1024;
  const ushort_t* Dh = Dsrc + (size_t)hz * 131072;
  f32x4 acc[2][4];
  #pragma unroll
  for (int m = 0; m < 2; ++m)
    #pragma unroll
    for (int n = 0; n < 4; ++n) acc[m][n] = (f32x4){0.f, 0.f, 0.f, 0.f};
  for (int k0 = 0; k0 < 1024; k0 += 64) {
    {
      int cid = tid;                    // A: 512 chunks
      int rowc = cid >> 3, slot = cid & 7;
      int gc = slot ^ (rowc & 7);
      gload_lds16(&Ah[(size_t)rowc * 1024 + k0 + gc * 8], &ldsA[cid * 8]);
      cid = tid + 256;
      rowc = cid >> 3; slot = cid & 7;
      gc = slot ^ (rowc & 7);
      gload_lds16(&Ah[(size_t)rowc * 1024 + k0 + gc * 8], &ldsA[cid * 8]);
    }
    #pragma unroll
    for (int i = 0; i < 4; ++i) {       // B: 1024 chunks
      int cid = tid + 256 * i;
      int rowc = cid >> 3, slot = cid & 7;
      int gc = slot ^ (rowc & 7);
      gload_lds16(&Dh[(size_t)rowc * 1024 + k0 + gc * 8], &ldsB[cid * 8]);
    }
    __syncthreads();
    #pragma unroll
    for (int ks = 0; ks < 2; ++ks) {
      short8 af[2], bfr[4];
      #pragma unroll
      for (int m = 0; m < 2; ++m) {
        int r = wr * 32 + m * 16 + l15;
        int c = ks * 4 + l4;
        af[m] = *(const short8*)&ldsA[r * 64 + (c ^ (r & 7)) * 8];
      }
      #pragma unroll
      for (int n = 0; n < 4; ++n) {
        int r = wc * 64 + n * 16 + l15;
        int c = ks * 4 + l4;
        bfr[n] = *(const short8*)&ldsB[r * 64 + (c ^ (r & 7)) * 8];
      }
      #pragma unroll
      for (int m = 0; m < 2; ++m)
        #pragma unroll
        for (int n = 0; n < 4; ++n)
          acc[m][n] = __builtin_amdgcn_mfma_f32_16x16x32_bf16(
              af[m], bfr[n], acc[m][n], 0, 0, 0);
    }
    __syncthreads();
  }
  float lam = 1.f / (1.f + __expf(-logit_lam[0]));
  ushort_t* Dd = Ddst + (size_t)hz * 131072;
  #pragma unroll
  for (int m = 0; m < 2; ++m)
    #pragma unroll
    for (int n = 0; n < 4; ++n)
      #pragma unroll
      for (int j = 0; j < 4; ++j) {
        int t = blockIdx.x * 64 + wr * 32 + m * 16 + l4 * 4 + j;
        int dd = wc * 64 + n * 16 + l15;
        size_t o = (size_t)dd * 1024 + t;
        float oldv = bf2f(Dh[o]);
        Dd[o] = f2bf((1.f - lam) * oldv + lam * acc[m][n][j]);
      }
}

// ---------------------------------------------------------------------------
// Wave-synchronous exact top-128 on bf16 scores via 16-step ballot binary
// search (no LDS / atomics / barriers). Tie -> lower index via ballot rank.
// MODE 0: fp32 dense write (phase output) + bf16 in-place WB (attnv input).
// MODE 1: bf16 in-place WB only.
// ---------------------------------------------------------------------------
template<int MODE>
__global__ __launch_bounds__(256) void topk16_kernel(
    ushort_t* __restrict__ Sb, float* __restrict__ denseOut) {
  const int tid = threadIdx.x;
  const int lane = tid & 63, wv = tid >> 6;
  const int row = blockIdx.x * 4 + wv;
  ushort_t* Srow = Sb + (size_t)row * 1024;

  float scr[2][8];
  unsigned kk[2][8];
  #pragma unroll
  for (int g = 0; g < 2; ++g) {
    u16x8 v = *(const u16x8*)&Srow[g * 512 + lane * 8];
    #pragma unroll
    for (int e = 0; e < 8; ++e) {
      scr[g][e] = bf2f(v[e]);
      kk[g][e] = fkey16((unsigned)v[e]);
    }
  }

  // exact K-th threshold: binary search bit-by-bit, wave-wide ballot counts
  unsigned prefix = 0, r = TOPK;
  #pragma unroll
  for (int b = 15; b >= 0; --b) {
    unsigned want = (prefix << 1) | 1u;
    unsigned cnt = 0;
    #pragma unroll
    for (int g = 0; g < 2; ++g)
      #pragma unroll
      for (int e = 0; e < 8; ++e)
        cnt += (unsigned)__popcll(__ballot((kk[g][e] >> b) == want));
    if (cnt >= r) prefix = want;
    else { prefix <<= 1; r -= cnt; }
  }
  const unsigned thr = prefix;  // key of K-th class; take first r equals

  // wave max for softmax
  float mx = -3.402823466e38f;
  #pragma unroll
  for (int g = 0; g < 2; ++g)
    #pragma unroll
    for (int e = 0; e < 8; ++e) mx = fmaxf(mx, scr[g][e]);
  #pragma unroll
  for (int off = 1; off < 64; off <<= 1) mx = fmaxf(mx, __shfl_xor(mx, off));

  // selection with exact (g,lane,e) lex tie-ranking (s = g*512+lane*8+e)
  const unsigned long long below = (1ull << lane) - 1ull;
  unsigned cum = 0;
  float w[2][8];
  float ps = 0.f;
  #pragma unroll
  for (int g = 0; g < 2; ++g) {
    unsigned long long bal[8];
    #pragma unroll
    for (int e = 0; e < 8; ++e) bal[e] = __ballot(kk[g][e] == thr);
    unsigned rb = cum;
    #pragma unroll
    for (int e = 0; e < 8; ++e) rb += (unsigned)__popcll(bal[e] & below);
    unsigned ownPrior = 0;
    #pragma unroll
    for (int e = 0; e < 8; ++e) {
      bool eq = (kk[g][e] == thr);
      bool sel = (kk[g][e] > thr) || (eq && (rb + ownPrior) < r);
      ownPrior += eq ? 1u : 0u;
      float ex = sel ? __expf(scr[g][e] - mx) : 0.f;
      w[g][e] = ex;
      ps += ex;
    }
    #pragma unroll
    for (int e = 0; e < 8; ++e) cum += (unsigned)__popcll(bal[e]);
  }
  float pss = ps;
  #pragma unroll
  for (int off = 1; off < 64; off <<= 1) pss += __shfl_xor(pss, off);
  const float inv = 1.f / pss;

  if (MODE == 0) {
    float* Drow = denseOut + (size_t)row * 1024;
    #pragma unroll
    for (int g = 0; g < 2; ++g) {
      *(float4*)&Drow[g * 512 + lane * 8] =
          make_float4(w[g][0] * inv, w[g][1] * inv, w[g][2] * inv, w[g][3] * inv);
      *(float4*)&Drow[g * 512 + lane * 8 + 4] =
          make_float4(w[g][4] * inv, w[g][5] * inv, w[g][6] * inv, w[g][7] * inv);
    }
  }
  // bf16 in-place writeback (MODE 0: consumed by attnv; MODE 1: by prop)
  #pragma unroll
  for (int g = 0; g < 2; ++g) {
    u16x8 o;
    #pragma unroll
    for (int e = 0; e < 8; ++e) o[e] = f2bf(w[g][e] * inv);
    *(u16x8*)&Srow[g * 512 + lane * 8] = o;
  }
}

// ---------- finalize: D += alpha*D0 (Dt layout); normalize -> P=[Ur|Ui] -----
__global__ __launch_bounds__(256) void finalize_kernel(
    const ushort_t* __restrict__ Dt, const ushort_t* __restrict__ Dt0,
    ushort_t* __restrict__ P, const float* __restrict__ log_alpha) {
  __shared__ float lds[64][129];
  __shared__ float red[4][64];
  __shared__ float nrmi[64];
  int tid = threadIdx.x;
  int hz = blockIdx.y;
  int t0 = blockIdx.x * 64;
  size_t base = (size_t)hz * 131072 + t0;
  float alpha = 1.f / (1.f + __expf(-log_alpha[0]));
  #pragma unroll
  for (int i = 0; i < 32; ++i) {
    int eid = tid + i * 256;
    int dd = eid >> 6, t = eid & 63;
    size_t o = base + (size_t)dd * 1024 + t;
    lds[t][dd] = bf2f(Dt[o]) + alpha * bf2f(Dt0[o]);
  }
  __syncthreads();
  int t = tid & 63, q = tid >> 6;
  float s = 0.f;
  #pragma unroll
  for (int k = 0; k < 32; ++k) {
    float v = lds[t][q * 32 + k];
    s += v * v;
  }
  red[q][t] = s;
  __syncthreads();
  if (tid < 64) {
    float tot = red[0][tid] + red[1][tid] + red[2][tid] + red[3][tid];
    nrmi[tid] = 1.f / fmaxf(sqrtf(tot), 1e-6f);
  }
  __syncthreads();
  #pragma unroll
  for (int i = 0; i < 32; ++i) {
    int eid = tid + i * 256;
    int dd = eid & 127, tt = eid >> 7;
    P[((size_t)hz * 1024 + t0 + tt) * 128 + dd] = f2bf(lds[tt][dd] * nrmi[tt]);
  }
}

// ---------- attn.V as MFMA (BM=64): C[t][d] = sum_s W[t][s]*Vt[d][s] --------
// W = bf16 weights (topk16<0>'s in-place writeback), Vt = [head][64][1024].
__global__ __launch_bounds__(256) void attnv_mfma(
    const ushort_t* __restrict__ Wb, const ushort_t* __restrict__ Vt,
    ushort_t* __restrict__ attn_b) {
  __shared__ ushort_t ldsA[64 * 64];   // t x k (8 KB)
  __shared__ ushort_t ldsB[64 * 64];   // d x k (8 KB)
  int tid = threadIdx.x, hz = blockIdx.y;
  const int lane = tid & 63, wid = tid >> 6;
  const int wr = wid >> 1, wc = wid & 1;
  const int l15 = lane & 15, l4 = lane >> 4;
  const ushort_t* Wh = Wb + (size_t)hz * 1048576 + (size_t)blockIdx.x * 64 * 1024;
  const ushort_t* Vh = Vt + (size_t)hz * 65536;
  f32x4 acc[2][2];
  #pragma unroll
  for (int m = 0; m < 2; ++m)
    #pragma unroll
    for (int n = 0; n < 2; ++n) acc[m][n] = (f32x4){0.f, 0.f, 0.f, 0.f};
  for (int k0 = 0; k0 < 1024; k0 += 64) {
    #pragma unroll
    for (int i = 0; i < 2; ++i) {       // A: 512 chunks of 16B
      int cid = tid + 256 * i;
      int rowc = cid >> 3, slot = cid & 7;
      int gc = slot ^ (rowc & 7);
      gload_lds16(&Wh[(size_t)rowc * 1024 + k0 + gc * 8], &ldsA[cid * 8]);
    }
    #pragma unroll
    for (int i = 0; i < 2; ++i) {       // B: 512 chunks of 16B
      int cid = tid + 256 * i;
      int rowc = cid >> 3, slot = cid & 7;
      int gc = slot ^ (rowc & 7);
      gload_lds16(&Vh[(size_t)rowc * 1024 + k0 + gc * 8], &ldsB[cid * 8]);
    }
    __syncthreads();
    #pragma unroll
    for (int ks = 0; ks < 2; ++ks) {
      short8 af[2], bfr[2];
      #pragma unroll
      for (int m = 0; m < 2; ++m) {
        int r = wr * 32 + m * 16 + l15;
        int c = ks * 4 + l4;
        af[m] = *(const short8*)&ldsA[r * 64 + (c ^ (r & 7)) * 8];
      }
      #pragma unroll
      for (int n = 0; n < 2; ++n) {
        int r = wc * 32 + n * 16 + l15;
        int c = ks * 4 + l4;
        bfr[n] = *(const short8*)&ldsB[r * 64 + (c ^ (r & 7)) * 8];
      }
      #pragma unroll
      for (int m = 0; m < 2; ++m)
        #pragma unroll
        for (int n = 0; n < 2; ++n)
          acc[m][n] = __builtin_amdgcn_mfma_f32_16x16x32_bf16(
              af[m], bfr[n], acc[m][n], 0, 0, 0);
    }
    __syncthreads();
  }
  int b = hz >> 4, h = hz & 15;
  #pragma unroll
  for (int m = 0; m < 2; ++m)
    #pragma unroll
    for (int n = 0; n < 2; ++n)
      #pragma unroll
      for (int j = 0; j < 4; ++j) {
        int t = blockIdx.x * 64 + wr * 32 + m * 16 + l4 * 4 + j;
        int d = wc * 32 + n * 16 + l15;
        attn_b[((size_t)(b * T_ + t)) * DM + h * DK_ + d] = f2bf(acc[m][n][j]);
      }
}

extern "C" void kernel_launch(void* const* d_in, const int* in_sizes, int n_in,
                              void* d_out, int out_size, void* d_ws, size_t ws_size,
                              hipStream_t stream) {
  (void)in_sizes; (void)n_in; (void)out_size; (void)ws_size;
  const float* x         = (const float*)d_in[0];
  const float* wq        = (const float*)d_in[1];
  const float* wk        = (const float*)d_in[2];
  const float* wre       = (const float*)d_in[3];
  const float* wim       = (const float*)d_in[4];
  const float* wv        = (const float*)d_in[5];
  const float* wo        = (const float*)d_in[6];
  const float* logit_lam = (const float*)d_in[7];
  const float* log_alpha = (const float*)d_in[8];

  float* out   = (float*)d_out;                 // (B,T,DM)
  float* dense = out + (size_t)B_ * T_ * DM;    // phase_attn (B,H,T,T) fp32 out
  // first 10 MB of dense doubles as bf16 weight scratch (wq..wv); dead after
  // proj5 and long before topk16<0> writes the dense region (stream-ordered).
  ushort_t* w5_b = (ushort_t*)dense;

  char* ws = (char*)d_ws;
  const size_t MB = (size_t)1 << 20;
  // 0-64 MB: adjacency bf16 scores -> in-place weights (prop input);
  //          later reused for phase bf16 scores -> in-place weights (attnv).
  ushort_t* A_b  = (ushort_t*)(ws + 0 * MB);
  ushort_t* S2_b = A_b;                          // phase scores (A dead)
  ushort_t* dt0  = (ushort_t*)(ws + 64 * MB);    // 8 MB Dt0 [32][128][1024]
  ushort_t* dtA  = (ushort_t*)(ws + 72 * MB);    // 8 MB ping; P_b after prop
  ushort_t* P_b  = dtA;                          // packed [Ur|Ui] bf16
  ushort_t* dtB  = (ushort_t*)(ws + 80 * MB);    // 8 MB pong (final D)
  ushort_t* vt_b = (ushort_t*)(ws + 88 * MB);    // 4 MB Vt [32][64][1024]
  ushort_t* xb   = (ushort_t*)(ws + 92 * MB);    // 4 MB bf16 x; reused attn_b
  ushort_t* attn_b = xb;                         // alias (x dead after proj)
  ushort_t* qh_b = (ushort_t*)(ws + 96 * MB);    // 4 MB bf16 Q; wo_b after adj
  ushort_t* wo_b = qh_b;                         // alias (Q dead after scores)
  ushort_t* kh_b = (ushort_t*)(ws + 100 * MB);   // 4 MB bf16 K
  // total workspace: 104 MB

  const int rows = B_ * H_ * T_;  // 32768

  // 0. bf16 casts, one launch (W_O deferred until Q is dead)
  cast6_kernel<<<dim3(2048, 6), 256, 0, stream>>>(
      x, wq, wk, wre, wim, wv, xb, w5_b);

  // 1. all 5 projections (MFMA)
  proj5_mfma<<<dim3(8, 16, 5), 256, 0, stream>>>(
      xb, w5_b, qh_b, kh_b, dt0, vt_b);

  // 2. adjacency scores (bf16 -> A_b) + top-k (in-place bf16 weights)
  score_mfma<64, true><<<dim3(8, 8, 32), 256, 0, stream>>>(
      qh_b, kh_b, A_b, 0.125f);
  cast_bf16_kernel<<<1024, 256, 0, stream>>>(wo, wo_b, DM * DM / 4);  // Q dead
  topk16_kernel<1><<<rows / 4, 256, 0, stream>>>(A_b, nullptr);

  // 3. topology propagation x4 as batched MFMA GEMM (512 blocks each)
  prop_mfma<<<dim3(16, 32), 256, 0, stream>>>(A_b, dt0, dtA, logit_lam);
  prop_mfma<<<dim3(16, 32), 256, 0, stream>>>(A_b, dtA, dtB, logit_lam);
  prop_mfma<<<dim3(16, 32), 256, 0, stream>>>(A_b, dtB, dtA, logit_lam);
  prop_mfma<<<dim3(16, 32), 256, 0, stream>>>(A_b, dtA, dtB, logit_lam);

  // 4. finalize (+alpha*D0, normalize, transpose) -> P_b (over dead dtA)
  finalize_kernel<<<dim3(16, 32), 256, 0, stream>>>(dtB, dt0, P_b, log_alpha);

  // 5. phase scores (bf16 -> S2_b over dead A) + top-k:
  //    fp32 dense output + bf16 in-place weights for attnv
  score_mfma<128, true><<<dim3(8, 8, 32), 256, 0, stream>>>(
      P_b, P_b, S2_b, 11.3137085f);
  topk16_kernel<0><<<rows / 4, 256, 0, stream>>>(S2_b, dense);

  // 6. attn . V as MFMA from bf16 weights, then output projection
  attnv_mfma<<<dim3(16, 32), 256, 0, stream>>>(S2_b, vt_b, attn_b);
  score_mfma<DM, false><<<dim3(8, 16, 1), 256, 0, stream>>>(
      attn_b, wo_b, out, 1.0f);
}

// Round 10
// 342.723 us; speedup vs baseline: 20.5568x; 1.1039x over previous
//
#include <hip/hip_runtime.h>
#include <cstdint>
#include <cstddef>

// Problem constants
#define B_  2
#define T_  1024
#define DM  1024
#define H_  16
#define DK_ 64
#define TOPK 128

typedef unsigned short ushort_t;
typedef __attribute__((ext_vector_type(8))) short short8;
typedef __attribute__((ext_vector_type(8))) unsigned short u16x8;
typedef __attribute__((ext_vector_type(4))) float f32x4;

// monotone map bf16 bits -> u16 (bigger key == bigger float)
__device__ __forceinline__ unsigned fkey16(unsigned b) {
  return (b & 0x8000u) ? (0xffffu & ~b) : (b | 0x8000u);
}

// round-to-nearest-even float -> bf16
__device__ __forceinline__ ushort_t f2bf(float f) {
  unsigned u = __float_as_uint(f);
  return (ushort_t)((u + 0x7fffu + ((u >> 16) & 1u)) >> 16);
}
__device__ __forceinline__ float bf2f(ushort_t u) {
  return __uint_as_float((unsigned)u << 16);
}

// async global->LDS 16B copy (linear LDS dest; global src may be swizzled)
__device__ __forceinline__ void gload_lds16(const ushort_t* g, ushort_t* l) {
  __builtin_amdgcn_global_load_lds(
      (const __attribute__((address_space(1))) unsigned int*)(const void*)g,
      (__attribute__((address_space(3))) unsigned int*)(void*)l, 16, 0, 0);
}

// ---------- fused bf16 casts: x + 5 weights in one launch --------------------
__global__ __launch_bounds__(256) void cast6_kernel(
    const float* __restrict__ x, const float* __restrict__ wq,
    const float* __restrict__ wk, const float* __restrict__ wre,
    const float* __restrict__ wim, const float* __restrict__ wv,
    ushort_t* __restrict__ xb, ushort_t* __restrict__ w5b) {
  int z = blockIdx.y;
  const float* src; ushort_t* dst; int n4;
  switch (z) {
    case 0: src = x;   dst = xb;                 n4 = 524288; break;
    case 1: src = wq;  dst = w5b;                n4 = 262144; break;
    case 2: src = wk;  dst = w5b + 1048576;      n4 = 262144; break;
    case 3: src = wre; dst = w5b + 2097152;      n4 = 262144; break;
    case 4: src = wim; dst = w5b + 3145728;      n4 = 262144; break;
    default: src = wv; dst = w5b + 4194304;      n4 = 262144; break;
  }
  int i = blockIdx.x * 256 + threadIdx.x;
  if (i < n4) {
    float4 v = ((const float4*)src)[i];
    ushort4 o;
    o.x = f2bf(v.x); o.y = f2bf(v.y); o.z = f2bf(v.z); o.w = f2bf(v.w);
    ((ushort4*)dst)[i] = o;
  }
}

__global__ __launch_bounds__(256) void cast_bf16_kernel(
    const float* __restrict__ in, ushort_t* __restrict__ out, int n4) {
  int i = blockIdx.x * 256 + threadIdx.x;
  if (i < n4) {
    float4 v = ((const float4*)in)[i];
    ushort4 o;
    o.x = f2bf(v.x); o.y = f2bf(v.y); o.z = f2bf(v.z); o.w = f2bf(v.w);
    ((ushort4*)out)[i] = o;
  }
}

// ---------------------------------------------------------------------------
// bf16 MFMA NT GEMM core: 128x128 tile, BK=64, 4 waves (2x2), fp32 acc.
// Staging via global_load_lds (linear LDS dest, pre-swizzled global src).
// ---------------------------------------------------------------------------
template<int KDIM>
__device__ __forceinline__ void gemm_core(
    const ushort_t* __restrict__ Ab, const ushort_t* __restrict__ Bb,
    ushort_t* ldsA, ushort_t* ldsB, int tid, f32x4 acc[4][4]) {
  const int lane = tid & 63, wid = tid >> 6;
  const int wr = (wid >> 1) * 64, wc = (wid & 1) * 64;
  const int l15 = lane & 15, l4 = lane >> 4;
  for (int k0 = 0; k0 < KDIM; k0 += 64) {
    #pragma unroll
    for (int i = 0; i < 4; ++i) {
      int cid = tid + 256 * i;          // 1024 chunks of 16B per tile
      int row = cid >> 3, slot = cid & 7;
      int gc = slot ^ (row & 7);        // pre-swizzled global chunk
      gload_lds16(&Ab[(size_t)row * KDIM + k0 + gc * 8], &ldsA[cid * 8]);
      gload_lds16(&Bb[(size_t)row * KDIM + k0 + gc * 8], &ldsB[cid * 8]);
    }
    __syncthreads();
    #pragma unroll
    for (int ks = 0; ks < 2; ++ks) {
      short8 af[4], bfr[4];
      #pragma unroll
      for (int m = 0; m < 4; ++m) {
        int r = wr + m * 16 + l15;
        int c = ks * 4 + l4;
        af[m] = *(const short8*)&ldsA[r * 64 + (c ^ (r & 7)) * 8];
      }
      #pragma unroll
      for (int n = 0; n < 4; ++n) {
        int r = wc + n * 16 + l15;
        int c = ks * 4 + l4;
        bfr[n] = *(const short8*)&ldsB[r * 64 + (c ^ (r & 7)) * 8];
      }
      #pragma unroll
      for (int m = 0; m < 4; ++m)
        #pragma unroll
        for (int n = 0; n < 4; ++n)
          acc[m][n] = __builtin_amdgcn_mfma_f32_16x16x32_bf16(
              af[m], bfr[n], acc[m][n], 0, 0, 0);
    }
    __syncthreads();
  }
}

// ---------- fused 5-way projection (MFMA): out[z] = x . W[z]^T ---------------
// 1D grid 640, XCD-swizzled. z=0,1 -> head-major (Q,K); z=2,3 -> Dt0
// [head][dd][t]; z=4 -> Vt [head][d][t].
__global__ __launch_bounds__(256) void proj5_mfma(
    const ushort_t* __restrict__ xb, const ushort_t* __restrict__ wb,
    ushort_t* __restrict__ qh_b, ushort_t* __restrict__ kh_b,
    ushort_t* __restrict__ dt0, ushort_t* __restrict__ vt_b) {
  __shared__ ushort_t ldsA[128 * 64];
  __shared__ ushort_t ldsB[128 * 64];
  int tid = threadIdx.x;
  int orig = (blockIdx.x & 7) * 80 + (blockIdx.x >> 3);
  int bx = orig & 7, by = (orig >> 3) & 15, z = orig >> 7;
  const ushort_t* W = wb + (size_t)z * (DM * DM);
  f32x4 acc[4][4];
  #pragma unroll
  for (int m = 0; m < 4; ++m)
    #pragma unroll
    for (int n = 0; n < 4; ++n) acc[m][n] = (f32x4){0.f, 0.f, 0.f, 0.f};
  gemm_core<DM>(xb + (size_t)by * 128 * DM,
                W + (size_t)bx * 128 * DM, ldsA, ldsB, tid, acc);
  const int lane = tid & 63, wid = tid >> 6;
  int row0 = by * 128 + (wid >> 1) * 64 + (lane >> 4) * 4;
  int col0 = bx * 128 + (wid & 1) * 64 + (lane & 15);
  #pragma unroll
  for (int m = 0; m < 4; ++m)
    #pragma unroll
    for (int n = 0; n < 4; ++n)
      #pragma unroll
      for (int j = 0; j < 4; ++j) {
        int nr = row0 + m * 16 + j;
        int mc = col0 + n * 16;
        int b = nr >> 10, t = nr & 1023, h = mc >> 6, d = mc & 63;
        int head = b * H_ + h;
        float v = acc[m][n][j];
        if (z == 0) {
          qh_b[((size_t)head * T_ + t) * DK_ + d] = f2bf(v);
        } else if (z == 1) {
          kh_b[((size_t)head * T_ + t) * DK_ + d] = f2bf(v);
        } else if (z == 4) {
          vt_b[(size_t)head * 65536 + (size_t)d * 1024 + t] = f2bf(v);
        } else {
          int ddofs = (z == 3) ? 64 : 0;
          dt0[(size_t)head * 131072 + (size_t)(d + ddofs) * 1024 + t] = f2bf(v);
        }
      }
}

// ---------- batched NT MFMA GEMM -> scaled bf16 dense (1D grid 2048) --------
template<int KDIM>
__global__ __launch_bounds__(256) void score_mfma(
    const ushort_t* __restrict__ A, const ushort_t* __restrict__ Bm,
    ushort_t* __restrict__ Sout, float scale) {
  __shared__ ushort_t ldsA[128 * 64];
  __shared__ ushort_t ldsB[128 * 64];
  int tid = threadIdx.x;
  int orig = (blockIdx.x & 7) * 256 + (blockIdx.x >> 3);
  int bx = orig & 7, by = (orig >> 3) & 7, z = orig >> 6;
  f32x4 acc[4][4];
  #pragma unroll
  for (int m = 0; m < 4; ++m)
    #pragma unroll
    for (int n = 0; n < 4; ++n) acc[m][n] = (f32x4){0.f, 0.f, 0.f, 0.f};
  gemm_core<KDIM>(A + (size_t)z * T_ * KDIM + (size_t)by * 128 * KDIM,
                  Bm + (size_t)z * T_ * KDIM + (size_t)bx * 128 * KDIM,
                  ldsA, ldsB, tid, acc);
  const int lane = tid & 63, wid = tid >> 6;
  int row0 = by * 128 + (wid >> 1) * 64 + (lane >> 4) * 4;
  int col0 = bx * 128 + (wid & 1) * 64 + (lane & 15);
  ushort_t* Sz = Sout + (size_t)z * T_ * T_;
  #pragma unroll
  for (int m = 0; m < 4; ++m)
    #pragma unroll
    for (int n = 0; n < 4; ++n)
      #pragma unroll
      for (int j = 0; j < 4; ++j)
        Sz[(size_t)(row0 + m * 16 + j) * T_ + col0 + n * 16] =
            f2bf(acc[m][n][j] * scale);
}

// ---------- shared BM=64 x BN=128 x K=1024 MFMA loop -------------------------
__device__ __forceinline__ void mfma_64x128_loop(
    const ushort_t* __restrict__ Ah, const ushort_t* __restrict__ Bh,
    ushort_t* ldsA, ushort_t* ldsB, int tid, f32x4 acc[2][4]) {
  const int lane = tid & 63, wid = tid >> 6;
  const int wr = wid >> 1, wc = wid & 1;
  const int l15 = lane & 15, l4 = lane >> 4;
  for (int k0 = 0; k0 < 1024; k0 += 64) {
    #pragma unroll
    for (int i = 0; i < 2; ++i) {       // A: 512 chunks of 16B
      int cid = tid + 256 * i;
      int rowc = cid >> 3, slot = cid & 7;
      int gc = slot ^ (rowc & 7);
      gload_lds16(&Ah[(size_t)rowc * 1024 + k0 + gc * 8], &ldsA[cid * 8]);
    }
    #pragma unroll
    for (int i = 0; i < 4; ++i) {       // B: 1024 chunks of 16B
      int cid = tid + 256 * i;
      int rowc = cid >> 3, slot = cid & 7;
      int gc = slot ^ (rowc & 7);
      gload_lds16(&Bh[(size_t)rowc * 1024 + k0 + gc * 8], &ldsB[cid * 8]);
    }
    __syncthreads();
    #pragma unroll
    for (int ks = 0; ks < 2; ++ks) {
      short8 af[2], bfr[4];
      #pragma unroll
      for (int m = 0; m < 2; ++m) {
        int r = wr * 32 + m * 16 + l15;
        int c = ks * 4 + l4;
        af[m] = *(const short8*)&ldsA[r * 64 + (c ^ (r & 7)) * 8];
      }
      #pragma unroll
      for (int n = 0; n < 4; ++n) {
        int r = wc * 64 + n * 16 + l15;
        int c = ks * 4 + l4;
        bfr[n] = *(const short8*)&ldsB[r * 64 + (c ^ (r & 7)) * 8];
      }
      #pragma unroll
      for (int m = 0; m < 2; ++m)
        #pragma unroll
        for (int n = 0; n < 4; ++n)
          acc[m][n] = __builtin_amdgcn_mfma_f32_16x16x32_bf16(
              af[m], bfr[n], acc[m][n], 0, 0, 0);
    }
    __syncthreads();
  }
}

// ---------- propagation step (per head), BM=64, 1D grid 512, XCD-swizzled ---
__global__ __launch_bounds__(256) void prop_mfma(
    const ushort_t* __restrict__ Ab, const ushort_t* __restrict__ Dsrc,
    ushort_t* __restrict__ Ddst, const float* __restrict__ logit_lam) {
  __shared__ ushort_t ldsA[64 * 64];
  __shared__ ushort_t ldsB[128 * 64];
  int tid = threadIdx.x;
  int orig = (blockIdx.x & 7) * 64 + (blockIdx.x >> 3);
  int bx = orig & 15, hz = orig >> 4;
  const int lane = tid & 63, wid = tid >> 6;
  const int wr = wid >> 1, wc = wid & 1;
  const int l15 = lane & 15, l4 = lane >> 4;
  const ushort_t* Dh = Dsrc + (size_t)hz * 131072;
  f32x4 acc[2][4];
  #pragma unroll
  for (int m = 0; m < 2; ++m)
    #pragma unroll
    for (int n = 0; n < 4; ++n) acc[m][n] = (f32x4){0.f, 0.f, 0.f, 0.f};
  mfma_64x128_loop(Ab + (size_t)hz * 1048576 + (size_t)bx * 64 * 1024,
                   Dh, ldsA, ldsB, tid, acc);
  float lam = 1.f / (1.f + __expf(-logit_lam[0]));
  ushort_t* Dd = Ddst + (size_t)hz * 131072;
  #pragma unroll
  for (int m = 0; m < 2; ++m)
    #pragma unroll
    for (int n = 0; n < 4; ++n)
      #pragma unroll
      for (int j = 0; j < 4; ++j) {
        int t = bx * 64 + wr * 32 + m * 16 + l4 * 4 + j;
        int dd = wc * 64 + n * 16 + l15;
        size_t o = (size_t)dd * 1024 + t;
        float oldv = bf2f(Dh[o]);
        Dd[o] = f2bf((1.f - lam) * oldv + lam * acc[m][n][j]);
      }
}

// ---------- final prop step fused with finalize: blend + alpha*D0 + norm ----
// Block covers 64 t x ALL 128 dd -> per-t norm in-block; writes P[t][dd].
__global__ __launch_bounds__(256) void prop_final_mfma(
    const ushort_t* __restrict__ Ab, const ushort_t* __restrict__ Dsrc,
    const ushort_t* __restrict__ Dt0, ushort_t* __restrict__ P,
    const float* __restrict__ logit_lam, const float* __restrict__ log_alpha) {
  __shared__ ushort_t ldsA[64 * 64];
  __shared__ ushort_t ldsB[128 * 64];
  __shared__ float sums[4][2][4][4];   // [wid][m][j][l4]
  int tid = threadIdx.x;
  int orig = (blockIdx.x & 7) * 64 + (blockIdx.x >> 3);
  int bx = orig & 15, hz = orig >> 4;
  const int lane = tid & 63, wid = tid >> 6;
  const int wr = wid >> 1, wc = wid & 1;
  const int l15 = lane & 15, l4 = lane >> 4;
  const ushort_t* Dh = Dsrc + (size_t)hz * 131072;
  f32x4 acc[2][4];
  #pragma unroll
  for (int m = 0; m < 2; ++m)
    #pragma unroll
    for (int n = 0; n < 4; ++n) acc[m][n] = (f32x4){0.f, 0.f, 0.f, 0.f};
  mfma_64x128_loop(Ab + (size_t)hz * 1048576 + (size_t)bx * 64 * 1024,
                   Dh, ldsA, ldsB, tid, acc);
  float lam = 1.f / (1.f + __expf(-logit_lam[0]));
  float alpha = 1.f / (1.f + __expf(-log_alpha[0]));
  const ushort_t* D0h = Dt0 + (size_t)hz * 131072;
  float F[2][4][4];
  float ssp[2][4];
  #pragma unroll
  for (int m = 0; m < 2; ++m)
    #pragma unroll
    for (int j = 0; j < 4; ++j) {
      int t = bx * 64 + wr * 32 + m * 16 + l4 * 4 + j;
      float s = 0.f;
      #pragma unroll
      for (int n = 0; n < 4; ++n) {
        int dd = wc * 64 + n * 16 + l15;
        size_t o = (size_t)dd * 1024 + t;
        float f = (1.f - lam) * bf2f(Dh[o]) + lam * acc[m][n][j] +
                  alpha * bf2f(D0h[o]);
        F[m][n][j] = f;
        s += f * f;
      }
      #pragma unroll
      for (int off = 1; off < 16; off <<= 1) s += __shfl_xor(s, off);
      ssp[m][j] = s;
    }
  if (l15 == 0) {
    #pragma unroll
    for (int m = 0; m < 2; ++m)
      #pragma unroll
      for (int j = 0; j < 4; ++j)
        sums[wid][m][j][l4] = ssp[m][j];
  }
  __syncthreads();
  ushort_t* Ph = P + (size_t)hz * 1024 * 128;
  #pragma unroll
  for (int m = 0; m < 2; ++m)
    #pragma unroll
    for (int j = 0; j < 4; ++j) {
      float tot = sums[wid][m][j][l4] + sums[wid ^ 1][m][j][l4];
      float ni = 1.f / fmaxf(sqrtf(tot), 1e-6f);
      int t = bx * 64 + wr * 32 + m * 16 + l4 * 4 + j;
      #pragma unroll
      for (int n = 0; n < 4; ++n) {
        int dd = wc * 64 + n * 16 + l15;
        Ph[(size_t)t * 128 + dd] = f2bf(F[m][n][j] * ni);
      }
    }
}

// ---------------------------------------------------------------------------
// Wave-synchronous exact top-128 on bf16 scores via 16-step ballot binary
// search (no LDS / atomics / barriers). Tie -> lower index via ballot rank.
// MODE 0: fp32 dense write (phase output) + bf16 in-place WB (attnv input).
// MODE 1: bf16 in-place WB only.
// ---------------------------------------------------------------------------
template<int MODE>
__global__ __launch_bounds__(256) void topk16_kernel(
    ushort_t* __restrict__ Sb, float* __restrict__ denseOut) {
  const int tid = threadIdx.x;
  const int lane = tid & 63, wv = tid >> 6;
  const int row = blockIdx.x * 4 + wv;
  ushort_t* Srow = Sb + (size_t)row * 1024;

  float scr[2][8];
  unsigned kk[2][8];
  #pragma unroll
  for (int g = 0; g < 2; ++g) {
    u16x8 v = *(const u16x8*)&Srow[g * 512 + lane * 8];
    #pragma unroll
    for (int e = 0; e < 8; ++e) {
      scr[g][e] = bf2f(v[e]);
      kk[g][e] = fkey16((unsigned)v[e]);
    }
  }

  unsigned prefix = 0, r = TOPK;
  #pragma unroll
  for (int b = 15; b >= 0; --b) {
    unsigned want = (prefix << 1) | 1u;
    unsigned cnt = 0;
    #pragma unroll
    for (int g = 0; g < 2; ++g)
      #pragma unroll
      for (int e = 0; e < 8; ++e)
        cnt += (unsigned)__popcll(__ballot((kk[g][e] >> b) == want));
    if (cnt >= r) prefix = want;
    else { prefix <<= 1; r -= cnt; }
  }
  const unsigned thr = prefix;

  float mx = -3.402823466e38f;
  #pragma unroll
  for (int g = 0; g < 2; ++g)
    #pragma unroll
    for (int e = 0; e < 8; ++e) mx = fmaxf(mx, scr[g][e]);
  #pragma unroll
  for (int off = 1; off < 64; off <<= 1) mx = fmaxf(mx, __shfl_xor(mx, off));

  const unsigned long long below = (1ull << lane) - 1ull;
  unsigned cum = 0;
  float w[2][8];
  float ps = 0.f;
  #pragma unroll
  for (int g = 0; g < 2; ++g) {
    unsigned long long bal[8];
    #pragma unroll
    for (int e = 0; e < 8; ++e) bal[e] = __ballot(kk[g][e] == thr);
    unsigned rb = cum;
    #pragma unroll
    for (int e = 0; e < 8; ++e) rb += (unsigned)__popcll(bal[e] & below);
    unsigned ownPrior = 0;
    #pragma unroll
    for (int e = 0; e < 8; ++e) {
      bool eq = (kk[g][e] == thr);
      bool sel = (kk[g][e] > thr) || (eq && (rb + ownPrior) < r);
      ownPrior += eq ? 1u : 0u;
      float ex = sel ? __expf(scr[g][e] - mx) : 0.f;
      w[g][e] = ex;
      ps += ex;
    }
    #pragma unroll
    for (int e = 0; e < 8; ++e) cum += (unsigned)__popcll(bal[e]);
  }
  float pss = ps;
  #pragma unroll
  for (int off = 1; off < 64; off <<= 1) pss += __shfl_xor(pss, off);
  const float inv = 1.f / pss;

  if (MODE == 0) {
    float* Drow = denseOut + (size_t)row * 1024;
    #pragma unroll
    for (int g = 0; g < 2; ++g) {
      *(float4*)&Drow[g * 512 + lane * 8] =
          make_float4(w[g][0] * inv, w[g][1] * inv, w[g][2] * inv, w[g][3] * inv);
      *(float4*)&Drow[g * 512 + lane * 8 + 4] =
          make_float4(w[g][4] * inv, w[g][5] * inv, w[g][6] * inv, w[g][7] * inv);
    }
  }
  #pragma unroll
  for (int g = 0; g < 2; ++g) {
    u16x8 o;
    #pragma unroll
    for (int e = 0; e < 8; ++e) o[e] = f2bf(w[g][e] * inv);
    *(u16x8*)&Srow[g * 512 + lane * 8] = o;
  }
}

// ---------- attn.V as MFMA (BM=64), 1D grid 512, XCD-swizzled ---------------
__global__ __launch_bounds__(256) void attnv_mfma(
    const ushort_t* __restrict__ Wb, const ushort_t* __restrict__ Vt,
    ushort_t* __restrict__ attn_b) {
  __shared__ ushort_t ldsA[64 * 64];
  __shared__ ushort_t ldsB[64 * 64];
  int tid = threadIdx.x;
  int orig = (blockIdx.x & 7) * 64 + (blockIdx.x >> 3);
  int bx = orig & 15, hz = orig >> 4;
  const int lane = tid & 63, wid = tid >> 6;
  const int wr = wid >> 1, wc = wid & 1;
  const int l15 = lane & 15, l4 = lane >> 4;
  const ushort_t* Wh = Wb + (size_t)hz * 1048576 + (size_t)bx * 64 * 1024;
  const ushort_t* Vh = Vt + (size_t)hz * 65536;
  f32x4 acc[2][2];
  #pragma unroll
  for (int m = 0; m < 2; ++m)
    #pragma unroll
    for (int n = 0; n < 2; ++n) acc[m][n] = (f32x4){0.f, 0.f, 0.f, 0.f};
  for (int k0 = 0; k0 < 1024; k0 += 64) {
    #pragma unroll
    for (int i = 0; i < 2; ++i) {
      int cid = tid + 256 * i;
      int rowc = cid >> 3, slot = cid & 7;
      int gc = slot ^ (rowc & 7);
      gload_lds16(&Wh[(size_t)rowc * 1024 + k0 + gc * 8], &ldsA[cid * 8]);
    }
    #pragma unroll
    for (int i = 0; i < 2; ++i) {
      int cid = tid + 256 * i;
      int rowc = cid >> 3, slot = cid & 7;
      int gc = slot ^ (rowc & 7);
      gload_lds16(&Vh[(size_t)rowc * 1024 + k0 + gc * 8], &ldsB[cid * 8]);
    }
    __syncthreads();
    #pragma unroll
    for (int ks = 0; ks < 2; ++ks) {
      short8 af[2], bfr[2];
      #pragma unroll
      for (int m = 0; m < 2; ++m) {
        int r = wr * 32 + m * 16 + l15;
        int c = ks * 4 + l4;
        af[m] = *(const short8*)&ldsA[r * 64 + (c ^ (r & 7)) * 8];
      }
      #pragma unroll
      for (int n = 0; n < 2; ++n) {
        int r = wc * 32 + n * 16 + l15;
        int c = ks * 4 + l4;
        bfr[n] = *(const short8*)&ldsB[r * 64 + (c ^ (r & 7)) * 8];
      }
      #pragma unroll
      for (int m = 0; m < 2; ++m)
        #pragma unroll
        for (int n = 0; n < 2; ++n)
          acc[m][n] = __builtin_amdgcn_mfma_f32_16x16x32_bf16(
              af[m], bfr[n], acc[m][n], 0, 0, 0);
    }
    __syncthreads();
  }
  int b = hz >> 4, h = hz & 15;
  #pragma unroll
  for (int m = 0; m < 2; ++m)
    #pragma unroll
    for (int n = 0; n < 2; ++n)
      #pragma unroll
      for (int j = 0; j < 4; ++j) {
        int t = bx * 64 + wr * 32 + m * 16 + l4 * 4 + j;
        int d = wc * 32 + n * 16 + l15;
        attn_b[((size_t)(b * T_ + t)) * DM + h * DK_ + d] = f2bf(acc[m][n][j]);
      }
}

// ---------- output projection: BM=64 x BN=128 x K=1024, grid 256 ------------
__global__ __launch_bounds__(256) void outproj_mfma(
    const ushort_t* __restrict__ A, const ushort_t* __restrict__ Wo,
    float* __restrict__ out) {
  __shared__ ushort_t ldsA[64 * 64];
  __shared__ ushort_t ldsB[128 * 64];
  int tid = threadIdx.x;
  int orig = (blockIdx.x & 7) * 32 + (blockIdx.x >> 3);
  int bx = orig & 7, by = orig >> 3;   // bx: 128-col tile, by: 64-row tile
  const int lane = tid & 63, wid = tid >> 6;
  const int wr = wid >> 1, wc = wid & 1;
  const int l15 = lane & 15, l4 = lane >> 4;
  f32x4 acc[2][4];
  #pragma unroll
  for (int m = 0; m < 2; ++m)
    #pragma unroll
    for (int n = 0; n < 4; ++n) acc[m][n] = (f32x4){0.f, 0.f, 0.f, 0.f};
  mfma_64x128_loop(A + (size_t)by * 64 * 1024,
                   Wo + (size_t)bx * 128 * 1024, ldsA, ldsB, tid, acc);
  #pragma unroll
  for (int m = 0; m < 2; ++m)
    #pragma unroll
    for (int n = 0; n < 4; ++n)
      #pragma unroll
      for (int j = 0; j < 4; ++j) {
        int r = by * 64 + wr * 32 + m * 16 + l4 * 4 + j;
        int c = bx * 128 + wc * 64 + n * 16 + l15;
        out[(size_t)r * 1024 + c] = acc[m][n][j];
      }
}

extern "C" void kernel_launch(void* const* d_in, const int* in_sizes, int n_in,
                              void* d_out, int out_size, void* d_ws, size_t ws_size,
                              hipStream_t stream) {
  (void)in_sizes; (void)n_in; (void)out_size; (void)ws_size;
  const float* x         = (const float*)d_in[0];
  const float* wq        = (const float*)d_in[1];
  const float* wk        = (const float*)d_in[2];
  const float* wre       = (const float*)d_in[3];
  const float* wim       = (const float*)d_in[4];
  const float* wv        = (const float*)d_in[5];
  const float* wo        = (const float*)d_in[6];
  const float* logit_lam = (const float*)d_in[7];
  const float* log_alpha = (const float*)d_in[8];

  float* out   = (float*)d_out;                 // (B,T,DM)
  float* dense = out + (size_t)B_ * T_ * DM;    // phase_attn (B,H,T,T) fp32 out
  // first 10 MB of dense doubles as bf16 weight scratch (wq..wv); dead after
  // proj5 and long before topk16<0> writes the dense region (stream-ordered).
  ushort_t* w5_b = (ushort_t*)dense;

  char* ws = (char*)d_ws;
  const size_t MB = (size_t)1 << 20;
  // 0-64 MB: adjacency bf16 scores -> in-place weights (prop input);
  //          later reused for phase bf16 scores -> in-place weights (attnv).
  ushort_t* A_b  = (ushort_t*)(ws + 0 * MB);
  ushort_t* S2_b = A_b;                          // phase scores (A dead)
  ushort_t* dt0  = (ushort_t*)(ws + 64 * MB);    // 8 MB Dt0 [32][128][1024]
  ushort_t* dtA  = (ushort_t*)(ws + 72 * MB);    // 8 MB ping
  ushort_t* dtB  = (ushort_t*)(ws + 80 * MB);    // 8 MB pong; P_b after prop3
  ushort_t* P_b  = dtB;                          // packed [t][Ur|Ui] bf16
  ushort_t* vt_b = (ushort_t*)(ws + 88 * MB);    // 4 MB Vt [32][64][1024]
  ushort_t* xb   = (ushort_t*)(ws + 92 * MB);    // 4 MB bf16 x; reused attn_b
  ushort_t* attn_b = xb;                         // alias (x dead after proj)
  ushort_t* qh_b = (ushort_t*)(ws + 96 * MB);    // 4 MB bf16 Q; wo_b after adj
  ushort_t* wo_b = qh_b;                         // alias (Q dead after scores)
  ushort_t* kh_b = (ushort_t*)(ws + 100 * MB);   // 4 MB bf16 K
  // total workspace: 104 MB

  const int rows = B_ * H_ * T_;  // 32768

  // 0. bf16 casts, one launch (W_O deferred until Q is dead)
  cast6_kernel<<<dim3(2048, 6), 256, 0, stream>>>(
      x, wq, wk, wre, wim, wv, xb, w5_b);

  // 1. all 5 projections (MFMA)
  proj5_mfma<<<640, 256, 0, stream>>>(xb, w5_b, qh_b, kh_b, dt0, vt_b);

  // 2. adjacency scores (bf16 -> A_b) + top-k (in-place bf16 weights)
  score_mfma<64><<<2048, 256, 0, stream>>>(qh_b, kh_b, A_b, 0.125f);
  cast_bf16_kernel<<<1024, 256, 0, stream>>>(wo, wo_b, DM * DM / 4);  // Q dead
  topk16_kernel<1><<<rows / 4, 256, 0, stream>>>(A_b, nullptr);

  // 3. topology propagation: 3 plain steps + final step fused with finalize
  prop_mfma<<<512, 256, 0, stream>>>(A_b, dt0, dtA, logit_lam);
  prop_mfma<<<512, 256, 0, stream>>>(A_b, dtA, dtB, logit_lam);
  prop_mfma<<<512, 256, 0, stream>>>(A_b, dtB, dtA, logit_lam);
  prop_final_mfma<<<512, 256, 0, stream>>>(A_b, dtA, dt0, P_b,
                                           logit_lam, log_alpha);

  // 4. phase scores (bf16 -> S2_b over dead A) + top-k:
  //    fp32 dense output + bf16 in-place weights for attnv
  score_mfma<128><<<2048, 256, 0, stream>>>(P_b, P_b, S2_b, 11.3137085f);
  topk16_kernel<0><<<rows / 4, 256, 0, stream>>>(S2_b, dense);

  // 5. attn . V as MFMA from bf16 weights, then output projection
  attnv_mfma<<<512, 256, 0, stream>>>(S2_b, vt_b, attn_b);
  outproj_mfma<<<256, 256, 0, stream>>>(attn_b, wo_b, out);
}

// Round 12
// 336.685 us; speedup vs baseline: 20.9254x; 1.0179x over previous
//
#include <hip/hip_runtime.h>
#include <cstdint>
#include <cstddef>

// Problem constants
#define B_  2
#define T_  1024
#define DM  1024
#define H_  16
#define DK_ 64
#define TOPK 128

typedef unsigned short ushort_t;
typedef __attribute__((ext_vector_type(8))) short short8;
typedef __attribute__((ext_vector_type(8))) unsigned short u16x8;
typedef __attribute__((ext_vector_type(4))) float f32x4;

// monotone map bf16 bits -> u16 (bigger key == bigger float)
__device__ __forceinline__ unsigned fkey16(unsigned b) {
  return (b & 0x8000u) ? (0xffffu & ~b) : (b | 0x8000u);
}

// round-to-nearest-even float -> bf16
__device__ __forceinline__ ushort_t f2bf(float f) {
  unsigned u = __float_as_uint(f);
  return (ushort_t)((u + 0x7fffu + ((u >> 16) & 1u)) >> 16);
}
__device__ __forceinline__ float bf2f(ushort_t u) {
  return __uint_as_float((unsigned)u << 16);
}

// async global->LDS 16B copy (linear LDS dest; global src may be swizzled)
__device__ __forceinline__ void gload_lds16(const ushort_t* g, ushort_t* l) {
  __builtin_amdgcn_global_load_lds(
      (const __attribute__((address_space(1))) unsigned int*)(const void*)g,
      (__attribute__((address_space(3))) unsigned int*)(void*)l, 16, 0, 0);
}

// ---------- fused bf16 casts: x + 5 weights in one launch --------------------
__global__ __launch_bounds__(256) void cast6_kernel(
    const float* __restrict__ x, const float* __restrict__ wq,
    const float* __restrict__ wk, const float* __restrict__ wre,
    const float* __restrict__ wim, const float* __restrict__ wv,
    ushort_t* __restrict__ xb, ushort_t* __restrict__ w5b) {
  int z = blockIdx.y;
  const float* src; ushort_t* dst; int n4;
  switch (z) {
    case 0: src = x;   dst = xb;                 n4 = 524288; break;
    case 1: src = wq;  dst = w5b;                n4 = 262144; break;
    case 2: src = wk;  dst = w5b + 1048576;      n4 = 262144; break;
    case 3: src = wre; dst = w5b + 2097152;      n4 = 262144; break;
    case 4: src = wim; dst = w5b + 3145728;      n4 = 262144; break;
    default: src = wv; dst = w5b + 4194304;      n4 = 262144; break;
  }
  int i = blockIdx.x * 256 + threadIdx.x;
  if (i < n4) {
    float4 v = ((const float4*)src)[i];
    ushort4 o;
    o.x = f2bf(v.x); o.y = f2bf(v.y); o.z = f2bf(v.z); o.w = f2bf(v.w);
    ((ushort4*)dst)[i] = o;
  }
}

__global__ __launch_bounds__(256) void cast_bf16_kernel(
    const float* __restrict__ in, ushort_t* __restrict__ out, int n4) {
  int i = blockIdx.x * 256 + threadIdx.x;
  if (i < n4) {
    float4 v = ((const float4*)in)[i];
    ushort4 o;
    o.x = f2bf(v.x); o.y = f2bf(v.y); o.z = f2bf(v.z); o.w = f2bf(v.w);
    ((ushort4*)out)[i] = o;
  }
}

// ---------------------------------------------------------------------------
// bf16 MFMA NT GEMM core: 128x128 tile, BK=64, 4 waves (2x2), fp32 acc.
// Staging via global_load_lds (linear LDS dest, pre-swizzled global src).
// ---------------------------------------------------------------------------
template<int KDIM>
__device__ __forceinline__ void gemm_core(
    const ushort_t* __restrict__ Ab, const ushort_t* __restrict__ Bb,
    ushort_t* ldsA, ushort_t* ldsB, int tid, f32x4 acc[4][4]) {
  const int lane = tid & 63, wid = tid >> 6;
  const int wr = (wid >> 1) * 64, wc = (wid & 1) * 64;
  const int l15 = lane & 15, l4 = lane >> 4;
  for (int k0 = 0; k0 < KDIM; k0 += 64) {
    #pragma unroll
    for (int i = 0; i < 4; ++i) {
      int cid = tid + 256 * i;          // 1024 chunks of 16B per tile
      int row = cid >> 3, slot = cid & 7;
      int gc = slot ^ (row & 7);        // pre-swizzled global chunk
      gload_lds16(&Ab[(size_t)row * KDIM + k0 + gc * 8], &ldsA[cid * 8]);
      gload_lds16(&Bb[(size_t)row * KDIM + k0 + gc * 8], &ldsB[cid * 8]);
    }
    __syncthreads();
    #pragma unroll
    for (int ks = 0; ks < 2; ++ks) {
      short8 af[4], bfr[4];
      #pragma unroll
      for (int m = 0; m < 4; ++m) {
        int r = wr + m * 16 + l15;
        int c = ks * 4 + l4;
        af[m] = *(const short8*)&ldsA[r * 64 + (c ^ (r & 7)) * 8];
      }
      #pragma unroll
      for (int n = 0; n < 4; ++n) {
        int r = wc + n * 16 + l15;
        int c = ks * 4 + l4;
        bfr[n] = *(const short8*)&ldsB[r * 64 + (c ^ (r & 7)) * 8];
      }
      #pragma unroll
      for (int m = 0; m < 4; ++m)
        #pragma unroll
        for (int n = 0; n < 4; ++n)
          acc[m][n] = __builtin_amdgcn_mfma_f32_16x16x32_bf16(
              af[m], bfr[n], acc[m][n], 0, 0, 0);
    }
    __syncthreads();
  }
}

// ---------- fused 5-way projection (MFMA): out[z] = x . W[z]^T ---------------
// 1D grid 640, XCD-swizzled. z=0,1 -> head-major (Q,K); z=2,3 -> Dt0
// [head][dd][t]; z=4 -> Vt [head][d][t].
__global__ __launch_bounds__(256) void proj5_mfma(
    const ushort_t* __restrict__ xb, const ushort_t* __restrict__ wb,
    ushort_t* __restrict__ qh_b, ushort_t* __restrict__ kh_b,
    ushort_t* __restrict__ dt0, ushort_t* __restrict__ vt_b) {
  __shared__ ushort_t ldsA[128 * 64];
  __shared__ ushort_t ldsB[128 * 64];
  int tid = threadIdx.x;
  int orig = (blockIdx.x & 7) * 80 + (blockIdx.x >> 3);
  int bx = orig & 7, by = (orig >> 3) & 15, z = orig >> 7;
  const ushort_t* W = wb + (size_t)z * (DM * DM);
  f32x4 acc[4][4];
  #pragma unroll
  for (int m = 0; m < 4; ++m)
    #pragma unroll
    for (int n = 0; n < 4; ++n) acc[m][n] = (f32x4){0.f, 0.f, 0.f, 0.f};
  gemm_core<DM>(xb + (size_t)by * 128 * DM,
                W + (size_t)bx * 128 * DM, ldsA, ldsB, tid, acc);
  const int lane = tid & 63, wid = tid >> 6;
  int row0 = by * 128 + (wid >> 1) * 64 + (lane >> 4) * 4;
  int col0 = bx * 128 + (wid & 1) * 64 + (lane & 15);
  #pragma unroll
  for (int m = 0; m < 4; ++m)
    #pragma unroll
    for (int n = 0; n < 4; ++n)
      #pragma unroll
      for (int j = 0; j < 4; ++j) {
        int nr = row0 + m * 16 + j;
        int mc = col0 + n * 16;
        int b = nr >> 10, t = nr & 1023, h = mc >> 6, d = mc & 63;
        int head = b * H_ + h;
        float v = acc[m][n][j];
        if (z == 0) {
          qh_b[((size_t)head * T_ + t) * DK_ + d] = f2bf(v);
        } else if (z == 1) {
          kh_b[((size_t)head * T_ + t) * DK_ + d] = f2bf(v);
        } else if (z == 4) {
          vt_b[(size_t)head * 65536 + (size_t)d * 1024 + t] = f2bf(v);
        } else {
          int ddofs = (z == 3) ? 64 : 0;
          dt0[(size_t)head * 131072 + (size_t)(d + ddofs) * 1024 + t] = f2bf(v);
        }
      }
}

// ---------- batched NT MFMA GEMM -> scaled bf16 dense (adjacency) -----------
template<int KDIM>
__global__ __launch_bounds__(256) void score_mfma(
    const ushort_t* __restrict__ A, const ushort_t* __restrict__ Bm,
    ushort_t* __restrict__ Sout, float scale) {
  __shared__ ushort_t ldsA[128 * 64];
  __shared__ ushort_t ldsB[128 * 64];
  int tid = threadIdx.x;
  int orig = (blockIdx.x & 7) * 256 + (blockIdx.x >> 3);
  int bx = orig & 7, by = (orig >> 3) & 7, z = orig >> 6;
  f32x4 acc[4][4];
  #pragma unroll
  for (int m = 0; m < 4; ++m)
    #pragma unroll
    for (int n = 0; n < 4; ++n) acc[m][n] = (f32x4){0.f, 0.f, 0.f, 0.f};
  gemm_core<KDIM>(A + (size_t)z * T_ * KDIM + (size_t)by * 128 * KDIM,
                  Bm + (size_t)z * T_ * KDIM + (size_t)bx * 128 * KDIM,
                  ldsA, ldsB, tid, acc);
  const int lane = tid & 63, wid = tid >> 6;
  int row0 = by * 128 + (wid >> 1) * 64 + (lane >> 4) * 4;
  int col0 = bx * 128 + (wid & 1) * 64 + (lane & 15);
  ushort_t* Sz = Sout + (size_t)z * T_ * T_;
  #pragma unroll
  for (int m = 0; m < 4; ++m)
    #pragma unroll
    for (int n = 0; n < 4; ++n)
      #pragma unroll
      for (int j = 0; j < 4; ++j)
        Sz[(size_t)(row0 + m * 16 + j) * T_ + col0 + n * 16] =
            f2bf(acc[m][n][j] * scale);
}

// ---------- symmetric phase score: S = scale * P P^T (upper triangle) -------
// 36 tile-pairs per head x 32 heads = 1152 blocks; mirror tile written via
// XOR-swizzled LDS transpose so both writes stay coalesced. Mirror values are
// bitwise-identical to the full compute (fp mul is commutative; same k order).
__global__ __launch_bounds__(256) void score_sym_mfma(
    const ushort_t* __restrict__ P, ushort_t* __restrict__ Sout, float scale) {
  __shared__ ushort_t lds[128 * 128];  // 32 KB; first 16 KB=A, next 16 KB=B
  ushort_t* ldsA = lds;
  ushort_t* ldsB = lds + 128 * 64;
  int tid = threadIdx.x;
  int swz = (blockIdx.x & 7) * 144 + (blockIdx.x >> 3);  // 1152 = 8*144
  int z = swz / 36, t = swz % 36;
  int by = 0, rem = t;
  while (rem >= 8 - by) { rem -= 8 - by; ++by; }
  int bx = by + rem;
  const ushort_t* Pz = P + (size_t)z * T_ * 128;
  f32x4 acc[4][4];
  #pragma unroll
  for (int m = 0; m < 4; ++m)
    #pragma unroll
    for (int n = 0; n < 4; ++n) acc[m][n] = (f32x4){0.f, 0.f, 0.f, 0.f};
  gemm_core<128>(Pz + (size_t)by * 128 * 128, Pz + (size_t)bx * 128 * 128,
                 ldsA, ldsB, tid, acc);
  const int lane = tid & 63, wid = tid >> 6;
  const int l15 = lane & 15, l4 = lane >> 4;
  ushort_t* Sz = Sout + (size_t)z * T_ * T_;
  int row0 = by * 128 + (wid >> 1) * 64 + l4 * 4;
  int col0 = bx * 128 + (wid & 1) * 64 + l15;
  #pragma unroll
  for (int m = 0; m < 4; ++m)
    #pragma unroll
    for (int n = 0; n < 4; ++n)
      #pragma unroll
      for (int j = 0; j < 4; ++j)
        Sz[(size_t)(row0 + m * 16 + j) * T_ + col0 + n * 16] =
            f2bf(acc[m][n][j] * scale);
  if (bx != by) {
    // local coords within the 128x128 tile
    int lr0 = (wid >> 1) * 64 + l4 * 4;
    int lc0 = (wid & 1) * 64 + l15;
    #pragma unroll
    for (int m = 0; m < 4; ++m)
      #pragma unroll
      for (int n = 0; n < 4; ++n)
        #pragma unroll
        for (int j = 0; j < 4; ++j) {
          int lr = lr0 + m * 16 + j;
          int lc = lc0 + n * 16;
          lds[lc * 128 + (lr ^ ((lc & 15) << 3))] = f2bf(acc[m][n][j] * scale);
        }
    __syncthreads();
    int p = tid >> 1, qh = (tid & 1) * 64;
    int s = (p & 15) << 3;
    ushort_t* dstRow = Sz + (size_t)(bx * 128 + p) * T_ + by * 128 + qh;
    #pragma unroll
    for (int qc = 0; qc < 8; ++qc)
      *(u16x8*)&dstRow[qc * 8] =
          *(const u16x8*)&lds[p * 128 + ((qh + qc * 8) ^ s)];
  }
}

// ---------- shared BM=64 x BN=128 x K=1024 MFMA loop -------------------------
__device__ __forceinline__ void mfma_64x128_loop(
    const ushort_t* __restrict__ Ah, const ushort_t* __restrict__ Bh,
    ushort_t* ldsA, ushort_t* ldsB, int tid, f32x4 acc[2][4]) {
  const int lane = tid & 63, wid = tid >> 6;
  const int wr = wid >> 1, wc = wid & 1;
  const int l15 = lane & 15, l4 = lane >> 4;
  for (int k0 = 0; k0 < 1024; k0 += 64) {
    #pragma unroll
    for (int i = 0; i < 2; ++i) {       // A: 512 chunks of 16B
      int cid = tid + 256 * i;
      int rowc = cid >> 3, slot = cid & 7;
      int gc = slot ^ (rowc & 7);
      gload_lds16(&Ah[(size_t)rowc * 1024 + k0 + gc * 8], &ldsA[cid * 8]);
    }
    #pragma unroll
    for (int i = 0; i < 4; ++i) {       // B: 1024 chunks of 16B
      int cid = tid + 256 * i;
      int rowc = cid >> 3, slot = cid & 7;
      int gc = slot ^ (rowc & 7);
      gload_lds16(&Bh[(size_t)rowc * 1024 + k0 + gc * 8], &ldsB[cid * 8]);
    }
    __syncthreads();
    #pragma unroll
    for (int ks = 0; ks < 2; ++ks) {
      short8 af[2], bfr[4];
      #pragma unroll
      for (int m = 0; m < 2; ++m) {
        int r = wr * 32 + m * 16 + l15;
        int c = ks * 4 + l4;
        af[m] = *(const short8*)&ldsA[r * 64 + (c ^ (r & 7)) * 8];
      }
      #pragma unroll
      for (int n = 0; n < 4; ++n) {
        int r = wc * 64 + n * 16 + l15;
        int c = ks * 4 + l4;
        bfr[n] = *(const short8*)&ldsB[r * 64 + (c ^ (r & 7)) * 8];
      }
      #pragma unroll
      for (int m = 0; m < 2; ++m)
        #pragma unroll
        for (int n = 0; n < 4; ++n)
          acc[m][n] = __builtin_amdgcn_mfma_f32_16x16x32_bf16(
              af[m], bfr[n], acc[m][n], 0, 0, 0);
    }
    __syncthreads();
  }
}

// ---------- propagation step (per head), BM=64, 1D grid 512, XCD-swizzled ---
__global__ __launch_bounds__(256) void prop_mfma(
    const ushort_t* __restrict__ Ab, const ushort_t* __restrict__ Dsrc,
    ushort_t* __restrict__ Ddst, const float* __restrict__ logit_lam) {
  __shared__ ushort_t ldsA[64 * 64];
  __shared__ ushort_t ldsB[128 * 64];
  int tid = threadIdx.x;
  int orig = (blockIdx.x & 7) * 64 + (blockIdx.x >> 3);
  int bx = orig & 15, hz = orig >> 4;
  const int lane = tid & 63, wid = tid >> 6;
  const int wr = wid >> 1, wc = wid & 1;
  const int l15 = lane & 15, l4 = lane >> 4;
  const ushort_t* Dh = Dsrc + (size_t)hz * 131072;
  f32x4 acc[2][4];
  #pragma unroll
  for (int m = 0; m < 2; ++m)
    #pragma unroll
    for (int n = 0; n < 4; ++n) acc[m][n] = (f32x4){0.f, 0.f, 0.f, 0.f};
  mfma_64x128_loop(Ab + (size_t)hz * 1048576 + (size_t)bx * 64 * 1024,
                   Dh, ldsA, ldsB, tid, acc);
  float lam = 1.f / (1.f + __expf(-logit_lam[0]));
  ushort_t* Dd = Ddst + (size_t)hz * 131072;
  #pragma unroll
  for (int m = 0; m < 2; ++m)
    #pragma unroll
    for (int n = 0; n < 4; ++n)
      #pragma unroll
      for (int j = 0; j < 4; ++j) {
        int t = bx * 64 + wr * 32 + m * 16 + l4 * 4 + j;
        int dd = wc * 64 + n * 16 + l15;
        size_t o = (size_t)dd * 1024 + t;
        float oldv = bf2f(Dh[o]);
        Dd[o] = f2bf((1.f - lam) * oldv + lam * acc[m][n][j]);
      }
}

// ---------- final prop step fused with finalize: blend + alpha*D0 + norm ----
// Block covers 64 t x ALL 128 dd -> per-t norm in-block; writes P[t][dd].
__global__ __launch_bounds__(256) void prop_final_mfma(
    const ushort_t* __restrict__ Ab, const ushort_t* __restrict__ Dsrc,
    const ushort_t* __restrict__ Dt0, ushort_t* __restrict__ P,
    const float* __restrict__ logit_lam, const float* __restrict__ log_alpha) {
  __shared__ ushort_t ldsA[64 * 64];
  __shared__ ushort_t ldsB[128 * 64];
  __shared__ float sums[4][2][4][4];   // [wid][m][j][l4]
  int tid = threadIdx.x;
  int orig = (blockIdx.x & 7) * 64 + (blockIdx.x >> 3);
  int bx = orig & 15, hz = orig >> 4;
  const int lane = tid & 63, wid = tid >> 6;
  const int wr = wid >> 1, wc = wid & 1;
  const int l15 = lane & 15, l4 = lane >> 4;
  const ushort_t* Dh = Dsrc + (size_t)hz * 131072;
  f32x4 acc[2][4];
  #pragma unroll
  for (int m = 0; m < 2; ++m)
    #pragma unroll
    for (int n = 0; n < 4; ++n) acc[m][n] = (f32x4){0.f, 0.f, 0.f, 0.f};
  mfma_64x128_loop(Ab + (size_t)hz * 1048576 + (size_t)bx * 64 * 1024,
                   Dh, ldsA, ldsB, tid, acc);
  float lam = 1.f / (1.f + __expf(-logit_lam[0]));
  float alpha = 1.f / (1.f + __expf(-log_alpha[0]));
  const ushort_t* D0h = Dt0 + (size_t)hz * 131072;
  float F[2][4][4];
  float ssp[2][4];
  #pragma unroll
  for (int m = 0; m < 2; ++m)
    #pragma unroll
    for (int j = 0; j < 4; ++j) {
      int t = bx * 64 + wr * 32 + m * 16 + l4 * 4 + j;
      float s = 0.f;
      #pragma unroll
      for (int n = 0; n < 4; ++n) {
        int dd = wc * 64 + n * 16 + l15;
        size_t o = (size_t)dd * 1024 + t;
        float f = (1.f - lam) * bf2f(Dh[o]) + lam * acc[m][n][j] +
                  alpha * bf2f(D0h[o]);
        F[m][n][j] = f;
        s += f * f;
      }
      #pragma unroll
      for (int off = 1; off < 16; off <<= 1) s += __shfl_xor(s, off);
      ssp[m][j] = s;
    }
  if (l15 == 0) {
    #pragma unroll
    for (int m = 0; m < 2; ++m)
      #pragma unroll
      for (int j = 0; j < 4; ++j)
        sums[wid][m][j][l4] = ssp[m][j];
  }
  __syncthreads();
  ushort_t* Ph = P + (size_t)hz * 1024 * 128;
  #pragma unroll
  for (int m = 0; m < 2; ++m)
    #pragma unroll
    for (int j = 0; j < 4; ++j) {
      float tot = sums[wid][m][j][l4] + sums[wid ^ 1][m][j][l4];
      float ni = 1.f / fmaxf(sqrtf(tot), 1e-6f);
      int t = bx * 64 + wr * 32 + m * 16 + l4 * 4 + j;
      #pragma unroll
      for (int n = 0; n < 4; ++n) {
        int dd = wc * 64 + n * 16 + l15;
        Ph[(size_t)t * 128 + dd] = f2bf(F[m][n][j] * ni);
      }
    }
}

// ---------------------------------------------------------------------------
// Wave-synchronous exact top-128 on bf16 scores via 16-step ballot binary
// search (no LDS / atomics / barriers). Tie -> lower index via ballot rank.
// MODE 0: fp32 dense write (phase output) + bf16 in-place WB (attnv input).
// MODE 1: bf16 in-place WB only.
// ---------------------------------------------------------------------------
template<int MODE>
__global__ __launch_bounds__(256) void topk16_kernel(
    ushort_t* __restrict__ Sb, float* __restrict__ denseOut) {
  const int tid = threadIdx.x;
  const int lane = tid & 63, wv = tid >> 6;
  const int row = blockIdx.x * 4 + wv;
  ushort_t* Srow = Sb + (size_t)row * 1024;

  float scr[2][8];
  unsigned kk[2][8];
  #pragma unroll
  for (int g = 0; g < 2; ++g) {
    u16x8 v = *(const u16x8*)&Srow[g * 512 + lane * 8];
    #pragma unroll
    for (int e = 0; e < 8; ++e) {
      scr[g][e] = bf2f(v[e]);
      kk[g][e] = fkey16((unsigned)v[e]);
    }
  }

  unsigned prefix = 0, r = TOPK;
  #pragma unroll
  for (int b = 15; b >= 0; --b) {
    unsigned want = (prefix << 1) | 1u;
    unsigned cnt = 0;
    #pragma unroll
    for (int g = 0; g < 2; ++g)
      #pragma unroll
      for (int e = 0; e < 8; ++e)
        cnt += (unsigned)__popcll(__ballot((kk[g][e] >> b) == want));
    if (cnt >= r) prefix = want;
    else { prefix <<= 1; r -= cnt; }
  }
  const unsigned thr = prefix;

  float mx = -3.402823466e38f;
  #pragma unroll
  for (int g = 0; g < 2; ++g)
    #pragma unroll
    for (int e = 0; e < 8; ++e) mx = fmaxf(mx, scr[g][e]);
  #pragma unroll
  for (int off = 1; off < 64; off <<= 1) mx = fmaxf(mx, __shfl_xor(mx, off));

  const unsigned long long below = (1ull << lane) - 1ull;
  unsigned cum = 0;
  float w[2][8];
  float ps = 0.f;
  #pragma unroll
  for (int g = 0; g < 2; ++g) {
    unsigned long long bal[8];
    #pragma unroll
    for (int e = 0; e < 8; ++e) bal[e] = __ballot(kk[g][e] == thr);
    unsigned rb = cum;
    #pragma unroll
    for (int e = 0; e < 8; ++e) rb += (unsigned)__popcll(bal[e] & below);
    unsigned ownPrior = 0;
    #pragma unroll
    for (int e = 0; e < 8; ++e) {
      bool eq = (kk[g][e] == thr);
      bool sel = (kk[g][e] > thr) || (eq && (rb + ownPrior) < r);
      ownPrior += eq ? 1u : 0u;
      float ex = sel ? __expf(scr[g][e] - mx) : 0.f;
      w[g][e] = ex;
      ps += ex;
    }
    #pragma unroll
    for (int e = 0; e < 8; ++e) cum += (unsigned)__popcll(bal[e]);
  }
  float pss = ps;
  #pragma unroll
  for (int off = 1; off < 64; off <<= 1) pss += __shfl_xor(pss, off);
  const float inv = 1.f / pss;

  if (MODE == 0) {
    float* Drow = denseOut + (size_t)row * 1024;
    #pragma unroll
    for (int g = 0; g < 2; ++g) {
      *(float4*)&Drow[g * 512 + lane * 8] =
          make_float4(w[g][0] * inv, w[g][1] * inv, w[g][2] * inv, w[g][3] * inv);
      *(float4*)&Drow[g * 512 + lane * 8 + 4] =
          make_float4(w[g][4] * inv, w[g][5] * inv, w[g][6] * inv, w[g][7] * inv);
    }
  }
  #pragma unroll
  for (int g = 0; g < 2; ++g) {
    u16x8 o;
    #pragma unroll
    for (int e = 0; e < 8; ++e) o[e] = f2bf(w[g][e] * inv);
    *(u16x8*)&Srow[g * 512 + lane * 8] = o;
  }
}

// ---------- attn.V as MFMA (BM=64), 1D grid 512, XCD-swizzled ---------------
__global__ __launch_bounds__(256) void attnv_mfma(
    const ushort_t* __restrict__ Wb, const ushort_t* __restrict__ Vt,
    ushort_t* __restrict__ attn_b) {
  __shared__ ushort_t ldsA[64 * 64];
  __shared__ ushort_t ldsB[64 * 64];
  int tid = threadIdx.x;
  int orig = (blockIdx.x & 7) * 64 + (blockIdx.x >> 3);
  int bx = orig & 15, hz = orig >> 4;
  const int lane = tid & 63, wid = tid >> 6;
  const int wr = wid >> 1, wc = wid & 1;
  const int l15 = lane & 15, l4 = lane >> 4;
  const ushort_t* Wh = Wb + (size_t)hz * 1048576 + (size_t)bx * 64 * 1024;
  const ushort_t* Vh = Vt + (size_t)hz * 65536;
  f32x4 acc[2][2];
  #pragma unroll
  for (int m = 0; m < 2; ++m)
    #pragma unroll
    for (int n = 0; n < 2; ++n) acc[m][n] = (f32x4){0.f, 0.f, 0.f, 0.f};
  for (int k0 = 0; k0 < 1024; k0 += 64) {
    #pragma unroll
    for (int i = 0; i < 2; ++i) {
      int cid = tid + 256 * i;
      int rowc = cid >> 3, slot = cid & 7;
      int gc = slot ^ (rowc & 7);
      gload_lds16(&Wh[(size_t)rowc * 1024 + k0 + gc * 8], &ldsA[cid * 8]);
    }
    #pragma unroll
    for (int i = 0; i < 2; ++i) {
      int cid = tid + 256 * i;
      int rowc = cid >> 3, slot = cid & 7;
      int gc = slot ^ (rowc & 7);
      gload_lds16(&Vh[(size_t)rowc * 1024 + k0 + gc * 8], &ldsB[cid * 8]);
    }
    __syncthreads();
    #pragma unroll
    for (int ks = 0; ks < 2; ++ks) {
      short8 af[2], bfr[2];
      #pragma unroll
      for (int m = 0; m < 2; ++m) {
        int r = wr * 32 + m * 16 + l15;
        int c = ks * 4 + l4;
        af[m] = *(const short8*)&ldsA[r * 64 + (c ^ (r & 7)) * 8];
      }
      #pragma unroll
      for (int n = 0; n < 2; ++n) {
        int r = wc * 32 + n * 16 + l15;
        int c = ks * 4 + l4;
        bfr[n] = *(const short8*)&ldsB[r * 64 + (c ^ (r & 7)) * 8];
      }
      #pragma unroll
      for (int m = 0; m < 2; ++m)
        #pragma unroll
        for (int n = 0; n < 2; ++n)
          acc[m][n] = __builtin_amdgcn_mfma_f32_16x16x32_bf16(
              af[m], bfr[n], acc[m][n], 0, 0, 0);
    }
    __syncthreads();
  }
  int b = hz >> 4, h = hz & 15;
  #pragma unroll
  for (int m = 0; m < 2; ++m)
    #pragma unroll
    for (int n = 0; n < 2; ++n)
      #pragma unroll
      for (int j = 0; j < 4; ++j) {
        int t = bx * 64 + wr * 32 + m * 16 + l4 * 4 + j;
        int d = wc * 32 + n * 16 + l15;
        attn_b[((size_t)(b * T_ + t)) * DM + h * DK_ + d] = f2bf(acc[m][n][j]);
      }
}

// ---------- output projection: BM=64 x BN=128 x K=1024, grid 256 ------------
__global__ __launch_bounds__(256) void outproj_mfma(
    const ushort_t* __restrict__ A, const ushort_t* __restrict__ Wo,
    float* __restrict__ out) {
  __shared__ ushort_t ldsA[64 * 64];
  __shared__ ushort_t ldsB[128 * 64];
  int tid = threadIdx.x;
  int orig = (blockIdx.x & 7) * 32 + (blockIdx.x >> 3);
  int bx = orig & 7, by = orig >> 3;   // bx: 128-col tile, by: 64-row tile
  const int lane = tid & 63, wid = tid >> 6;
  const int wr = wid >> 1, wc = wid & 1;
  const int l15 = lane & 15, l4 = lane >> 4;
  f32x4 acc[2][4];
  #pragma unroll
  for (int m = 0; m < 2; ++m)
    #pragma unroll
    for (int n = 0; n < 4; ++n) acc[m][n] = (f32x4){0.f, 0.f, 0.f, 0.f};
  mfma_64x128_loop(A + (size_t)by * 64 * 1024,
                   Wo + (size_t)bx * 128 * 1024, ldsA, ldsB, tid, acc);
  #pragma unroll
  for (int m = 0; m < 2; ++m)
    #pragma unroll
    for (int n = 0; n < 4; ++n)
      #pragma unroll
      for (int j = 0; j < 4; ++j) {
        int r = by * 64 + wr * 32 + m * 16 + l4 * 4 + j;
        int c = bx * 128 + wc * 64 + n * 16 + l15;
        out[(size_t)r * 1024 + c] = acc[m][n][j];
      }
}

extern "C" void kernel_launch(void* const* d_in, const int* in_sizes, int n_in,
                              void* d_out, int out_size, void* d_ws, size_t ws_size,
                              hipStream_t stream) {
  (void)in_sizes; (void)n_in; (void)out_size; (void)ws_size;
  const float* x         = (const float*)d_in[0];
  const float* wq        = (const float*)d_in[1];
  const float* wk        = (const float*)d_in[2];
  const float* wre       = (const float*)d_in[3];
  const float* wim       = (const float*)d_in[4];
  const float* wv        = (const float*)d_in[5];
  const float* wo        = (const float*)d_in[6];
  const float* logit_lam = (const float*)d_in[7];
  const float* log_alpha = (const float*)d_in[8];

  float* out   = (float*)d_out;                 // (B,T,DM)
  float* dense = out + (size_t)B_ * T_ * DM;    // phase_attn (B,H,T,T) fp32 out
  // first 10 MB of dense doubles as bf16 weight scratch (wq..wv); dead after
  // proj5 and long before topk16<0> writes the dense region (stream-ordered).
  ushort_t* w5_b = (ushort_t*)dense;

  char* ws = (char*)d_ws;
  const size_t MB = (size_t)1 << 20;
  // 0-64 MB: adjacency bf16 scores -> in-place weights (prop input);
  //          later reused for phase bf16 scores -> in-place weights (attnv).
  ushort_t* A_b  = (ushort_t*)(ws + 0 * MB);
  ushort_t* S2_b = A_b;                          // phase scores (A dead)
  ushort_t* dt0  = (ushort_t*)(ws + 64 * MB);    // 8 MB Dt0 [32][128][1024]
  ushort_t* dtA  = (ushort_t*)(ws + 72 * MB);    // 8 MB ping
  ushort_t* dtB  = (ushort_t*)(ws + 80 * MB);    // 8 MB pong; P_b after prop3
  ushort_t* P_b  = dtB;                          // packed [t][Ur|Ui] bf16
  ushort_t* vt_b = (ushort_t*)(ws + 88 * MB);    // 4 MB Vt [32][64][1024]
  ushort_t* xb   = (ushort_t*)(ws + 92 * MB);    // 4 MB bf16 x; reused attn_b
  ushort_t* attn_b = xb;                         // alias (x dead after proj)
  ushort_t* qh_b = (ushort_t*)(ws + 96 * MB);    // 4 MB bf16 Q; wo_b after adj
  ushort_t* wo_b = qh_b;                         // alias (Q dead after scores)
  ushort_t* kh_b = (ushort_t*)(ws + 100 * MB);   // 4 MB bf16 K
  // total workspace: 104 MB

  const int rows = B_ * H_ * T_;  // 32768

  // 0. bf16 casts, one launch (W_O deferred until Q is dead)
  cast6_kernel<<<dim3(2048, 6), 256, 0, stream>>>(
      x, wq, wk, wre, wim, wv, xb, w5_b);

  // 1. all 5 projections (MFMA)
  proj5_mfma<<<640, 256, 0, stream>>>(xb, w5_b, qh_b, kh_b, dt0, vt_b);

  // 2. adjacency scores (bf16 -> A_b) + top-k (in-place bf16 weights)
  score_mfma<64><<<2048, 256, 0, stream>>>(qh_b, kh_b, A_b, 0.125f);
  cast_bf16_kernel<<<1024, 256, 0, stream>>>(wo, wo_b, DM * DM / 4);  // Q dead
  topk16_kernel<1><<<rows / 4, 256, 0, stream>>>(A_b, nullptr);

  // 3. topology propagation: 3 plain steps + final step fused with finalize
  prop_mfma<<<512, 256, 0, stream>>>(A_b, dt0, dtA, logit_lam);
  prop_mfma<<<512, 256, 0, stream>>>(A_b, dtA, dtB, logit_lam);
  prop_mfma<<<512, 256, 0, stream>>>(A_b, dtB, dtA, logit_lam);
  prop_final_mfma<<<512, 256, 0, stream>>>(A_b, dtA, dt0, P_b,
                                           logit_lam, log_alpha);

  // 4. phase scores, symmetric (bf16 -> S2_b over dead A) + top-k:
  //    fp32 dense output + bf16 in-place weights for attnv
  score_sym_mfma<<<1152, 256, 0, stream>>>(P_b, S2_b, 11.3137085f);
  topk16_kernel<0><<<rows / 4, 256, 0, stream>>>(S2_b, dense);

  // 5. attn . V as MFMA from bf16 weights, then output projection
  attnv_mfma<<<512, 256, 0, stream>>>(S2_b, vt_b, attn_b);
  outproj_mfma<<<256, 256, 0, stream>>>(attn_b, wo_b, out);
}